// Round 1
// baseline (1202.841 us; speedup 1.0000x reference)
//
#include <hip/hip_runtime.h>
#include <math.h>

#define NN 50000
#define NE 400000
#define FIN 70
#define EDIM 4
#define HIDD 128
#define NHEAD 4
#define HD1 512
constexpr int ET = NE + NN;

constexpr size_t al4(size_t x){ return (x + 3) & ~size_t(3); }
// ws offsets in 4-byte words
constexpr size_t CNT_O   = 0;                          // int[NN]   (zeroed)
constexpr size_t CUR_O   = al4(CNT_O + NN);            // int[NN]   (zeroed)
constexpr size_t M1_O    = al4(CUR_O + NN);            // uint[NN*4](zeroed)
constexpr size_t DEN1_O  = al4(M1_O + (size_t)NN*4);   // f32[NN*4] (zeroed)
constexpr size_t M2_O    = al4(DEN1_O + (size_t)NN*4); // uint[NN]  (zeroed)
constexpr size_t DEN2_O  = al4(M2_O + NN);             // f32[NN]   (zeroed)
constexpr size_t LOOPA_O = al4(DEN2_O + NN);           // f32[NN*4] (zeroed; sum then mean)
constexpr size_t ZEND    = al4(LOOPA_O + (size_t)NN*4);
constexpr size_t CSR_O   = ZEND;                       // int[NN+1]
constexpr size_t EID_O   = al4(CSR_O + NN + 1);        // int[ET]
constexpr size_t SS1_O   = al4(EID_O + ET);            // f32[NN*4]
constexpr size_t SD1_O   = al4(SS1_O + (size_t)NN*4);
constexpr size_t SS2_O   = al4(SD1_O + (size_t)NN*4);  // f32[NN]
constexpr size_t SD2_O   = al4(SS2_O + NN);
constexpr size_t AL1_O   = al4(SD2_O + NN);            // f32[ET*4]
constexpr size_t AL2_O   = al4(AL1_O + (size_t)ET*4);  // f32[ET]
constexpr size_t CST_O   = al4(AL2_O + ET);            // f32[2048]
constexpr size_t XS1_O   = al4(CST_O + 2048);          // f32[NN*512]
constexpr size_t X1_O    = XS1_O + (size_t)NN*HD1;     // f32[NN*512]
constexpr size_t XS2_O   = X1_O  + (size_t)NN*HD1;     // f32[NN*128]

// const-block sub-offsets (words, within CST)
constexpr int VS1 = 0;    // [70][4]
constexpr int VD1 = 320;  // [70][4]
constexpr int VE1 = 640;  // [4][4]
constexpr int VE2 = 656;  // [4]
constexpr int VS2 = 704;  // [512]
constexpr int VD2 = 1216; // [512]

__device__ __forceinline__ unsigned fenc(float f){
  unsigned u = __float_as_uint(f);
  return (u & 0x80000000u) ? ~u : (u | 0x80000000u);
}
__device__ __forceinline__ float fdec(unsigned u){
  return (u & 0x80000000u) ? __uint_as_float(u & 0x7fffffffu) : __uint_as_float(~u);
}
__device__ __forceinline__ float gelu_exact(float x){
  return 0.5f * x * (1.f + erff(x * 0.70710678118654752440f));
}

// ---- self-loop prep: per-dst degree + edge_attr sum -------------------------
__global__ void k_deg(const int* __restrict__ ei, const float* __restrict__ ea,
                      int* __restrict__ cnt, float* __restrict__ loopa){
  int e = blockIdx.x * 256 + threadIdx.x;
  if (e >= NE) return;
  int d = ei[NE + e];
  atomicAdd(&cnt[d], 1);
  float4 a = *(const float4*)&ea[(size_t)e * 4];
  atomicAdd(&loopa[d*4+0], a.x);
  atomicAdd(&loopa[d*4+1], a.y);
  atomicAdd(&loopa[d*4+2], a.z);
  atomicAdd(&loopa[d*4+3], a.w);
}

__global__ void k_loopnorm(const int* __restrict__ cnt, float* __restrict__ loopa){
  int n = blockIdx.x * 256 + threadIdx.x;
  if (n >= NN) return;
  int c = cnt[n];
  float inv = 1.f / (float)(c > 1 ? c : 1);
  loopa[n*4+0] *= inv; loopa[n*4+1] *= inv;
  loopa[n*4+2] *= inv; loopa[n*4+3] *= inv;
}

// ---- CSR build: exclusive scan of (cnt+1), then fill ------------------------
__global__ void k_scan(const int* __restrict__ cnt, int* __restrict__ csr){
  __shared__ int sh[1024];
  __shared__ int carry;
  int tid = threadIdx.x;
  if (tid == 0){ carry = 0; csr[0] = 0; }
  __syncthreads();
  for (int base = 0; base < NN; base += 1024){
    int i = base + tid;
    int v = (i < NN) ? cnt[i] + 1 : 0;
    sh[tid] = v;
    __syncthreads();
    for (int off = 1; off < 1024; off <<= 1){
      int t = (tid >= off) ? sh[tid - off] : 0;
      __syncthreads();
      sh[tid] += t;
      __syncthreads();
    }
    int c = carry;
    if (i < NN) csr[i + 1] = c + sh[tid];
    __syncthreads();
    if (tid == 1023) carry = c + sh[1023];
    __syncthreads();
  }
}

__global__ void k_fill(const int* __restrict__ ei, const int* __restrict__ csr,
                       int* __restrict__ cur, int* __restrict__ eid){
  int e = blockIdx.x * 256 + threadIdx.x;
  if (e >= NE) return;
  int d = ei[NE + e];
  int p = csr[d] + atomicAdd(&cur[d], 1);
  eid[p] = e;
}

__global__ void k_self(const int* __restrict__ csr, const int* __restrict__ cnt,
                       int* __restrict__ eid){
  int n = blockIdx.x * 256 + threadIdx.x;
  if (n >= NN) return;
  eid[csr[n] + cnt[n]] = NE + n;   // last slot of segment n
}

// ---- tiny weight pre-reductions --------------------------------------------
__global__ void k_prep(const float* __restrict__ W1, const float* __restrict__ as1,
                       const float* __restrict__ ad1, const float* __restrict__ We1,
                       const float* __restrict__ ae1, const float* __restrict__ W2,
                       const float* __restrict__ as2, const float* __restrict__ ad2,
                       const float* __restrict__ We2, const float* __restrict__ ae2,
                       float* __restrict__ C){
  int t = threadIdx.x;                       // block of 512
  if (t < 280){                              // vs1/vd1: [k=t/4][h=t&3]
    int k = t >> 2, h = t & 3;
    float s = 0.f, d = 0.f;
    for (int dd = 0; dd < 128; ++dd){
      float w = W1[k*512 + h*128 + dd];
      s += w * as1[h*128 + dd];
      d += w * ad1[h*128 + dd];
    }
    C[VS1 + t] = s; C[VD1 + t] = d;
  }
  if (t < 16){                               // ve1[k][h]
    int k = t >> 2, h = t & 3;
    float s = 0.f;
    for (int dd = 0; dd < 128; ++dd) s += We1[k*512 + h*128 + dd] * ae1[h*128 + dd];
    C[VE1 + t] = s;
  }
  if (t < 4){                                // ve2[k]
    float s = 0.f;
    for (int dd = 0; dd < 128; ++dd) s += We2[t*128 + dd] * ae2[dd];
    C[VE2 + t] = s;
  }
  {                                          // vs2/vd2: all 512 threads
    float s = 0.f, d = 0.f;
    for (int dd = 0; dd < 128; ++dd){
      float w = W2[t*128 + dd];
      s += w * as2[dd];
      d += w * ad2[dd];
    }
    C[VS2 + t] = s; C[VD2 + t] = d;
  }
}

// ---- generic f32 GEMM: C[M,N] = A[M,K] @ B[K,N], 64x64 tile, 4x4/thread -----
__global__ __launch_bounds__(256) void k_gemm(const float* __restrict__ A,
    const float* __restrict__ B, float* __restrict__ Cm, int M, int K, int N){
  __shared__ float As[32][68];   // As[k][m] (transposed), row = 272B (16B-aligned)
  __shared__ float Bs[32][68];   // Bs[k][n]
  int tid = threadIdx.x, tx = tid & 15, ty = tid >> 4;
  int row0 = blockIdx.x * 64, col0 = blockIdx.y * 64;
  float acc[4][4] = {};
  for (int kc = 0; kc < K; kc += 32){
    int kk = tid & 31, mm = tid >> 5;
    #pragma unroll
    for (int m = 0; m < 64; m += 8){
      int gr = row0 + mm + m, gk = kc + kk;
      As[kk][mm + m] = (gr < M && gk < K) ? A[(size_t)gr * K + gk] : 0.f;
    }
    int nn = tid & 63, k2 = tid >> 6;
    #pragma unroll
    for (int k = 0; k < 32; k += 4){
      int gk = kc + k2 + k;
      Bs[k2 + k][nn] = (gk < K) ? B[(size_t)gk * N + col0 + nn] : 0.f;
    }
    __syncthreads();
    #pragma unroll
    for (int k = 0; k < 32; ++k){
      float4 a = *(const float4*)&As[k][ty * 4];
      float4 b = *(const float4*)&Bs[k][tx * 4];
      acc[0][0]+=a.x*b.x; acc[0][1]+=a.x*b.y; acc[0][2]+=a.x*b.z; acc[0][3]+=a.x*b.w;
      acc[1][0]+=a.y*b.x; acc[1][1]+=a.y*b.y; acc[1][2]+=a.y*b.z; acc[1][3]+=a.y*b.w;
      acc[2][0]+=a.z*b.x; acc[2][1]+=a.z*b.y; acc[2][2]+=a.z*b.z; acc[2][3]+=a.z*b.w;
      acc[3][0]+=a.w*b.x; acc[3][1]+=a.w*b.y; acc[3][2]+=a.w*b.z; acc[3][3]+=a.w*b.w;
    }
    __syncthreads();
  }
  #pragma unroll
  for (int i = 0; i < 4; ++i){
    int r = row0 + ty * 4 + i;
    if (r < M){
      #pragma unroll
      for (int j = 0; j < 4; ++j) Cm[(size_t)r * N + col0 + tx * 4 + j] = acc[i][j];
    }
  }
}

// ---- layer1 attention scalars ----------------------------------------------
__global__ void k_s1(const float* __restrict__ nf, const float* __restrict__ C,
                     float* __restrict__ ss1, float* __restrict__ sd1){
  int t = blockIdx.x * 256 + threadIdx.x;
  if (t >= NN * 4) return;
  int n = t >> 2, h = t & 3;
  float s = 0.f, d = 0.f;
  for (int k = 0; k < FIN; ++k){
    float xv = nf[(size_t)n * FIN + k];
    s += xv * C[VS1 + k*4 + h];
    d += xv * C[VD1 + k*4 + h];
  }
  ss1[t] = s; sd1[t] = d;
}

__global__ void k_alpha1(const int* __restrict__ ei, const float* __restrict__ ea,
                         const float* __restrict__ loopa, const float* __restrict__ ss1,
                         const float* __restrict__ sd1, const float* __restrict__ C,
                         float* __restrict__ al1, unsigned* __restrict__ m1){
  int e = blockIdx.x * 256 + threadIdx.x;
  if (e >= ET) return;
  int s, d; float4 a;
  if (e < NE){ s = ei[e]; d = ei[NE + e]; a = *(const float4*)&ea[(size_t)e * 4]; }
  else { s = e - NE; d = s; a = *(const float4*)&loopa[(size_t)s * 4]; }
  #pragma unroll
  for (int h = 0; h < 4; ++h){
    float se = a.x*C[VE1+h] + a.y*C[VE1+4+h] + a.z*C[VE1+8+h] + a.w*C[VE1+12+h];
    float al = ss1[s*4+h] + sd1[d*4+h] + se;
    al = al > 0.f ? al : 0.2f * al;
    al1[(size_t)e*4 + h] = al;
    atomicMax(&m1[d*4 + h], fenc(al));
  }
}

__global__ void k_ex1(const int* __restrict__ ei, float* __restrict__ al1,
                      const unsigned* __restrict__ m1, float* __restrict__ den1){
  int e = blockIdx.x * 256 + threadIdx.x;
  if (e >= ET) return;
  int d = (e < NE) ? ei[NE + e] : e - NE;
  #pragma unroll
  for (int h = 0; h < 4; ++h){
    float ex = expf(al1[(size_t)e*4 + h] - fdec(m1[d*4 + h]));
    al1[(size_t)e*4 + h] = ex;
    atomicAdd(&den1[d*4 + h], ex);
  }
}

// ---- layer1 aggregation (CSR gather) + bias + GELU --------------------------
__global__ __launch_bounds__(256) void k_agg1(const int* __restrict__ ei,
    const int* __restrict__ csr, const int* __restrict__ eid,
    const float* __restrict__ al1, const float* __restrict__ den1,
    const float* __restrict__ xs1, const float* __restrict__ b1,
    float* __restrict__ x1){
  int n = blockIdx.x, tid = threadIdx.x;
  __shared__ float invd[4];
  if (tid < 4) invd[tid] = 1.f / (den1[n*4 + tid] + 1e-16f);
  __syncthreads();
  int off = csr[n], deg = csr[n + 1] - off;
  int h0 = tid >> 7, h1 = h0 + 2;
  float a0 = 0.f, a1 = 0.f;
  for (int j = 0; j < deg; ++j){
    int e = eid[off + j];
    int s = (e < NE) ? ei[e] : (e - NE);
    const float* xr = &xs1[(size_t)s * 512];
    float w0 = al1[(size_t)e*4 + h0] * invd[h0];
    float w1 = al1[(size_t)e*4 + h1] * invd[h1];
    a0 += w0 * xr[tid];
    a1 += w1 * xr[tid + 256];
  }
  x1[(size_t)n*512 + tid]       = gelu_exact(a0 + b1[tid]);
  x1[(size_t)n*512 + tid + 256] = gelu_exact(a1 + b1[tid + 256]);
}

// ---- layer2 attention scalars ----------------------------------------------
__global__ void k_s2(const float* __restrict__ x1, const float* __restrict__ C,
                     float* __restrict__ ss2, float* __restrict__ sd2){
  int tid = threadIdx.x, lane = tid & 63;
  int n = blockIdx.x * 4 + (tid >> 6);
  if (n >= NN) return;
  const float4* xr = (const float4*)&x1[(size_t)n * 512];
  const float4* vs = (const float4*)&C[VS2];
  const float4* vd = (const float4*)&C[VD2];
  float4 a = xr[lane], b = xr[lane + 64];
  float4 v1 = vs[lane], v2 = vs[lane + 64];
  float4 w1 = vd[lane], w2 = vd[lane + 64];
  float s = a.x*v1.x + a.y*v1.y + a.z*v1.z + a.w*v1.w
          + b.x*v2.x + b.y*v2.y + b.z*v2.z + b.w*v2.w;
  float d = a.x*w1.x + a.y*w1.y + a.z*w1.z + a.w*w1.w
          + b.x*w2.x + b.y*w2.y + b.z*w2.z + b.w*w2.w;
  for (int o = 32; o; o >>= 1){ s += __shfl_down(s, o); d += __shfl_down(d, o); }
  if (lane == 0){ ss2[n] = s; sd2[n] = d; }
}

__global__ void k_alpha2(const int* __restrict__ ei, const float* __restrict__ ea,
                         const float* __restrict__ loopa, const float* __restrict__ ss2,
                         const float* __restrict__ sd2, const float* __restrict__ C,
                         float* __restrict__ al2, unsigned* __restrict__ m2){
  int e = blockIdx.x * 256 + threadIdx.x;
  if (e >= ET) return;
  int s, d; float4 a;
  if (e < NE){ s = ei[e]; d = ei[NE + e]; a = *(const float4*)&ea[(size_t)e * 4]; }
  else { s = e - NE; d = s; a = *(const float4*)&loopa[(size_t)s * 4]; }
  float se = a.x*C[VE2] + a.y*C[VE2+1] + a.z*C[VE2+2] + a.w*C[VE2+3];
  float al = ss2[s] + sd2[d] + se;
  al = al > 0.f ? al : 0.2f * al;
  al2[e] = al;
  atomicMax(&m2[d], fenc(al));
}

__global__ void k_ex2(const int* __restrict__ ei, float* __restrict__ al2,
                      const unsigned* __restrict__ m2, float* __restrict__ den2){
  int e = blockIdx.x * 256 + threadIdx.x;
  if (e >= ET) return;
  int d = (e < NE) ? ei[NE + e] : e - NE;
  float ex = expf(al2[e] - fdec(m2[d]));
  al2[e] = ex;
  atomicAdd(&den2[d], ex);
}

// ---- layer2 aggregation + GELU + LayerNorm + both projections (fused) -------
__global__ __launch_bounds__(128) void k_agg2(const int* __restrict__ ei,
    const int* __restrict__ csr, const int* __restrict__ eid,
    const float* __restrict__ al2, const float* __restrict__ den2,
    const float* __restrict__ xs2, const float* __restrict__ b2,
    const float* __restrict__ lng, const float* __restrict__ lnb,
    const float* __restrict__ pw, const float* __restrict__ pb,
    const float* __restrict__ dwm, const float* __restrict__ dbv,
    float* __restrict__ out){
  int n = blockIdx.x, tid = threadIdx.x, lane = tid & 63, wv = tid >> 6;
  int off = csr[n], deg = csr[n + 1] - off;
  float invd = 1.f / (den2[n] + 1e-16f);
  float acc = 0.f;
  for (int j = 0; j < deg; ++j){
    int e = eid[off + j];
    int s = (e < NE) ? ei[e] : (e - NE);
    acc += (al2[e] * invd) * xs2[(size_t)s * 128 + tid];
  }
  float g = gelu_exact(acc + b2[tid]);
  __shared__ float red[2], red2[2], yl[128];
  float t = g;
  for (int o = 32; o; o >>= 1) t += __shfl_down(t, o);
  if (lane == 0) red[wv] = t;
  __syncthreads();
  float mu = (red[0] + red[1]) * (1.f / 128.f);
  float dv = g - mu;
  float q = dv * dv;
  for (int o = 32; o; o >>= 1) q += __shfl_down(q, o);
  if (lane == 0) red2[wv] = q;
  __syncthreads();
  float var = (red2[0] + red2[1]) * (1.f / 128.f);
  float y = dv * rsqrtf(var + 1e-5f) * lng[tid] + lnb[tid];
  yl[tid] = y;
  __syncthreads();
  if (tid < 8){
    float o1 = pb[tid];
    for (int d2 = 0; d2 < 128; ++d2) o1 += yl[d2] * pw[d2*8 + tid];
    out[(size_t)n*8 + tid] = o1;
  } else if (tid >= 64 && tid < 68){
    int j = tid - 64;
    float o2 = dbv[j];
    for (int d2 = 0; d2 < 128; ++d2) o2 += yl[d2] * dwm[d2*4 + j];
    out[(size_t)NN*8 + (size_t)n*4 + j] = o2;
  }
}

extern "C" void kernel_launch(void* const* d_in, const int* in_sizes, int n_in,
                              void* d_out, int out_size, void* d_ws, size_t ws_size,
                              hipStream_t stream){
  const float* nf  = (const float*)d_in[0];
  const int*   ei  = (const int*)  d_in[1];
  const float* ea  = (const float*)d_in[2];
  const float* W1  = (const float*)d_in[3];
  const float* as1 = (const float*)d_in[4];
  const float* ad1 = (const float*)d_in[5];
  const float* We1 = (const float*)d_in[6];
  const float* ae1 = (const float*)d_in[7];
  const float* b1  = (const float*)d_in[8];
  const float* W2  = (const float*)d_in[9];
  const float* as2 = (const float*)d_in[10];
  const float* ad2 = (const float*)d_in[11];
  const float* We2 = (const float*)d_in[12];
  const float* ae2 = (const float*)d_in[13];
  const float* b2  = (const float*)d_in[14];
  const float* lng = (const float*)d_in[15];
  const float* lnb = (const float*)d_in[16];
  const float* pw  = (const float*)d_in[17];
  const float* pb  = (const float*)d_in[18];
  const float* dw  = (const float*)d_in[19];
  const float* db  = (const float*)d_in[20];
  float* out = (float*)d_out;

  float* wf = (float*)d_ws;
  int*      cnt  = (int*)     (wf + CNT_O);
  int*      cur  = (int*)     (wf + CUR_O);
  unsigned* m1   = (unsigned*)(wf + M1_O);
  float*    den1 =            (wf + DEN1_O);
  unsigned* m2   = (unsigned*)(wf + M2_O);
  float*    den2 =            (wf + DEN2_O);
  float*    loopa=            (wf + LOOPA_O);
  int*      csr  = (int*)     (wf + CSR_O);
  int*      eid  = (int*)     (wf + EID_O);
  float*    ss1  =            (wf + SS1_O);
  float*    sd1  =            (wf + SD1_O);
  float*    ss2  =            (wf + SS2_O);
  float*    sd2  =            (wf + SD2_O);
  float*    al1  =            (wf + AL1_O);
  float*    al2  =            (wf + AL2_O);
  float*    Cc   =            (wf + CST_O);
  float*    xs1  =            (wf + XS1_O);
  float*    x1   =            (wf + X1_O);
  float*    xs2  =            (wf + XS2_O);

  hipMemsetAsync(wf, 0, ZEND * 4, stream);
  k_prep<<<1, 512, 0, stream>>>(W1, as1, ad1, We1, ae1, W2, as2, ad2, We2, ae2, Cc);
  k_deg<<<(NE + 255) / 256, 256, 0, stream>>>(ei, ea, cnt, loopa);
  k_loopnorm<<<(NN + 255) / 256, 256, 0, stream>>>(cnt, loopa);
  k_scan<<<1, 1024, 0, stream>>>(cnt, csr);
  k_fill<<<(NE + 255) / 256, 256, 0, stream>>>(ei, csr, cur, eid);
  k_self<<<(NN + 255) / 256, 256, 0, stream>>>(csr, cnt, eid);
  k_gemm<<<dim3(782, 8), 256, 0, stream>>>(nf, W1, xs1, NN, FIN, 512);
  k_s1<<<(NN * 4 + 255) / 256, 256, 0, stream>>>(nf, Cc, ss1, sd1);
  k_alpha1<<<(ET + 255) / 256, 256, 0, stream>>>(ei, ea, loopa, ss1, sd1, Cc, al1, m1);
  k_ex1<<<(ET + 255) / 256, 256, 0, stream>>>(ei, al1, m1, den1);
  k_agg1<<<NN, 256, 0, stream>>>(ei, csr, eid, al1, den1, xs1, b1, x1);
  k_gemm<<<dim3(782, 2), 256, 0, stream>>>(x1, W2, xs2, NN, 512, HIDD);
  k_s2<<<(NN + 3) / 4, 256, 0, stream>>>(x1, Cc, ss2, sd2);
  k_alpha2<<<(ET + 255) / 256, 256, 0, stream>>>(ei, ea, loopa, ss2, sd2, Cc, al2, m2);
  k_ex2<<<(ET + 255) / 256, 256, 0, stream>>>(ei, al2, m2, den2);
  k_agg2<<<NN, 128, 0, stream>>>(ei, csr, eid, al2, den2, xs2, b2, lng, lnb,
                                 pw, pb, dw, db, out);
}

// Round 2
// 1044.343 us; speedup vs baseline: 1.1518x; 1.1518x over previous
//
#include <hip/hip_runtime.h>
#include <math.h>

#define NN 50000
#define NE 400000
#define FIN 70
#define EDIM 4
#define HIDD 128
#define NHEAD 4
constexpr int ET = NE + NN;

constexpr size_t al4(size_t x){ return (x + 3) & ~size_t(3); }
// ws offsets in 4-byte words
constexpr size_t CNT_O   = 0;                          // int[NN]   (zeroed)
constexpr size_t CUR_O   = al4(CNT_O + NN);            // int[NN]   (zeroed)
constexpr size_t M1_O    = al4(CUR_O + NN);            // uint[NN*4](zeroed)
constexpr size_t DEN1_O  = al4(M1_O + (size_t)NN*4);   // f32[NN*4] (zeroed)
constexpr size_t M2_O    = al4(DEN1_O + (size_t)NN*4); // uint[NN]  (zeroed)
constexpr size_t DEN2_O  = al4(M2_O + NN);             // f32[NN]   (zeroed)
constexpr size_t LOOPA_O = al4(DEN2_O + NN);           // f32[NN*4] (zeroed; sum then mean)
constexpr size_t ZEND    = al4(LOOPA_O + (size_t)NN*4);
constexpr size_t CSR_O   = ZEND;                       // int[NN+1]
constexpr size_t ESRC_O  = al4(CSR_O + NN + 1);        // int[ET]  src node per CSR slot
constexpr size_t EDST_O  = al4(ESRC_O + ET);           // int[ET]  dst node per CSR slot
constexpr size_t EAI_O   = al4(EDST_O + ET);           // int[ET]  original edge id (NE+n for self)
constexpr size_t SS1_O   = al4(EAI_O + ET);            // f32[NN*4]
constexpr size_t SD1_O   = al4(SS1_O + (size_t)NN*4);
constexpr size_t SS2_O   = al4(SD1_O + (size_t)NN*4);  // f32[NN]
constexpr size_t SD2_O   = al4(SS2_O + NN);
constexpr size_t AL1_O   = al4(SD2_O + NN);            // f32[ET*4] (CSR order)
constexpr size_t AL2_O   = al4(AL1_O + (size_t)ET*4);  // f32[ET]   (CSR order)
constexpr size_t CST_O   = al4(AL2_O + ET);            // f32[2048]
constexpr size_t AGG_O   = al4(CST_O + 2048);          // f32[4][NN][70]
constexpr size_t X1_O    = AGG_O + (size_t)4*NN*FIN;   // f32[NN*512]
constexpr size_t XS2_O   = X1_O  + (size_t)NN*512;     // f32[NN*128]

// const-block sub-offsets (words, within CST)
constexpr int VS1 = 0;    // [70][4]
constexpr int VD1 = 320;  // [70][4]
constexpr int VE1 = 640;  // [4][4]
constexpr int VE2 = 656;  // [4]
constexpr int VS2 = 704;  // [512]
constexpr int VD2 = 1216; // [512]

__device__ __forceinline__ unsigned fenc(float f){
  unsigned u = __float_as_uint(f);
  return (u & 0x80000000u) ? ~u : (u | 0x80000000u);
}
__device__ __forceinline__ float fdec(unsigned u){
  return (u & 0x80000000u) ? __uint_as_float(u & 0x7fffffffu) : __uint_as_float(~u);
}
__device__ __forceinline__ float gelu_exact(float x){
  return 0.5f * x * (1.f + erff(x * 0.70710678118654752440f));
}

// ---- self-loop prep: per-dst degree + edge_attr sum -------------------------
__global__ void k_deg(const int* __restrict__ ei, const float* __restrict__ ea,
                      int* __restrict__ cnt, float* __restrict__ loopa){
  int e = blockIdx.x * 256 + threadIdx.x;
  if (e >= NE) return;
  int d = ei[NE + e];
  atomicAdd(&cnt[d], 1);
  float4 a = *(const float4*)&ea[(size_t)e * 4];
  atomicAdd(&loopa[d*4+0], a.x);
  atomicAdd(&loopa[d*4+1], a.y);
  atomicAdd(&loopa[d*4+2], a.z);
  atomicAdd(&loopa[d*4+3], a.w);
}

__global__ void k_loopnorm(const int* __restrict__ cnt, float* __restrict__ loopa){
  int n = blockIdx.x * 256 + threadIdx.x;
  if (n >= NN) return;
  int c = cnt[n];
  float inv = 1.f / (float)(c > 1 ? c : 1);
  loopa[n*4+0] *= inv; loopa[n*4+1] *= inv;
  loopa[n*4+2] *= inv; loopa[n*4+3] *= inv;
}

// ---- CSR build: exclusive scan of (cnt+1) via shfl wave-scans ---------------
__global__ void k_scan(const int* __restrict__ cnt, int* __restrict__ csr){
  __shared__ int wsum[16];
  __shared__ int carry;
  int tid = threadIdx.x, lane = tid & 63, w = tid >> 6;
  if (tid == 0){ carry = 0; csr[0] = 0; }
  __syncthreads();
  for (int base = 0; base < NN; base += 1024){
    int i = base + tid;
    int x = (i < NN) ? cnt[i] + 1 : 0;
    #pragma unroll
    for (int o = 1; o < 64; o <<= 1){ int t = __shfl_up(x, o); if (lane >= o) x += t; }
    if (lane == 63) wsum[w] = x;
    __syncthreads();
    if (w == 0 && lane < 16){
      int y = wsum[lane];
      #pragma unroll
      for (int o = 1; o < 16; o <<= 1){ int t = __shfl_up(y, o); if (lane >= o) y += t; }
      wsum[lane] = y;
    }
    __syncthreads();
    int add = carry + (w > 0 ? wsum[w - 1] : 0);
    if (i < NN) csr[i + 1] = add + x;
    __syncthreads();
    if (tid == 1023) carry = carry + wsum[15];
    __syncthreads();
  }
}

__global__ void k_fill(const int* __restrict__ ei, const int* __restrict__ csr,
                       int* __restrict__ cur, int* __restrict__ esrc,
                       int* __restrict__ edst, int* __restrict__ eai){
  int e = blockIdx.x * 256 + threadIdx.x;
  if (e >= NE) return;
  int s = ei[e], d = ei[NE + e];
  int p = csr[d] + atomicAdd(&cur[d], 1);
  esrc[p] = s; edst[p] = d; eai[p] = e;
}

__global__ void k_self(const int* __restrict__ csr, const int* __restrict__ cnt,
                       int* __restrict__ esrc, int* __restrict__ edst,
                       int* __restrict__ eai){
  int n = blockIdx.x * 256 + threadIdx.x;
  if (n >= NN) return;
  int p = csr[n] + cnt[n];        // last slot of segment n
  esrc[p] = n; edst[p] = n; eai[p] = NE + n;
}

// ---- tiny weight pre-reductions --------------------------------------------
__global__ void k_prep(const float* __restrict__ W1, const float* __restrict__ as1,
                       const float* __restrict__ ad1, const float* __restrict__ We1,
                       const float* __restrict__ ae1, const float* __restrict__ W2,
                       const float* __restrict__ as2, const float* __restrict__ ad2,
                       const float* __restrict__ We2, const float* __restrict__ ae2,
                       float* __restrict__ C){
  int t = threadIdx.x;                       // block of 512
  if (t < 280){                              // vs1/vd1: [k=t/4][h=t&3]
    int k = t >> 2, h = t & 3;
    float s = 0.f, d = 0.f;
    for (int dd = 0; dd < 128; ++dd){
      float w = W1[k*512 + h*128 + dd];
      s += w * as1[h*128 + dd];
      d += w * ad1[h*128 + dd];
    }
    C[VS1 + t] = s; C[VD1 + t] = d;
  }
  if (t < 16){                               // ve1[k][h]
    int k = t >> 2, h = t & 3;
    float s = 0.f;
    for (int dd = 0; dd < 128; ++dd) s += We1[k*512 + h*128 + dd] * ae1[h*128 + dd];
    C[VE1 + t] = s;
  }
  if (t < 4){                                // ve2[k]
    float s = 0.f;
    for (int dd = 0; dd < 128; ++dd) s += We2[t*128 + dd] * ae2[dd];
    C[VE2 + t] = s;
  }
  {                                          // vs2/vd2: all 512 threads
    float s = 0.f, d = 0.f;
    for (int dd = 0; dd < 128; ++dd){
      float w = W2[t*128 + dd];
      s += w * as2[dd];
      d += w * ad2[dd];
    }
    C[VS2 + t] = s; C[VD2 + t] = d;
  }
}

// ---- generic strided/batched f32 GEMM: 64x64 tile, 4x4/thread ---------------
// C[z][M,N] = A[z] @ B[z]  (+bias, +gelu per template)
template<bool BIAS, bool GELU>
__global__ __launch_bounds__(256) void k_gemm(
    const float* __restrict__ A, int lda, long aSz,
    const float* __restrict__ B, int ldb, long bSz,
    float* __restrict__ Cm, int ldc, long cSz,
    const float* __restrict__ bias, long biasSz,
    int M, int K){
  int z = blockIdx.z;
  A += (size_t)z * aSz; B += (size_t)z * bSz; Cm += (size_t)z * cSz;
  __shared__ float As[32][68];   // As[k][m] (transposed), row = 272B (16B-aligned)
  __shared__ float Bs[32][68];   // Bs[k][n]
  int tid = threadIdx.x, tx = tid & 15, ty = tid >> 4;
  int row0 = blockIdx.x * 64, col0 = blockIdx.y * 64;
  float acc[4][4] = {};
  for (int kc = 0; kc < K; kc += 32){
    int kk = tid & 31, mm = tid >> 5;
    #pragma unroll
    for (int m = 0; m < 64; m += 8){
      int gr = row0 + mm + m, gk = kc + kk;
      As[kk][mm + m] = (gr < M && gk < K) ? A[(size_t)gr * lda + gk] : 0.f;
    }
    int nn = tid & 63, k2 = tid >> 6;
    #pragma unroll
    for (int k = 0; k < 32; k += 4){
      int gk = kc + k2 + k;
      Bs[k2 + k][nn] = (gk < K) ? B[(size_t)gk * ldb + col0 + nn] : 0.f;
    }
    __syncthreads();
    #pragma unroll
    for (int k = 0; k < 32; ++k){
      float4 a = *(const float4*)&As[k][ty * 4];
      float4 b = *(const float4*)&Bs[k][tx * 4];
      acc[0][0]+=a.x*b.x; acc[0][1]+=a.x*b.y; acc[0][2]+=a.x*b.z; acc[0][3]+=a.x*b.w;
      acc[1][0]+=a.y*b.x; acc[1][1]+=a.y*b.y; acc[1][2]+=a.y*b.z; acc[1][3]+=a.y*b.w;
      acc[2][0]+=a.z*b.x; acc[2][1]+=a.z*b.y; acc[2][2]+=a.z*b.z; acc[2][3]+=a.z*b.w;
      acc[3][0]+=a.w*b.x; acc[3][1]+=a.w*b.y; acc[3][2]+=a.w*b.z; acc[3][3]+=a.w*b.w;
    }
    __syncthreads();
  }
  #pragma unroll
  for (int i = 0; i < 4; ++i){
    int r = row0 + ty * 4 + i;
    if (r < M){
      #pragma unroll
      for (int j = 0; j < 4; ++j){
        float v = acc[i][j];
        if (BIAS) v += bias[(size_t)z * biasSz + col0 + tx * 4 + j];
        if (GELU) v = gelu_exact(v);
        Cm[(size_t)r * ldc + col0 + tx * 4 + j] = v;
      }
    }
  }
}

// ---- layer1 attention scalars ----------------------------------------------
__global__ void k_s1(const float* __restrict__ nf, const float* __restrict__ C,
                     float* __restrict__ ss1, float* __restrict__ sd1){
  int t = blockIdx.x * 256 + threadIdx.x;
  if (t >= NN * 4) return;
  int n = t >> 2, h = t & 3;
  float s = 0.f, d = 0.f;
  for (int k = 0; k < FIN; ++k){
    float xv = nf[(size_t)n * FIN + k];
    s += xv * C[VS1 + k*4 + h];
    d += xv * C[VD1 + k*4 + h];
  }
  ss1[t] = s; sd1[t] = d;
}

__global__ void k_alpha1(const int* __restrict__ esrc, const int* __restrict__ edst,
                         const int* __restrict__ eai, const float* __restrict__ ea,
                         const float* __restrict__ loopa, const float* __restrict__ ss1,
                         const float* __restrict__ sd1, const float* __restrict__ C,
                         float* __restrict__ al1, unsigned* __restrict__ m1){
  int p = blockIdx.x * 256 + threadIdx.x;
  if (p >= ET) return;
  int s = esrc[p], d = edst[p], e = eai[p];
  float4 a = (e < NE) ? *(const float4*)&ea[(size_t)e * 4]
                      : *(const float4*)&loopa[(size_t)d * 4];
  #pragma unroll
  for (int h = 0; h < 4; ++h){
    float se = a.x*C[VE1+h] + a.y*C[VE1+4+h] + a.z*C[VE1+8+h] + a.w*C[VE1+12+h];
    float al = ss1[s*4+h] + sd1[d*4+h] + se;
    al = al > 0.f ? al : 0.2f * al;
    al1[(size_t)p*4 + h] = al;
    atomicMax(&m1[d*4 + h], fenc(al));
  }
}

__global__ void k_ex1(const int* __restrict__ edst, float* __restrict__ al1,
                      const unsigned* __restrict__ m1, float* __restrict__ den1){
  int p = blockIdx.x * 256 + threadIdx.x;
  if (p >= ET) return;
  int d = edst[p];
  #pragma unroll
  for (int h = 0; h < 4; ++h){
    float ex = expf(al1[(size_t)p*4 + h] - fdec(m1[d*4 + h]));
    al1[(size_t)p*4 + h] = ex;
    atomicAdd(&den1[d*4 + h], ex);
  }
}

// ---- layer1 aggregation in INPUT space: agg[h][n][k] = inv*Σ ex*nf[src][k] --
__global__ __launch_bounds__(256) void k_aggnf(const int* __restrict__ csr,
    const int* __restrict__ esrc, const float* __restrict__ al1,
    const float* __restrict__ den1, const float* __restrict__ nf,
    float* __restrict__ agg){
  int lane = threadIdx.x & 63, w = threadIdx.x >> 6;
  int n = blockIdx.x * 4 + w;
  if (n >= NN) return;
  float4 dn = *(const float4*)&den1[(size_t)n * 4];
  float i0 = 1.f/(dn.x+1e-16f), i1 = 1.f/(dn.y+1e-16f);
  float i2 = 1.f/(dn.z+1e-16f), i3 = 1.f/(dn.w+1e-16f);
  int off = csr[n], end = csr[n + 1];
  bool hi = lane < (FIN - 64);
  float a0=0,a1=0,a2=0,a3=0,b0=0,b1=0,b2=0,b3=0;
  for (int p = off; p < end; ++p){
    int s = esrc[p];
    float4 wv = *(const float4*)&al1[(size_t)p * 4];
    float v0 = nf[(size_t)s * FIN + lane];
    float v1 = hi ? nf[(size_t)s * FIN + 64 + lane] : 0.f;
    a0 += wv.x*v0; a1 += wv.y*v0; a2 += wv.z*v0; a3 += wv.w*v0;
    b0 += wv.x*v1; b1 += wv.y*v1; b2 += wv.z*v1; b3 += wv.w*v1;
  }
  size_t base = (size_t)n * FIN + lane;
  constexpr size_t HS = (size_t)NN * FIN;
  agg[base]        = a0*i0; agg[base +   HS] = a1*i1;
  agg[base + 2*HS] = a2*i2; agg[base + 3*HS] = a3*i3;
  if (hi){
    agg[base + 64]        = b0*i0; agg[base + 64 +   HS] = b1*i1;
    agg[base + 64 + 2*HS] = b2*i2; agg[base + 64 + 3*HS] = b3*i3;
  }
}

// ---- layer2 attention scalars ----------------------------------------------
__global__ void k_s2(const float* __restrict__ x1, const float* __restrict__ C,
                     float* __restrict__ ss2, float* __restrict__ sd2){
  int tid = threadIdx.x, lane = tid & 63;
  int n = blockIdx.x * 4 + (tid >> 6);
  if (n >= NN) return;
  const float4* xr = (const float4*)&x1[(size_t)n * 512];
  const float4* vs = (const float4*)&C[VS2];
  const float4* vd = (const float4*)&C[VD2];
  float4 a = xr[lane], b = xr[lane + 64];
  float4 v1 = vs[lane], v2 = vs[lane + 64];
  float4 w1 = vd[lane], w2 = vd[lane + 64];
  float s = a.x*v1.x + a.y*v1.y + a.z*v1.z + a.w*v1.w
          + b.x*v2.x + b.y*v2.y + b.z*v2.z + b.w*v2.w;
  float d = a.x*w1.x + a.y*w1.y + a.z*w1.z + a.w*w1.w
          + b.x*w2.x + b.y*w2.y + b.z*w2.z + b.w*w2.w;
  for (int o = 32; o; o >>= 1){ s += __shfl_down(s, o); d += __shfl_down(d, o); }
  if (lane == 0){ ss2[n] = s; sd2[n] = d; }
}

__global__ void k_alpha2(const int* __restrict__ esrc, const int* __restrict__ edst,
                         const int* __restrict__ eai, const float* __restrict__ ea,
                         const float* __restrict__ loopa, const float* __restrict__ ss2,
                         const float* __restrict__ sd2, const float* __restrict__ C,
                         float* __restrict__ al2, unsigned* __restrict__ m2){
  int p = blockIdx.x * 256 + threadIdx.x;
  if (p >= ET) return;
  int s = esrc[p], d = edst[p], e = eai[p];
  float4 a = (e < NE) ? *(const float4*)&ea[(size_t)e * 4]
                      : *(const float4*)&loopa[(size_t)d * 4];
  float se = a.x*C[VE2] + a.y*C[VE2+1] + a.z*C[VE2+2] + a.w*C[VE2+3];
  float al = ss2[s] + sd2[d] + se;
  al = al > 0.f ? al : 0.2f * al;
  al2[p] = al;
  atomicMax(&m2[d], fenc(al));
}

__global__ void k_ex2(const int* __restrict__ edst, float* __restrict__ al2,
                      const unsigned* __restrict__ m2, float* __restrict__ den2){
  int p = blockIdx.x * 256 + threadIdx.x;
  if (p >= ET) return;
  int d = edst[p];
  float ex = expf(al2[p] - fdec(m2[d]));
  al2[p] = ex;
  atomicAdd(&den2[d], ex);
}

// ---- layer2 aggregation + GELU + LayerNorm + both projections (fused) -------
__global__ __launch_bounds__(128) void k_agg2(
    const int* __restrict__ csr, const int* __restrict__ esrc,
    const float* __restrict__ al2, const float* __restrict__ den2,
    const float* __restrict__ xs2, const float* __restrict__ b2,
    const float* __restrict__ lng, const float* __restrict__ lnb,
    const float* __restrict__ pw, const float* __restrict__ pb,
    const float* __restrict__ dwm, const float* __restrict__ dbv,
    float* __restrict__ out){
  int n = blockIdx.x, tid = threadIdx.x, lane = tid & 63, wv = tid >> 6;
  int off = csr[n], end = csr[n + 1];
  float invd = 1.f / (den2[n] + 1e-16f);
  float acc = 0.f;
  for (int p = off; p < end; ++p){
    int s = esrc[p];
    acc += al2[p] * xs2[(size_t)s * 128 + tid];
  }
  float g = gelu_exact(acc * invd + b2[tid]);
  __shared__ float red[2], red2[2], yl[128];
  float t = g;
  for (int o = 32; o; o >>= 1) t += __shfl_down(t, o);
  if (lane == 0) red[wv] = t;
  __syncthreads();
  float mu = (red[0] + red[1]) * (1.f / 128.f);
  float dv = g - mu;
  float q = dv * dv;
  for (int o = 32; o; o >>= 1) q += __shfl_down(q, o);
  if (lane == 0) red2[wv] = q;
  __syncthreads();
  float var = (red2[0] + red2[1]) * (1.f / 128.f);
  float y = dv * rsqrtf(var + 1e-5f) * lng[tid] + lnb[tid];
  yl[tid] = y;
  __syncthreads();
  if (tid < 8){
    float o1 = pb[tid];
    for (int d2 = 0; d2 < 128; ++d2) o1 += yl[d2] * pw[d2*8 + tid];
    out[(size_t)n*8 + tid] = o1;
  } else if (tid >= 64 && tid < 68){
    int j = tid - 64;
    float o2 = dbv[j];
    for (int d2 = 0; d2 < 128; ++d2) o2 += yl[d2] * dwm[d2*4 + j];
    out[(size_t)NN*8 + (size_t)n*4 + j] = o2;
  }
}

extern "C" void kernel_launch(void* const* d_in, const int* in_sizes, int n_in,
                              void* d_out, int out_size, void* d_ws, size_t ws_size,
                              hipStream_t stream){
  const float* nf  = (const float*)d_in[0];
  const int*   ei  = (const int*)  d_in[1];
  const float* ea  = (const float*)d_in[2];
  const float* W1  = (const float*)d_in[3];
  const float* as1 = (const float*)d_in[4];
  const float* ad1 = (const float*)d_in[5];
  const float* We1 = (const float*)d_in[6];
  const float* ae1 = (const float*)d_in[7];
  const float* b1  = (const float*)d_in[8];
  const float* W2  = (const float*)d_in[9];
  const float* as2 = (const float*)d_in[10];
  const float* ad2 = (const float*)d_in[11];
  const float* We2 = (const float*)d_in[12];
  const float* ae2 = (const float*)d_in[13];
  const float* b2  = (const float*)d_in[14];
  const float* lng = (const float*)d_in[15];
  const float* lnb = (const float*)d_in[16];
  const float* pw  = (const float*)d_in[17];
  const float* pb  = (const float*)d_in[18];
  const float* dw  = (const float*)d_in[19];
  const float* db  = (const float*)d_in[20];
  float* out = (float*)d_out;

  float* wf = (float*)d_ws;
  int*      cnt  = (int*)     (wf + CNT_O);
  int*      cur  = (int*)     (wf + CUR_O);
  unsigned* m1   = (unsigned*)(wf + M1_O);
  float*    den1 =            (wf + DEN1_O);
  unsigned* m2   = (unsigned*)(wf + M2_O);
  float*    den2 =            (wf + DEN2_O);
  float*    loopa=            (wf + LOOPA_O);
  int*      csr  = (int*)     (wf + CSR_O);
  int*      esrc = (int*)     (wf + ESRC_O);
  int*      edst = (int*)     (wf + EDST_O);
  int*      eai  = (int*)     (wf + EAI_O);
  float*    ss1  =            (wf + SS1_O);
  float*    sd1  =            (wf + SD1_O);
  float*    ss2  =            (wf + SS2_O);
  float*    sd2  =            (wf + SD2_O);
  float*    al1  =            (wf + AL1_O);
  float*    al2  =            (wf + AL2_O);
  float*    Cc   =            (wf + CST_O);
  float*    agg  =            (wf + AGG_O);
  float*    x1   =            (wf + X1_O);
  float*    xs2  =            (wf + XS2_O);

  hipMemsetAsync(wf, 0, ZEND * 4, stream);
  k_prep<<<1, 512, 0, stream>>>(W1, as1, ad1, We1, ae1, W2, as2, ad2, We2, ae2, Cc);
  k_deg<<<(NE + 255) / 256, 256, 0, stream>>>(ei, ea, cnt, loopa);
  k_loopnorm<<<(NN + 255) / 256, 256, 0, stream>>>(cnt, loopa);
  k_scan<<<1, 1024, 0, stream>>>(cnt, csr);
  k_fill<<<(NE + 255) / 256, 256, 0, stream>>>(ei, csr, cur, esrc, edst, eai);
  k_self<<<(NN + 255) / 256, 256, 0, stream>>>(csr, cnt, esrc, edst, eai);
  k_s1<<<(NN * 4 + 255) / 256, 256, 0, stream>>>(nf, Cc, ss1, sd1);
  k_alpha1<<<(ET + 255) / 256, 256, 0, stream>>>(esrc, edst, eai, ea, loopa, ss1, sd1, Cc, al1, m1);
  k_ex1<<<(ET + 255) / 256, 256, 0, stream>>>(edst, al1, m1, den1);
  k_aggnf<<<(NN + 3) / 4, 256, 0, stream>>>(csr, esrc, al1, den1, nf, agg);
  // layer-1 transform: per head h, x1[:, h*128:(h+1)*128] = gelu(agg_h @ W1_h + b1_h)
  k_gemm<true, true><<<dim3((NN + 63) / 64, 2, 4), 256, 0, stream>>>(
      agg, FIN, (long)NN * FIN, W1, 512, 128, x1, 512, 128, b1, 128, NN, FIN);
  k_s2<<<(NN + 3) / 4, 256, 0, stream>>>(x1, Cc, ss2, sd2);
  // layer-2 GEMM: xs2 = x1 @ W2
  k_gemm<false, false><<<dim3((NN + 63) / 64, 2, 1), 256, 0, stream>>>(
      x1, 512, 0, W2, 128, 0, xs2, 128, 0, nullptr, 0, NN, 512);
  k_alpha2<<<(ET + 255) / 256, 256, 0, stream>>>(esrc, edst, eai, ea, loopa, ss2, sd2, Cc, al2, m2);
  k_ex2<<<(ET + 255) / 256, 256, 0, stream>>>(edst, al2, m2, den2);
  k_agg2<<<NN, 128, 0, stream>>>(csr, esrc, al2, den2, xs2, b2, lng, lnb,
                                 pw, pb, dw, db, out);
}

// Round 3
// 690.884 us; speedup vs baseline: 1.7410x; 1.5116x over previous
//
#include <hip/hip_runtime.h>
#include <hip/hip_bf16.h>
#include <math.h>

#define NN 50000
#define NE 400000
#define FIN 70
#define EDIM 4
#define HIDD 128
#define NHEAD 4
constexpr int ET = NE + NN;
constexpr int KP1 = 96;           // layer-1 K padded (70 -> 96)

constexpr size_t al4(size_t x){ return (x + 3) & ~size_t(3); }
// ws offsets in 4-byte words
constexpr size_t CNT_O   = 0;                          // int[NN]   (zeroed)
constexpr size_t CUR_O   = al4(CNT_O + NN);            // int[NN]   (zeroed)
constexpr size_t DEN1_O  = al4(CUR_O + NN);            // f32[NN*4] (zeroed)
constexpr size_t DEN2_O  = al4(DEN1_O + (size_t)NN*4); // f32[NN]   (zeroed)
constexpr size_t LOOPA_O = al4(DEN2_O + NN);           // f32[NN*4] (zeroed)
constexpr size_t ZEND    = al4(LOOPA_O + (size_t)NN*4);
constexpr size_t CSR_O   = ZEND;                       // int[NN+1]
constexpr size_t ESRC_O  = al4(CSR_O + NN + 1);        // int[ET]
constexpr size_t EDST_O  = al4(ESRC_O + ET);           // int[ET]
constexpr size_t EAI_O   = al4(EDST_O + ET);           // int[ET]
constexpr size_t SS1_O   = al4(EAI_O + ET);            // f32[NN*4]
constexpr size_t SD1_O   = al4(SS1_O + (size_t)NN*4);
constexpr size_t SS2_O   = al4(SD1_O + (size_t)NN*4);  // f32[NN]
constexpr size_t SD2_O   = al4(SS2_O + NN);
constexpr size_t AL1_O   = al4(SD2_O + NN);            // f32[ET*4] (CSR order, holds ex)
constexpr size_t AL2_O   = al4(AL1_O + (size_t)ET*4);  // f32[ET]
constexpr size_t CST_O   = al4(AL2_O + ET);            // f32[2048]
constexpr size_t W1T_O   = al4(CST_O + 2048);          // bf16[4][128][96]  = 49152 el
constexpr size_t W2T_O   = al4(W1T_O + 4*128*KP1/2);   // bf16[128][512]    = 65536 el
constexpr size_t AGG_O   = al4(W2T_O + 128*512/2);     // bf16[4][NN][96]
constexpr size_t X1_O    = al4(AGG_O + (size_t)4*NN*KP1/2); // bf16[NN][512]
constexpr size_t XS2_O   = al4(X1_O + (size_t)NN*512/2);    // f32[NN*128]

// const-block sub-offsets (words, within CST)
constexpr int VS1 = 0;    // [70][4]
constexpr int VD1 = 320;  // [70][4]
constexpr int VE1 = 640;  // [4][4]
constexpr int VE2 = 656;  // [4]
constexpr int VS2 = 704;  // [512]
constexpr int VD2 = 1216; // [512]

typedef short s8v __attribute__((ext_vector_type(8)));
typedef float f4v __attribute__((ext_vector_type(4)));

__device__ __forceinline__ float gelu_exact(float x){
  return 0.5f * x * (1.f + erff(x * 0.70710678118654752440f));
}
__device__ __forceinline__ unsigned short f2b(float v){
  __hip_bfloat16 b = __float2bfloat16(v);
  return *(unsigned short*)&b;
}
__device__ __forceinline__ float b2f(unsigned u_lo16){
  return __uint_as_float(u_lo16 << 16);
}

// ---- self-loop prep ---------------------------------------------------------
__global__ void k_deg(const int* __restrict__ ei, const float* __restrict__ ea,
                      int* __restrict__ cnt, float* __restrict__ loopa){
  int e = blockIdx.x * 256 + threadIdx.x;
  if (e >= NE) return;
  int d = ei[NE + e];
  atomicAdd(&cnt[d], 1);
  float4 a = *(const float4*)&ea[(size_t)e * 4];
  atomicAdd(&loopa[d*4+0], a.x);
  atomicAdd(&loopa[d*4+1], a.y);
  atomicAdd(&loopa[d*4+2], a.z);
  atomicAdd(&loopa[d*4+3], a.w);
}

__global__ void k_loopnorm(const int* __restrict__ cnt, float* __restrict__ loopa){
  int n = blockIdx.x * 256 + threadIdx.x;
  if (n >= NN) return;
  int c = cnt[n];
  float inv = 1.f / (float)(c > 1 ? c : 1);
  loopa[n*4+0] *= inv; loopa[n*4+1] *= inv;
  loopa[n*4+2] *= inv; loopa[n*4+3] *= inv;
}

// ---- CSR build: exclusive scan of (cnt+1), 4 elems/thread -------------------
__global__ void k_scan(const int* __restrict__ cnt, int* __restrict__ csr){
  __shared__ int wsum[16];
  __shared__ int carry;
  int tid = threadIdx.x, lane = tid & 63, w = tid >> 6;
  if (tid == 0){ carry = 0; csr[0] = 0; }
  __syncthreads();
  for (int base = 0; base < NN; base += 4096){
    int i0 = base + tid * 4;
    int v[4]; int s = 0;
    if (i0 + 3 < NN){
      int4 c4 = *(const int4*)&cnt[i0];
      v[0]=c4.x+1; v[1]=c4.y+1; v[2]=c4.z+1; v[3]=c4.w+1;
    } else {
      #pragma unroll
      for (int j = 0; j < 4; ++j) v[j] = (i0 + j < NN) ? cnt[i0 + j] + 1 : 0;
    }
    s = v[0]+v[1]+v[2]+v[3];
    int x = s;
    #pragma unroll
    for (int o = 1; o < 64; o <<= 1){ int t = __shfl_up(x, o); if (lane >= o) x += t; }
    if (lane == 63) wsum[w] = x;
    __syncthreads();
    if (w == 0 && lane < 16){
      int y = wsum[lane];
      #pragma unroll
      for (int o = 1; o < 16; o <<= 1){ int t = __shfl_up(y, o); if (lane >= o) y += t; }
      wsum[lane] = y;
    }
    __syncthreads();
    int run = carry + (w > 0 ? wsum[w - 1] : 0) + x - s;  // exclusive prefix
    #pragma unroll
    for (int j = 0; j < 4; ++j){
      run += v[j];
      if (i0 + j < NN) csr[i0 + j + 1] = run;
    }
    __syncthreads();
    if (tid == 1023) carry += wsum[15];
    __syncthreads();
  }
}

__global__ void k_fill(const int* __restrict__ ei, const int* __restrict__ csr,
                       int* __restrict__ cur, int* __restrict__ esrc,
                       int* __restrict__ edst, int* __restrict__ eai){
  int e = blockIdx.x * 256 + threadIdx.x;
  if (e >= NE) return;
  int s = ei[e], d = ei[NE + e];
  int p = csr[d] + atomicAdd(&cur[d], 1);
  esrc[p] = s; edst[p] = d; eai[p] = e;
}

__global__ void k_self(const int* __restrict__ csr, const int* __restrict__ cnt,
                       int* __restrict__ esrc, int* __restrict__ edst,
                       int* __restrict__ eai){
  int n = blockIdx.x * 256 + threadIdx.x;
  if (n >= NN) return;
  int p = csr[n] + cnt[n];
  esrc[p] = n; edst[p] = n; eai[p] = NE + n;
}

// ---- tiny weight pre-reductions --------------------------------------------
__global__ void k_prep(const float* __restrict__ W1, const float* __restrict__ as1,
                       const float* __restrict__ ad1, const float* __restrict__ We1,
                       const float* __restrict__ ae1, const float* __restrict__ W2,
                       const float* __restrict__ as2, const float* __restrict__ ad2,
                       const float* __restrict__ We2, const float* __restrict__ ae2,
                       float* __restrict__ C){
  int t = threadIdx.x;                       // block of 512
  if (t < 280){
    int k = t >> 2, h = t & 3;
    float s = 0.f, d = 0.f;
    for (int dd = 0; dd < 128; ++dd){
      float w = W1[k*512 + h*128 + dd];
      s += w * as1[h*128 + dd];
      d += w * ad1[h*128 + dd];
    }
    C[VS1 + t] = s; C[VD1 + t] = d;
  }
  if (t < 16){
    int k = t >> 2, h = t & 3;
    float s = 0.f;
    for (int dd = 0; dd < 128; ++dd) s += We1[k*512 + h*128 + dd] * ae1[h*128 + dd];
    C[VE1 + t] = s;
  }
  if (t < 4){
    float s = 0.f;
    for (int dd = 0; dd < 128; ++dd) s += We2[t*128 + dd] * ae2[dd];
    C[VE2 + t] = s;
  }
  {
    float s = 0.f, d = 0.f;
    for (int dd = 0; dd < 128; ++dd){
      float w = W2[t*128 + dd];
      s += w * as2[dd];
      d += w * ad2[dd];
    }
    C[VS2 + t] = s; C[VD2 + t] = d;
  }
}

// ---- transpose + bf16-cast weights: W1t[h][n][k96], W2t[n][k512] ------------
__global__ void k_tw(const float* __restrict__ W1, const float* __restrict__ W2,
                     unsigned short* __restrict__ W1t, unsigned short* __restrict__ W2t){
  int i = blockIdx.x * 256 + threadIdx.x;
  if (i < 4*128*KP1){
    int k = i % KP1, n = (i / KP1) & 127, h = i / (KP1*128);
    float v = (k < FIN) ? W1[k*512 + h*128 + n] : 0.f;
    W1t[i] = f2b(v);
  } else {
    int j = i - 4*128*KP1;
    if (j < 128*512){
      int k = j & 511, n = j >> 9;
      W2t[j] = f2b(W2[k*128 + n]);
    }
  }
}

// ---- MFMA GEMM: C[M,N=128] = A[M,KP] @ Bt^T, 128x128 tile, 4 waves ----------
// FUSE1: out = bf16( gelu(acc + bias[z*128+col]) ) into x1[M][512] at col z*128
// else : out = f32 acc into C[M][128]
template<bool FUSE1>
__global__ __launch_bounds__(256) void k_mfma(
    const unsigned short* __restrict__ A, int lda, long aSz,
    const unsigned short* __restrict__ Bt, long bSz,
    void* __restrict__ Cout, const float* __restrict__ bias,
    int M, int KP){
  int z = blockIdx.y;
  A  += (size_t)z * aSz;
  Bt += (size_t)z * bSz;
  __shared__ unsigned short As[128 * 40];   // pitch 40 bf16 (80 B)
  __shared__ unsigned short Bs[128 * 40];
  int tid = threadIdx.x, lane = tid & 63, w = tid >> 6;
  int wm = w & 1, wn = w >> 1;
  int row0 = blockIdx.x * 128;
  f4v acc[4][4] = {};
  int r4 = tid >> 2, c4 = tid & 3;          // staging: row, 8-elem chunk
  for (int k0 = 0; k0 < KP; k0 += 32){
    #pragma unroll
    for (int half = 0; half < 2; ++half){
      int r = r4 + half * 64;
      int gr = row0 + r;
      uint4 va = make_uint4(0,0,0,0);
      if (gr < M) va = *(const uint4*)&A[(size_t)gr * lda + k0 + c4*8];
      *(uint4*)&As[r*40 + c4*8] = va;
      uint4 vb = *(const uint4*)&Bt[(size_t)r * lda + k0 + c4*8];
      *(uint4*)&Bs[r*40 + c4*8] = vb;
    }
    __syncthreads();
    s8v af[4], bf[4];
    #pragma unroll
    for (int i = 0; i < 4; ++i){
      af[i] = *(const s8v*)&As[(wm*64 + i*16 + (lane & 15))*40 + (lane >> 4)*8];
      bf[i] = *(const s8v*)&Bs[(wn*64 + i*16 + (lane & 15))*40 + (lane >> 4)*8];
    }
    #pragma unroll
    for (int mi = 0; mi < 4; ++mi)
      #pragma unroll
      for (int ni = 0; ni < 4; ++ni)
        acc[mi][ni] = __builtin_amdgcn_mfma_f32_16x16x32_bf16(af[mi], bf[ni], acc[mi][ni], 0, 0, 0);
    __syncthreads();
  }
  // epilogue: D layout col=lane&15, row=(lane>>4)*4+reg
  int cq = lane & 15, rq = lane >> 4;
  #pragma unroll
  for (int mi = 0; mi < 4; ++mi){
    #pragma unroll
    for (int r = 0; r < 4; ++r){
      int row = row0 + wm*64 + mi*16 + rq*4 + r;
      if (row >= M) continue;
      #pragma unroll
      for (int ni = 0; ni < 4; ++ni){
        int col = wn*64 + ni*16 + cq;
        float v = acc[mi][ni][r];
        if (FUSE1){
          int colg = z*128 + col;
          v = gelu_exact(v + bias[colg]);
          ((unsigned short*)Cout)[(size_t)row*512 + colg] = f2b(v);
        } else {
          ((float*)Cout)[(size_t)row*128 + col] = v;
        }
      }
    }
  }
}

// ---- layer1 attention scalars ----------------------------------------------
__global__ void k_s1(const float* __restrict__ nf, const float* __restrict__ C,
                     float* __restrict__ ss1, float* __restrict__ sd1){
  int t = blockIdx.x * 256 + threadIdx.x;
  if (t >= NN * 4) return;
  int n = t >> 2, h = t & 3;
  float s = 0.f, d = 0.f;
  for (int k = 0; k < FIN; ++k){
    float xv = nf[(size_t)n * FIN + k];
    s += xv * C[VS1 + k*4 + h];
    d += xv * C[VD1 + k*4 + h];
  }
  ss1[t] = s; sd1[t] = d;
}

// fused: leaky-relu -> exp (no max-shift; softmax is shift-invariant, |alpha|~O(5))
__global__ void k_alpha1(const int* __restrict__ esrc, const int* __restrict__ edst,
                         const int* __restrict__ eai, const float* __restrict__ ea,
                         const float* __restrict__ loopa, const float* __restrict__ ss1,
                         const float* __restrict__ sd1, const float* __restrict__ C,
                         float* __restrict__ al1, float* __restrict__ den1){
  int p = blockIdx.x * 256 + threadIdx.x;
  if (p >= ET) return;
  int s = esrc[p], d = edst[p], e = eai[p];
  float4 a = (e < NE) ? *(const float4*)&ea[(size_t)e * 4]
                      : *(const float4*)&loopa[(size_t)d * 4];
  #pragma unroll
  for (int h = 0; h < 4; ++h){
    float se = a.x*C[VE1+h] + a.y*C[VE1+4+h] + a.z*C[VE1+8+h] + a.w*C[VE1+12+h];
    float al = ss1[s*4+h] + sd1[d*4+h] + se;
    al = al > 0.f ? al : 0.2f * al;
    float ex = expf(al);
    al1[(size_t)p*4 + h] = ex;
    atomicAdd(&den1[d*4 + h], ex);
  }
}

// ---- layer1 aggregation in input space, bf16 out, K padded to 96 ------------
__global__ __launch_bounds__(256) void k_aggnf(const int* __restrict__ csr,
    const int* __restrict__ esrc, const float* __restrict__ al1,
    const float* __restrict__ den1, const float* __restrict__ nf,
    unsigned short* __restrict__ agg){
  int lane = threadIdx.x & 63, w = threadIdx.x >> 6;
  int n = blockIdx.x * 4 + w;
  if (n >= NN) return;
  float4 dn = *(const float4*)&den1[(size_t)n * 4];
  float i0 = 1.f/(dn.x+1e-16f), i1 = 1.f/(dn.y+1e-16f);
  float i2 = 1.f/(dn.z+1e-16f), i3 = 1.f/(dn.w+1e-16f);
  int off = csr[n], end = csr[n + 1];
  bool hi = lane < (FIN - 64);
  float a0=0,a1=0,a2=0,a3=0,b0=0,b1=0,b2=0,b3=0;
  for (int p = off; p < end; ++p){
    int s = esrc[p];
    float4 wv = *(const float4*)&al1[(size_t)p * 4];
    float v0 = nf[(size_t)s * FIN + lane];
    float v1 = hi ? nf[(size_t)s * FIN + 64 + lane] : 0.f;
    a0 += wv.x*v0; a1 += wv.y*v0; a2 += wv.z*v0; a3 += wv.w*v0;
    b0 += wv.x*v1; b1 += wv.y*v1; b2 += wv.z*v1; b3 += wv.w*v1;
  }
  size_t base = (size_t)n * KP1 + lane;
  constexpr size_t HS = (size_t)NN * KP1;
  agg[base]        = f2b(a0*i0); agg[base +   HS] = f2b(a1*i1);
  agg[base + 2*HS] = f2b(a2*i2); agg[base + 3*HS] = f2b(a3*i3);
  if (lane < 32){
    unsigned short z0 = f2b(hi ? b0*i0 : 0.f), z1 = f2b(hi ? b1*i1 : 0.f);
    unsigned short z2 = f2b(hi ? b2*i2 : 0.f), z3 = f2b(hi ? b3*i3 : 0.f);
    if (!hi){ z0 = z1 = z2 = z3 = 0; }
    agg[base + 64]        = z0; agg[base + 64 +   HS] = z1;
    agg[base + 64 + 2*HS] = z2; agg[base + 64 + 3*HS] = z3;
  }
}

// ---- layer2 attention scalars (x1 is bf16) ----------------------------------
__global__ void k_s2(const unsigned short* __restrict__ x1, const float* __restrict__ C,
                     float* __restrict__ ss2, float* __restrict__ sd2){
  int tid = threadIdx.x, lane = tid & 63;
  int n = blockIdx.x * 4 + (tid >> 6);
  if (n >= NN) return;
  uint4 xv = *(const uint4*)&x1[(size_t)n * 512 + lane * 8];
  float xf[8];
  xf[0] = b2f(xv.x & 0xffffu); xf[1] = b2f(xv.x >> 16);
  xf[2] = b2f(xv.y & 0xffffu); xf[3] = b2f(xv.y >> 16);
  xf[4] = b2f(xv.z & 0xffffu); xf[5] = b2f(xv.z >> 16);
  xf[6] = b2f(xv.w & 0xffffu); xf[7] = b2f(xv.w >> 16);
  float s = 0.f, d = 0.f;
  #pragma unroll
  for (int j = 0; j < 8; ++j){
    s += xf[j] * C[VS2 + lane*8 + j];
    d += xf[j] * C[VD2 + lane*8 + j];
  }
  for (int o = 32; o; o >>= 1){ s += __shfl_down(s, o); d += __shfl_down(d, o); }
  if (lane == 0){ ss2[n] = s; sd2[n] = d; }
}

__global__ void k_alpha2(const int* __restrict__ esrc, const int* __restrict__ edst,
                         const int* __restrict__ eai, const float* __restrict__ ea,
                         const float* __restrict__ loopa, const float* __restrict__ ss2,
                         const float* __restrict__ sd2, const float* __restrict__ C,
                         float* __restrict__ al2, float* __restrict__ den2){
  int p = blockIdx.x * 256 + threadIdx.x;
  if (p >= ET) return;
  int s = esrc[p], d = edst[p], e = eai[p];
  float4 a = (e < NE) ? *(const float4*)&ea[(size_t)e * 4]
                      : *(const float4*)&loopa[(size_t)d * 4];
  float se = a.x*C[VE2] + a.y*C[VE2+1] + a.z*C[VE2+2] + a.w*C[VE2+3];
  float al = ss2[s] + sd2[d] + se;
  al = al > 0.f ? al : 0.2f * al;
  float ex = expf(al);
  al2[p] = ex;
  atomicAdd(&den2[d], ex);
}

// ---- layer2 aggregation + GELU + LayerNorm + projections (fused) ------------
__global__ __launch_bounds__(128) void k_agg2(
    const int* __restrict__ csr, const int* __restrict__ esrc,
    const float* __restrict__ al2, const float* __restrict__ den2,
    const float* __restrict__ xs2, const float* __restrict__ b2,
    const float* __restrict__ lng, const float* __restrict__ lnb,
    const float* __restrict__ pw, const float* __restrict__ pb,
    const float* __restrict__ dwm, const float* __restrict__ dbv,
    float* __restrict__ out){
  int n = blockIdx.x, tid = threadIdx.x, lane = tid & 63, wv = tid >> 6;
  int off = csr[n], end = csr[n + 1];
  float invd = 1.f / (den2[n] + 1e-16f);
  float acc = 0.f;
  for (int p = off; p < end; ++p){
    int s = esrc[p];
    acc += al2[p] * xs2[(size_t)s * 128 + tid];
  }
  float g = gelu_exact(acc * invd + b2[tid]);
  __shared__ float red[2], red2[2], yl[128];
  float t = g;
  for (int o = 32; o; o >>= 1) t += __shfl_down(t, o);
  if (lane == 0) red[wv] = t;
  __syncthreads();
  float mu = (red[0] + red[1]) * (1.f / 128.f);
  float dv = g - mu;
  float q = dv * dv;
  for (int o = 32; o; o >>= 1) q += __shfl_down(q, o);
  if (lane == 0) red2[wv] = q;
  __syncthreads();
  float var = (red2[0] + red2[1]) * (1.f / 128.f);
  float y = dv * rsqrtf(var + 1e-5f) * lng[tid] + lnb[tid];
  yl[tid] = y;
  __syncthreads();
  if (tid < 8){
    float o1 = pb[tid];
    for (int d2 = 0; d2 < 128; ++d2) o1 += yl[d2] * pw[d2*8 + tid];
    out[(size_t)n*8 + tid] = o1;
  } else if (tid >= 64 && tid < 68){
    int j = tid - 64;
    float o2 = dbv[j];
    for (int d2 = 0; d2 < 128; ++d2) o2 += yl[d2] * dwm[d2*4 + j];
    out[(size_t)NN*8 + (size_t)n*4 + j] = o2;
  }
}

extern "C" void kernel_launch(void* const* d_in, const int* in_sizes, int n_in,
                              void* d_out, int out_size, void* d_ws, size_t ws_size,
                              hipStream_t stream){
  const float* nf  = (const float*)d_in[0];
  const int*   ei  = (const int*)  d_in[1];
  const float* ea  = (const float*)d_in[2];
  const float* W1  = (const float*)d_in[3];
  const float* as1 = (const float*)d_in[4];
  const float* ad1 = (const float*)d_in[5];
  const float* We1 = (const float*)d_in[6];
  const float* ae1 = (const float*)d_in[7];
  const float* b1  = (const float*)d_in[8];
  const float* W2  = (const float*)d_in[9];
  const float* as2 = (const float*)d_in[10];
  const float* ad2 = (const float*)d_in[11];
  const float* We2 = (const float*)d_in[12];
  const float* ae2 = (const float*)d_in[13];
  const float* b2  = (const float*)d_in[14];
  const float* lng = (const float*)d_in[15];
  const float* lnb = (const float*)d_in[16];
  const float* pw  = (const float*)d_in[17];
  const float* pb  = (const float*)d_in[18];
  const float* dw  = (const float*)d_in[19];
  const float* db  = (const float*)d_in[20];
  float* out = (float*)d_out;

  float* wf = (float*)d_ws;
  int*      cnt  = (int*)     (wf + CNT_O);
  int*      cur  = (int*)     (wf + CUR_O);
  float*    den1 =            (wf + DEN1_O);
  float*    den2 =            (wf + DEN2_O);
  float*    loopa=            (wf + LOOPA_O);
  int*      csr  = (int*)     (wf + CSR_O);
  int*      esrc = (int*)     (wf + ESRC_O);
  int*      edst = (int*)     (wf + EDST_O);
  int*      eai  = (int*)     (wf + EAI_O);
  float*    ss1  =            (wf + SS1_O);
  float*    sd1  =            (wf + SD1_O);
  float*    ss2  =            (wf + SS2_O);
  float*    sd2  =            (wf + SD2_O);
  float*    al1  =            (wf + AL1_O);
  float*    al2  =            (wf + AL2_O);
  float*    Cc   =            (wf + CST_O);
  unsigned short* W1t = (unsigned short*)(wf + W1T_O);
  unsigned short* W2t = (unsigned short*)(wf + W2T_O);
  unsigned short* agg = (unsigned short*)(wf + AGG_O);
  unsigned short* x1  = (unsigned short*)(wf + X1_O);
  float*    xs2  =            (wf + XS2_O);

  hipMemsetAsync(wf, 0, ZEND * 4, stream);
  k_prep<<<1, 512, 0, stream>>>(W1, as1, ad1, We1, ae1, W2, as2, ad2, We2, ae2, Cc);
  k_tw<<<(4*128*KP1 + 128*512 + 255) / 256, 256, 0, stream>>>(W1, W2, W1t, W2t);
  k_deg<<<(NE + 255) / 256, 256, 0, stream>>>(ei, ea, cnt, loopa);
  k_loopnorm<<<(NN + 255) / 256, 256, 0, stream>>>(cnt, loopa);
  k_scan<<<1, 1024, 0, stream>>>(cnt, csr);
  k_fill<<<(NE + 255) / 256, 256, 0, stream>>>(ei, csr, cur, esrc, edst, eai);
  k_self<<<(NN + 255) / 256, 256, 0, stream>>>(csr, cnt, esrc, edst, eai);
  k_s1<<<(NN * 4 + 255) / 256, 256, 0, stream>>>(nf, Cc, ss1, sd1);
  k_alpha1<<<(ET + 255) / 256, 256, 0, stream>>>(esrc, edst, eai, ea, loopa, ss1, sd1, Cc, al1, den1);
  k_aggnf<<<(NN + 3) / 4, 256, 0, stream>>>(csr, esrc, al1, den1, nf, agg);
  // layer-1: per head h, x1[:, h*128:(h+1)*128] = gelu(agg_h @ W1_h + b1_h), bf16 out
  k_mfma<true><<<dim3((NN + 127) / 128, 4), 256, 0, stream>>>(
      agg, KP1, (long)NN * KP1, W1t, (long)128 * KP1, x1, b1, NN, KP1);
  k_s2<<<(NN + 3) / 4, 256, 0, stream>>>(x1, Cc, ss2, sd2);
  // layer-2: xs2 = x1 @ W2, f32 out
  k_mfma<false><<<dim3((NN + 127) / 128, 1), 256, 0, stream>>>(
      x1, 512, 0, W2t, 0, xs2, nullptr, NN, 512);
  k_alpha2<<<(ET + 255) / 256, 256, 0, stream>>>(esrc, edst, eai, ea, loopa, ss2, sd2, Cc, al2, den2);
  k_agg2<<<NN, 128, 0, stream>>>(csr, esrc, al2, den2, xs2, b2, lng, lnb,
                                 pw, pb, dw, db, out);
}

// Round 4
// 498.915 us; speedup vs baseline: 2.4109x; 1.3848x over previous
//
#include <hip/hip_runtime.h>
#include <hip/hip_bf16.h>
#include <math.h>

#define NN 50000
#define NE 400000
#define FIN 70
#define EDIM 4
#define HIDD 128
#define NHEAD 4
constexpr int ET = NE + NN;
constexpr int KP1 = 96;           // layer-1 K padded (70 -> 96)
constexpr int NFP = 72;           // nf bf16 row pitch
constexpr int SCB = (NN + 255) / 256;   // scan blocks = 196

constexpr size_t al4(size_t x){ return (x + 3) & ~size_t(3); }
// ws offsets in 4-byte words
constexpr size_t CNT_O   = 0;                          // int[NN]   (zeroed)
constexpr size_t CUR_O   = al4(CNT_O + NN);            // int[NN]   (zeroed)
constexpr size_t LOOPA_O = al4(CUR_O + NN);            // f32[NN*4] (zeroed)
constexpr size_t ZEND    = al4(LOOPA_O + (size_t)NN*4);
constexpr size_t CSR_O   = ZEND;                       // int[NN+1]
constexpr size_t BSUM_O  = al4(CSR_O + NN + 1);        // int[256]
constexpr size_t BOFF_O  = al4(BSUM_O + 256);          // int[256]
constexpr size_t EPK_O   = al4(BOFF_O + 256);          // int4[ET]
constexpr size_t SS1_O   = al4(EPK_O + (size_t)ET*4);  // f32[NN*4]
constexpr size_t SD1_O   = al4(SS1_O + (size_t)NN*4);
constexpr size_t SS2_O   = al4(SD1_O + (size_t)NN*4);  // f32[NN]
constexpr size_t SD2_O   = al4(SS2_O + NN);
constexpr size_t AL1_O   = al4(SD2_O + NN);            // f32[ET*4] (CSR order, holds ex)
constexpr size_t AL2_O   = al4(AL1_O + (size_t)ET*4);  // f32[ET]
constexpr size_t CST_O   = al4(AL2_O + ET);            // f32[2048]
constexpr size_t W1T_O   = al4(CST_O + 2048);          // bf16[4][128][96]
constexpr size_t W2T_O   = al4(W1T_O + 4*128*KP1/2);   // bf16[128][512]
constexpr size_t NFB_O   = al4(W2T_O + 128*512/2);     // bf16[NN][72]
constexpr size_t AGG_O   = al4(NFB_O + (size_t)NN*NFP/2);   // bf16[4][NN][96]
constexpr size_t X1_O    = al4(AGG_O + (size_t)4*NN*KP1/2); // bf16[NN][512]
constexpr size_t XS2_O   = al4(X1_O + (size_t)NN*512/2);    // bf16[NN][128]

// const-block sub-offsets (words, within CST)
constexpr int VS1 = 0;    // [70][4]
constexpr int VD1 = 320;  // [70][4]
constexpr int VE1 = 640;  // [4][4]
constexpr int VE2 = 656;  // [4]
constexpr int VS2 = 704;  // [512]
constexpr int VD2 = 1216; // [512]

typedef short s8v __attribute__((ext_vector_type(8)));
typedef float f4v __attribute__((ext_vector_type(4)));

__device__ __forceinline__ float gelu_exact(float x){
  return 0.5f * x * (1.f + erff(x * 0.70710678118654752440f));
}
__device__ __forceinline__ unsigned short f2b(float v){
  __hip_bfloat16 b = __float2bfloat16(v);
  return *(unsigned short*)&b;
}
__device__ __forceinline__ float b2f(unsigned u_lo16){
  return __uint_as_float(u_lo16 << 16);
}
__device__ __forceinline__ unsigned pk2(float lo, float hi){
  return (unsigned)f2b(lo) | ((unsigned)f2b(hi) << 16);
}

// ---- self-loop prep ---------------------------------------------------------
__global__ void k_deg(const int* __restrict__ ei, const float* __restrict__ ea,
                      int* __restrict__ cnt, float* __restrict__ loopa){
  int e = blockIdx.x * 256 + threadIdx.x;
  if (e >= NE) return;
  int d = ei[NE + e];
  atomicAdd(&cnt[d], 1);
  float4 a = *(const float4*)&ea[(size_t)e * 4];
  atomicAdd(&loopa[d*4+0], a.x);
  atomicAdd(&loopa[d*4+1], a.y);
  atomicAdd(&loopa[d*4+2], a.z);
  atomicAdd(&loopa[d*4+3], a.w);
}

__global__ void k_loopnorm(const int* __restrict__ cnt, float* __restrict__ loopa){
  int n = blockIdx.x * 256 + threadIdx.x;
  if (n >= NN) return;
  int c = cnt[n];
  float inv = 1.f / (float)(c > 1 ? c : 1);
  loopa[n*4+0] *= inv; loopa[n*4+1] *= inv;
  loopa[n*4+2] *= inv; loopa[n*4+3] *= inv;
}

// ---- CSR build: 3-phase scan of (cnt+1) -------------------------------------
__global__ void k_scan1(const int* __restrict__ cnt, int* __restrict__ bsum){
  __shared__ int ws[4];
  int t = threadIdx.x, lane = t & 63, w = t >> 6;
  int i = blockIdx.x * 256 + t;
  int v = (i < NN) ? cnt[i] + 1 : 0;
  for (int o = 32; o; o >>= 1) v += __shfl_down(v, o);
  if (lane == 0) ws[w] = v;
  __syncthreads();
  if (t == 0) bsum[blockIdx.x] = ws[0] + ws[1] + ws[2] + ws[3];
}

__global__ void k_scan2(const int* __restrict__ bsum, int* __restrict__ boff){
  __shared__ int ws[4];
  int t = threadIdx.x, lane = t & 63, w = t >> 6;
  int v = (t < SCB) ? bsum[t] : 0;
  int x = v;
  #pragma unroll
  for (int o = 1; o < 64; o <<= 1){ int u = __shfl_up(x, o); if (lane >= o) x += u; }
  if (lane == 63) ws[w] = x;
  __syncthreads();
  if (w == 0 && lane < 4){
    int y = ws[lane];
    #pragma unroll
    for (int o = 1; o < 4; o <<= 1){ int u = __shfl_up(y, o); if (lane >= o) y += u; }
    ws[lane] = y;
  }
  __syncthreads();
  int incl = x + (w > 0 ? ws[w - 1] : 0);
  if (t < SCB) boff[t] = incl - v;
}

__global__ void k_scan3(const int* __restrict__ cnt, const int* __restrict__ boff,
                        int* __restrict__ csr){
  __shared__ int ws[4];
  int t = threadIdx.x, lane = t & 63, w = t >> 6;
  int i = blockIdx.x * 256 + t;
  int v = (i < NN) ? cnt[i] + 1 : 0;
  int x = v;
  #pragma unroll
  for (int o = 1; o < 64; o <<= 1){ int u = __shfl_up(x, o); if (lane >= o) x += u; }
  if (lane == 63) ws[w] = x;
  __syncthreads();
  if (w == 0 && lane < 4){
    int y = ws[lane];
    #pragma unroll
    for (int o = 1; o < 4; o <<= 1){ int u = __shfl_up(y, o); if (lane >= o) y += u; }
    ws[lane] = y;
  }
  __syncthreads();
  if (i < NN) csr[i + 1] = boff[blockIdx.x] + (w > 0 ? ws[w - 1] : 0) + x;
  if (i == 0) csr[0] = 0;
}

__global__ void k_fill(const int* __restrict__ ei, const int* __restrict__ csr,
                       int* __restrict__ cur, int4* __restrict__ epack){
  int e = blockIdx.x * 256 + threadIdx.x;
  if (e >= NE) return;
  int s = ei[e], d = ei[NE + e];
  int p = csr[d] + atomicAdd(&cur[d], 1);
  epack[p] = make_int4(s, d, e, 0);
}

__global__ void k_self(const int* __restrict__ csr, const int* __restrict__ cnt,
                       int4* __restrict__ epack){
  int n = blockIdx.x * 256 + threadIdx.x;
  if (n >= NN) return;
  epack[csr[n] + cnt[n]] = make_int4(n, n, NE + n, 0);
}

// ---- tiny weight pre-reductions --------------------------------------------
__global__ void k_prep(const float* __restrict__ W1, const float* __restrict__ as1,
                       const float* __restrict__ ad1, const float* __restrict__ We1,
                       const float* __restrict__ ae1, const float* __restrict__ W2,
                       const float* __restrict__ as2, const float* __restrict__ ad2,
                       const float* __restrict__ We2, const float* __restrict__ ae2,
                       float* __restrict__ C){
  int t = threadIdx.x;                       // block of 512
  if (t < 280){
    int k = t >> 2, h = t & 3;
    float s = 0.f, d = 0.f;
    for (int dd = 0; dd < 128; ++dd){
      float w = W1[k*512 + h*128 + dd];
      s += w * as1[h*128 + dd];
      d += w * ad1[h*128 + dd];
    }
    C[VS1 + t] = s; C[VD1 + t] = d;
  }
  if (t < 16){
    int k = t >> 2, h = t & 3;
    float s = 0.f;
    for (int dd = 0; dd < 128; ++dd) s += We1[k*512 + h*128 + dd] * ae1[h*128 + dd];
    C[VE1 + t] = s;
  }
  if (t < 4){
    float s = 0.f;
    for (int dd = 0; dd < 128; ++dd) s += We2[t*128 + dd] * ae2[dd];
    C[VE2 + t] = s;
  }
  {
    float s = 0.f, d = 0.f;
    for (int dd = 0; dd < 128; ++dd){
      float w = W2[t*128 + dd];
      s += w * as2[dd];
      d += w * ad2[dd];
    }
    C[VS2 + t] = s; C[VD2 + t] = d;
  }
}

// ---- transpose + bf16-cast weights -----------------------------------------
__global__ void k_tw(const float* __restrict__ W1, const float* __restrict__ W2,
                     unsigned short* __restrict__ W1t, unsigned short* __restrict__ W2t){
  int i = blockIdx.x * 256 + threadIdx.x;
  if (i < 4*128*KP1){
    int k = i % KP1, n = (i / KP1) & 127, h = i / (KP1*128);
    float v = (k < FIN) ? W1[k*512 + h*128 + n] : 0.f;
    W1t[i] = f2b(v);
  } else {
    int j = i - 4*128*KP1;
    if (j < 128*512){
      int k = j & 511, n = j >> 9;
      W2t[j] = f2b(W2[k*128 + n]);
    }
  }
}

// ---- nf -> bf16 copy, pitch 72, pad zeros ----------------------------------
__global__ void k_cnf(const float* __restrict__ nf, unsigned short* __restrict__ nfb){
  int i = blockIdx.x * 256 + threadIdx.x;
  if (i >= NN * NFP) return;
  int n = i / NFP, c = i - n * NFP;
  nfb[i] = (c < FIN) ? f2b(nf[(size_t)n * FIN + c]) : (unsigned short)0;
}

// ---- MFMA GEMM: C[M,128] = A[M,KP] @ Bt^T, 128x128 tile, 4 waves ------------
// MODE 1: x1 bf16 out with gelu(acc+bias) at col z*128 (pitch 512)
// MODE 2: bf16 out, pitch 128
template<int MODE>
__global__ __launch_bounds__(256) void k_mfma(
    const unsigned short* __restrict__ A, int lda, long aSz,
    const unsigned short* __restrict__ Bt, long bSz,
    void* __restrict__ Cout, const float* __restrict__ bias,
    int M, int KP){
  int z = blockIdx.y;
  A  += (size_t)z * aSz;
  Bt += (size_t)z * bSz;
  __shared__ unsigned short As[128 * 40];   // pitch 40 bf16 (80 B)
  __shared__ unsigned short Bs[128 * 40];
  int tid = threadIdx.x, lane = tid & 63, w = tid >> 6;
  int wm = w & 1, wn = w >> 1;
  int row0 = blockIdx.x * 128;
  f4v acc[4][4] = {};
  int r4 = tid >> 2, c4 = tid & 3;
  for (int k0 = 0; k0 < KP; k0 += 32){
    #pragma unroll
    for (int half = 0; half < 2; ++half){
      int r = r4 + half * 64;
      int gr = row0 + r;
      uint4 va = make_uint4(0,0,0,0);
      if (gr < M) va = *(const uint4*)&A[(size_t)gr * lda + k0 + c4*8];
      *(uint4*)&As[r*40 + c4*8] = va;
      uint4 vb = *(const uint4*)&Bt[(size_t)r * lda + k0 + c4*8];
      *(uint4*)&Bs[r*40 + c4*8] = vb;
    }
    __syncthreads();
    s8v af[4], bf[4];
    #pragma unroll
    for (int i = 0; i < 4; ++i){
      af[i] = *(const s8v*)&As[(wm*64 + i*16 + (lane & 15))*40 + (lane >> 4)*8];
      bf[i] = *(const s8v*)&Bs[(wn*64 + i*16 + (lane & 15))*40 + (lane >> 4)*8];
    }
    #pragma unroll
    for (int mi = 0; mi < 4; ++mi)
      #pragma unroll
      for (int ni = 0; ni < 4; ++ni)
        acc[mi][ni] = __builtin_amdgcn_mfma_f32_16x16x32_bf16(af[mi], bf[ni], acc[mi][ni], 0, 0, 0);
    __syncthreads();
  }
  int cq = lane & 15, rq = lane >> 4;
  #pragma unroll
  for (int mi = 0; mi < 4; ++mi){
    #pragma unroll
    for (int r = 0; r < 4; ++r){
      int row = row0 + wm*64 + mi*16 + rq*4 + r;
      if (row >= M) continue;
      #pragma unroll
      for (int ni = 0; ni < 4; ++ni){
        int col = wn*64 + ni*16 + cq;
        float v = acc[mi][ni][r];
        if (MODE == 1){
          int colg = z*128 + col;
          v = gelu_exact(v + bias[colg]);
          ((unsigned short*)Cout)[(size_t)row*512 + colg] = f2b(v);
        } else {
          ((unsigned short*)Cout)[(size_t)row*128 + col] = f2b(v);
        }
      }
    }
  }
}

// ---- layer1 attention scalars ----------------------------------------------
__global__ void k_s1(const float* __restrict__ nf, const float* __restrict__ C,
                     float* __restrict__ ss1, float* __restrict__ sd1){
  int t = blockIdx.x * 256 + threadIdx.x;
  if (t >= NN * 4) return;
  int n = t >> 2, h = t & 3;
  float s = 0.f, d = 0.f;
  for (int k = 0; k < FIN; ++k){
    float xv = nf[(size_t)n * FIN + k];
    s += xv * C[VS1 + k*4 + h];
    d += xv * C[VD1 + k*4 + h];
  }
  ss1[t] = s; sd1[t] = d;
}

// leaky-relu -> exp; no atomics (den computed inline by aggregators)
__global__ void k_alpha1(const int4* __restrict__ epack, const float* __restrict__ ea,
                         const float* __restrict__ loopa, const float* __restrict__ ss1,
                         const float* __restrict__ sd1, const float* __restrict__ C,
                         float* __restrict__ al1){
  int p = blockIdx.x * 256 + threadIdx.x;
  if (p >= ET) return;
  int4 pk = epack[p];
  int s = pk.x, d = pk.y, e = pk.z;
  float4 a = (e < NE) ? *(const float4*)&ea[(size_t)e * 4]
                      : *(const float4*)&loopa[(size_t)d * 4];
  float4 o;
  #pragma unroll
  for (int h = 0; h < 4; ++h){
    float se = a.x*C[VE1+h] + a.y*C[VE1+4+h] + a.z*C[VE1+8+h] + a.w*C[VE1+12+h];
    float al = ss1[s*4+h] + sd1[d*4+h] + se;
    al = al > 0.f ? al : 0.2f * al;
    (&o.x)[h] = expf(al);
  }
  *(float4*)&al1[(size_t)p*4] = o;
}

// ---- layer1 aggregation: wave per node, bf16 nf gather ----------------------
__global__ __launch_bounds__(256) void k_aggnf(const int* __restrict__ csr,
    const int* __restrict__ epk, const float* __restrict__ al1,
    const unsigned short* __restrict__ nfb, unsigned short* __restrict__ agg){
  int lane = threadIdx.x & 63, w = threadIdx.x >> 6;
  int n = blockIdx.x * 4 + w;
  if (n >= NN) return;
  int off = csr[n], end = csr[n + 1];
  int col = lane * 2;
  bool act = lane < 36;                 // covers 72 cols (incl. zero pad 70,71)
  float d0=0,d1=0,d2=0,d3=0;
  float a00=0,a01=0,a10=0,a11=0,a20=0,a21=0,a30=0,a31=0;
  for (int p = off; p < end; ++p){
    int s = epk[(size_t)p * 4];         // .x only
    float4 wv = *(const float4*)&al1[(size_t)p * 4];
    d0 += wv.x; d1 += wv.y; d2 += wv.z; d3 += wv.w;
    if (act){
      unsigned u = *(const unsigned*)&nfb[(size_t)s * NFP + col];
      float v0 = b2f(u & 0xffffu), v1 = b2f(u >> 16);
      a00 += wv.x*v0; a01 += wv.x*v1;
      a10 += wv.y*v0; a11 += wv.y*v1;
      a20 += wv.z*v0; a21 += wv.z*v1;
      a30 += wv.w*v0; a31 += wv.w*v1;
    }
  }
  float i0 = 1.f/(d0+1e-16f), i1 = 1.f/(d1+1e-16f);
  float i2 = 1.f/(d2+1e-16f), i3 = 1.f/(d3+1e-16f);
  constexpr size_t HS = (size_t)NN * KP1;
  size_t base = (size_t)n * KP1 + col;
  if (act){
    *(unsigned*)&agg[base]        = pk2(a00*i0, a01*i0);
    *(unsigned*)&agg[base +   HS] = pk2(a10*i1, a11*i1);
    *(unsigned*)&agg[base + 2*HS] = pk2(a20*i2, a21*i2);
    *(unsigned*)&agg[base + 3*HS] = pk2(a30*i3, a31*i3);
  } else if (lane < 48){                // zero cols 72..95
    *(unsigned*)&agg[base]        = 0u;
    *(unsigned*)&agg[base +   HS] = 0u;
    *(unsigned*)&agg[base + 2*HS] = 0u;
    *(unsigned*)&agg[base + 3*HS] = 0u;
  }
}

// ---- layer2 attention scalars (x1 is bf16) ----------------------------------
__global__ void k_s2(const unsigned short* __restrict__ x1, const float* __restrict__ C,
                     float* __restrict__ ss2, float* __restrict__ sd2){
  int tid = threadIdx.x, lane = tid & 63;
  int n = blockIdx.x * 4 + (tid >> 6);
  if (n >= NN) return;
  uint4 xv = *(const uint4*)&x1[(size_t)n * 512 + lane * 8];
  float xf[8];
  xf[0] = b2f(xv.x & 0xffffu); xf[1] = b2f(xv.x >> 16);
  xf[2] = b2f(xv.y & 0xffffu); xf[3] = b2f(xv.y >> 16);
  xf[4] = b2f(xv.z & 0xffffu); xf[5] = b2f(xv.z >> 16);
  xf[6] = b2f(xv.w & 0xffffu); xf[7] = b2f(xv.w >> 16);
  float s = 0.f, d = 0.f;
  #pragma unroll
  for (int j = 0; j < 8; ++j){
    s += xf[j] * C[VS2 + lane*8 + j];
    d += xf[j] * C[VD2 + lane*8 + j];
  }
  for (int o = 32; o; o >>= 1){ s += __shfl_down(s, o); d += __shfl_down(d, o); }
  if (lane == 0){ ss2[n] = s; sd2[n] = d; }
}

__global__ void k_alpha2(const int4* __restrict__ epack, const float* __restrict__ ea,
                         const float* __restrict__ loopa, const float* __restrict__ ss2,
                         const float* __restrict__ sd2, const float* __restrict__ C,
                         float* __restrict__ al2){
  int p = blockIdx.x * 256 + threadIdx.x;
  if (p >= ET) return;
  int4 pk = epack[p];
  int s = pk.x, d = pk.y, e = pk.z;
  float4 a = (e < NE) ? *(const float4*)&ea[(size_t)e * 4]
                      : *(const float4*)&loopa[(size_t)d * 4];
  float se = a.x*C[VE2] + a.y*C[VE2+1] + a.z*C[VE2+2] + a.w*C[VE2+3];
  float al = ss2[s] + sd2[d] + se;
  al = al > 0.f ? al : 0.2f * al;
  al2[p] = expf(al);
}

// ---- layer2 aggregation (wave/node, bf16 gather) + GELU + LN + projections --
__global__ __launch_bounds__(256) void k_agg2(
    const int* __restrict__ csr, const int* __restrict__ epk,
    const float* __restrict__ al2, const unsigned short* __restrict__ xs2b,
    const float* __restrict__ b2, const float* __restrict__ lng,
    const float* __restrict__ lnb, const float* __restrict__ pw,
    const float* __restrict__ pb, const float* __restrict__ dwm,
    const float* __restrict__ dbv, float* __restrict__ out){
  int lane = threadIdx.x & 63, w = threadIdx.x >> 6;
  int n = blockIdx.x * 4 + w;
  if (n >= NN) return;
  int off = csr[n], end = csr[n + 1];
  int c0 = lane * 2;
  float acc0 = 0.f, acc1 = 0.f, den = 0.f;
  for (int p = off; p < end; ++p){
    int s = epk[(size_t)p * 4];
    float wv = al2[p];
    den += wv;
    unsigned u = *(const unsigned*)&xs2b[(size_t)s * 128 + c0];
    acc0 += wv * b2f(u & 0xffffu);
    acc1 += wv * b2f(u >> 16);
  }
  float invd = 1.f / (den + 1e-16f);
  float g0 = gelu_exact(acc0 * invd + b2[c0]);
  float g1 = gelu_exact(acc1 * invd + b2[c0 + 1]);
  float s = g0 + g1;
  #pragma unroll
  for (int o = 32; o; o >>= 1) s += __shfl_xor(s, o);
  float mu = s * (1.f / 128.f);
  float e0 = g0 - mu, e1 = g1 - mu;
  float q = e0*e0 + e1*e1;
  #pragma unroll
  for (int o = 32; o; o >>= 1) q += __shfl_xor(q, o);
  float rstd = rsqrtf(q * (1.f / 128.f) + 1e-5f);
  float y0 = e0 * rstd * lng[c0] + lnb[c0];
  float y1 = e1 * rstd * lng[c0 + 1] + lnb[c0 + 1];
  float pr[12];
  #pragma unroll
  for (int j = 0; j < 8; ++j) pr[j] = y0 * pw[c0*8 + j] + y1 * pw[(c0+1)*8 + j];
  #pragma unroll
  for (int j = 0; j < 4; ++j) pr[8+j] = y0 * dwm[c0*4 + j] + y1 * dwm[(c0+1)*4 + j];
  #pragma unroll
  for (int o = 32; o; o >>= 1)
    #pragma unroll
    for (int j = 0; j < 12; ++j) pr[j] += __shfl_xor(pr[j], o);
  if (lane == 0){
    #pragma unroll
    for (int j = 0; j < 8; ++j) out[(size_t)n*8 + j] = pr[j] + pb[j];
    #pragma unroll
    for (int j = 0; j < 4; ++j) out[(size_t)NN*8 + (size_t)n*4 + j] = pr[8+j] + dbv[j];
  }
}

extern "C" void kernel_launch(void* const* d_in, const int* in_sizes, int n_in,
                              void* d_out, int out_size, void* d_ws, size_t ws_size,
                              hipStream_t stream){
  const float* nf  = (const float*)d_in[0];
  const int*   ei  = (const int*)  d_in[1];
  const float* ea  = (const float*)d_in[2];
  const float* W1  = (const float*)d_in[3];
  const float* as1 = (const float*)d_in[4];
  const float* ad1 = (const float*)d_in[5];
  const float* We1 = (const float*)d_in[6];
  const float* ae1 = (const float*)d_in[7];
  const float* b1  = (const float*)d_in[8];
  const float* W2  = (const float*)d_in[9];
  const float* as2 = (const float*)d_in[10];
  const float* ad2 = (const float*)d_in[11];
  const float* We2 = (const float*)d_in[12];
  const float* ae2 = (const float*)d_in[13];
  const float* b2  = (const float*)d_in[14];
  const float* lng = (const float*)d_in[15];
  const float* lnb = (const float*)d_in[16];
  const float* pw  = (const float*)d_in[17];
  const float* pb  = (const float*)d_in[18];
  const float* dw  = (const float*)d_in[19];
  const float* db  = (const float*)d_in[20];
  float* out = (float*)d_out;

  float* wf = (float*)d_ws;
  int*      cnt  = (int*)     (wf + CNT_O);
  int*      cur  = (int*)     (wf + CUR_O);
  float*    loopa=            (wf + LOOPA_O);
  int*      csr  = (int*)     (wf + CSR_O);
  int*      bsum = (int*)     (wf + BSUM_O);
  int*      boff = (int*)     (wf + BOFF_O);
  int4*     epack= (int4*)    (wf + EPK_O);
  float*    ss1  =            (wf + SS1_O);
  float*    sd1  =            (wf + SD1_O);
  float*    ss2  =            (wf + SS2_O);
  float*    sd2  =            (wf + SD2_O);
  float*    al1  =            (wf + AL1_O);
  float*    al2  =            (wf + AL2_O);
  float*    Cc   =            (wf + CST_O);
  unsigned short* W1t = (unsigned short*)(wf + W1T_O);
  unsigned short* W2t = (unsigned short*)(wf + W2T_O);
  unsigned short* nfb = (unsigned short*)(wf + NFB_O);
  unsigned short* agg = (unsigned short*)(wf + AGG_O);
  unsigned short* x1  = (unsigned short*)(wf + X1_O);
  unsigned short* xs2b= (unsigned short*)(wf + XS2_O);

  hipMemsetAsync(wf, 0, ZEND * 4, stream);
  k_prep<<<1, 512, 0, stream>>>(W1, as1, ad1, We1, ae1, W2, as2, ad2, We2, ae2, Cc);
  k_tw<<<(4*128*KP1 + 128*512 + 255) / 256, 256, 0, stream>>>(W1, W2, W1t, W2t);
  k_cnf<<<((size_t)NN*NFP + 255) / 256, 256, 0, stream>>>(nf, nfb);
  k_deg<<<(NE + 255) / 256, 256, 0, stream>>>(ei, ea, cnt, loopa);
  k_loopnorm<<<(NN + 255) / 256, 256, 0, stream>>>(cnt, loopa);
  k_scan1<<<SCB, 256, 0, stream>>>(cnt, bsum);
  k_scan2<<<1, 256, 0, stream>>>(bsum, boff);
  k_scan3<<<SCB, 256, 0, stream>>>(cnt, boff, csr);
  k_fill<<<(NE + 255) / 256, 256, 0, stream>>>(ei, csr, cur, epack);
  k_self<<<(NN + 255) / 256, 256, 0, stream>>>(csr, cnt, epack);
  k_s1<<<(NN * 4 + 255) / 256, 256, 0, stream>>>(nf, Cc, ss1, sd1);
  k_alpha1<<<(ET + 255) / 256, 256, 0, stream>>>(epack, ea, loopa, ss1, sd1, Cc, al1);
  k_aggnf<<<(NN + 3) / 4, 256, 0, stream>>>(csr, (const int*)epack, al1, nfb, agg);
  // layer-1: per head h, x1[:, h*128:(h+1)*128] = gelu(agg_h @ W1_h + b1_h), bf16 out
  k_mfma<1><<<dim3((NN + 127) / 128, 4), 256, 0, stream>>>(
      agg, KP1, (long)NN * KP1, W1t, (long)128 * KP1, x1, b1, NN, KP1);
  k_s2<<<(NN + 3) / 4, 256, 0, stream>>>(x1, Cc, ss2, sd2);
  // layer-2: xs2b = bf16(x1 @ W2)
  k_mfma<2><<<dim3((NN + 127) / 128, 1), 256, 0, stream>>>(
      x1, 512, 0, W2t, 0, xs2b, nullptr, NN, 512);
  k_alpha2<<<(ET + 255) / 256, 256, 0, stream>>>(epack, ea, loopa, ss2, sd2, Cc, al2);
  k_agg2<<<(NN + 3) / 4, 256, 0, stream>>>(csr, (const int*)epack, al2, xs2b, b2,
                                           lng, lnb, pw, pb, dw, db, out);
}

// Round 5
// 446.370 us; speedup vs baseline: 2.6947x; 1.1177x over previous
//
#include <hip/hip_runtime.h>
#include <hip/hip_bf16.h>
#include <math.h>

#define NN 50000
#define NE 400000
#define FIN 70
#define EDIM 4
#define HIDD 128
#define NHEAD 4
constexpr int ET = NE + NN;
constexpr int KP1 = 96;           // layer-1 K padded (70 -> 96)
constexpr int NFP = 72;           // nf bf16 row pitch
constexpr int SCB = (NN + 255) / 256;   // scan blocks = 196

constexpr size_t al4(size_t x){ return (x + 3) & ~size_t(3); }
// ws offsets in 4-byte words
constexpr size_t CNT_O   = 0;                          // int[NN] (zeroed each call)
constexpr size_t ZEND    = al4(CNT_O + NN);
constexpr size_t CSR_O   = ZEND;                       // int[NN+1]
constexpr size_t BSUM_O  = al4(CSR_O + NN + 1);        // int[256]
constexpr size_t BOFF_O  = al4(BSUM_O + 256);          // int[256]
constexpr size_t ESRC_O  = al4(BOFF_O + 256);          // int[ET]       (CSR order)
constexpr size_t EAB_O   = al4(ESRC_O + ET);           // float4[ET]    (CSR order)
constexpr size_t SS1_O   = al4(EAB_O + (size_t)ET*4);  // f32[NN*4]
constexpr size_t SD1_O   = al4(SS1_O + (size_t)NN*4);
constexpr size_t SS2_O   = al4(SD1_O + (size_t)NN*4);  // f32[NN]
constexpr size_t SD2_O   = al4(SS2_O + NN);
constexpr size_t CST_O   = al4(SD2_O + NN);            // f32[2048]
constexpr size_t W1T_O   = al4(CST_O + 2048);          // bf16[4][128][96]
constexpr size_t W2T_O   = al4(W1T_O + 4*128*KP1/2);   // bf16[128][512]
constexpr size_t NFB_O   = al4(W2T_O + 128*512/2);     // bf16[NN][72]
constexpr size_t AGG_O   = al4(NFB_O + (size_t)NN*NFP/2);   // bf16[4][NN][96]
constexpr size_t X1_O    = al4(AGG_O + (size_t)4*NN*KP1/2); // bf16[NN][512]
constexpr size_t XS2_O   = al4(X1_O + (size_t)NN*512/2);    // bf16[NN][128]

// const-block sub-offsets (words, within CST)
constexpr int VS1 = 0;    // [70][4]
constexpr int VD1 = 320;  // [70][4]
constexpr int VE1 = 640;  // [4][4]
constexpr int VE2 = 656;  // [4]
constexpr int VS2 = 704;  // [512]
constexpr int VD2 = 1216; // [512]

typedef short s8v __attribute__((ext_vector_type(8)));
typedef float f4v __attribute__((ext_vector_type(4)));

__device__ __forceinline__ float gelu_exact(float x){
  return 0.5f * x * (1.f + erff(x * 0.70710678118654752440f));
}
__device__ __forceinline__ unsigned short f2b(float v){
  __hip_bfloat16 b = __float2bfloat16(v);
  return *(unsigned short*)&b;
}
__device__ __forceinline__ float b2f(unsigned u_lo16){
  return __uint_as_float(u_lo16 << 16);
}
__device__ __forceinline__ unsigned pk2(float lo, float hi){
  return (unsigned)f2b(lo) | ((unsigned)f2b(hi) << 16);
}
__device__ __forceinline__ float lrelu(float x){ return x > 0.f ? x : 0.2f * x; }

// ---- degree histogram: ONE atomic per edge ----------------------------------
__global__ void k_deg(const int* __restrict__ ei, int* __restrict__ cnt){
  int e = blockIdx.x * 256 + threadIdx.x;
  if (e >= NE) return;
  atomicAdd(&cnt[ei[NE + e]], 1);
}

// ---- CSR build: 3-phase scan of (cnt+1) -------------------------------------
__global__ void k_scan1(const int* __restrict__ cnt, int* __restrict__ bsum){
  __shared__ int ws[4];
  int t = threadIdx.x, lane = t & 63, w = t >> 6;
  int i = blockIdx.x * 256 + t;
  int v = (i < NN) ? cnt[i] + 1 : 0;
  for (int o = 32; o; o >>= 1) v += __shfl_down(v, o);
  if (lane == 0) ws[w] = v;
  __syncthreads();
  if (t == 0) bsum[blockIdx.x] = ws[0] + ws[1] + ws[2] + ws[3];
}

__global__ void k_scan2(const int* __restrict__ bsum, int* __restrict__ boff){
  __shared__ int ws[4];
  int t = threadIdx.x, lane = t & 63, w = t >> 6;
  int v = (t < SCB) ? bsum[t] : 0;
  int x = v;
  #pragma unroll
  for (int o = 1; o < 64; o <<= 1){ int u = __shfl_up(x, o); if (lane >= o) x += u; }
  if (lane == 63) ws[w] = x;
  __syncthreads();
  if (w == 0 && lane < 4){
    int y = ws[lane];
    #pragma unroll
    for (int o = 1; o < 4; o <<= 1){ int u = __shfl_up(y, o); if (lane >= o) y += u; }
    ws[lane] = y;
  }
  __syncthreads();
  int incl = x + (w > 0 ? ws[w - 1] : 0);
  if (t < SCB) boff[t] = incl - v;
}

__global__ void k_scan3(const int* __restrict__ cnt, const int* __restrict__ boff,
                        int* __restrict__ csr){
  __shared__ int ws[4];
  int t = threadIdx.x, lane = t & 63, w = t >> 6;
  int i = blockIdx.x * 256 + t;
  int v = (i < NN) ? cnt[i] + 1 : 0;
  int x = v;
  #pragma unroll
  for (int o = 1; o < 64; o <<= 1){ int u = __shfl_up(x, o); if (lane >= o) x += u; }
  if (lane == 63) ws[w] = x;
  __syncthreads();
  if (w == 0 && lane < 4){
    int y = ws[lane];
    #pragma unroll
    for (int o = 1; o < 4; o <<= 1){ int u = __shfl_up(y, o); if (lane >= o) y += u; }
    ws[lane] = y;
  }
  __syncthreads();
  if (i < NN) csr[i + 1] = boff[blockIdx.x] + (w > 0 ? ws[w - 1] : 0) + x;
  if (i == 0) csr[0] = 0;
}

// ---- fill CSR slots: esrc + CSR-ordered edge attr; consumes cnt -> 0 --------
__global__ void k_fill(const int* __restrict__ ei, const float* __restrict__ ea,
                       const int* __restrict__ csr, int* __restrict__ cnt,
                       int* __restrict__ esrc, float4* __restrict__ eab){
  int e = blockIdx.x * 256 + threadIdx.x;
  if (e >= NE) return;
  int s = ei[e], d = ei[NE + e];
  int r = atomicSub(&cnt[d], 1);        // r in [deg..1]
  int p = csr[d] + r - 1;
  esrc[p] = s;
  eab[p] = *(const float4*)&ea[(size_t)e * 4];
}

// ---- per-node: self-loop attr = mean of real-edge attrs; self esrc ----------
__global__ void k_loopself(const int* __restrict__ csr, int* __restrict__ esrc,
                           float4* __restrict__ eab){
  int n = blockIdx.x * 256 + threadIdx.x;
  if (n >= NN) return;
  int a = csr[n], b = csr[n + 1];
  int deg = b - a - 1;
  float4 s = make_float4(0.f, 0.f, 0.f, 0.f);
  for (int p = a; p < b - 1; ++p){
    float4 v = eab[p];
    s.x += v.x; s.y += v.y; s.z += v.z; s.w += v.w;
  }
  float inv = 1.f / (float)(deg > 1 ? deg : 1);
  eab[b - 1] = make_float4(s.x*inv, s.y*inv, s.z*inv, s.w*inv);
  esrc[b - 1] = n;
}

// ---- tiny weight pre-reductions --------------------------------------------
__global__ void k_prep(const float* __restrict__ W1, const float* __restrict__ as1,
                       const float* __restrict__ ad1, const float* __restrict__ We1,
                       const float* __restrict__ ae1, const float* __restrict__ W2,
                       const float* __restrict__ as2, const float* __restrict__ ad2,
                       const float* __restrict__ We2, const float* __restrict__ ae2,
                       float* __restrict__ C){
  int t = threadIdx.x;                       // block of 512
  if (t < 280){
    int k = t >> 2, h = t & 3;
    float s = 0.f, d = 0.f;
    for (int dd = 0; dd < 128; ++dd){
      float w = W1[k*512 + h*128 + dd];
      s += w * as1[h*128 + dd];
      d += w * ad1[h*128 + dd];
    }
    C[VS1 + t] = s; C[VD1 + t] = d;
  }
  if (t < 16){
    int k = t >> 2, h = t & 3;
    float s = 0.f;
    for (int dd = 0; dd < 128; ++dd) s += We1[k*512 + h*128 + dd] * ae1[h*128 + dd];
    C[VE1 + t] = s;
  }
  if (t < 4){
    float s = 0.f;
    for (int dd = 0; dd < 128; ++dd) s += We2[t*128 + dd] * ae2[dd];
    C[VE2 + t] = s;
  }
  {
    float s = 0.f, d = 0.f;
    for (int dd = 0; dd < 128; ++dd){
      float w = W2[t*128 + dd];
      s += w * as2[dd];
      d += w * ad2[dd];
    }
    C[VS2 + t] = s; C[VD2 + t] = d;
  }
}

// ---- transpose + bf16-cast weights -----------------------------------------
__global__ void k_tw(const float* __restrict__ W1, const float* __restrict__ W2,
                     unsigned short* __restrict__ W1t, unsigned short* __restrict__ W2t){
  int i = blockIdx.x * 256 + threadIdx.x;
  if (i < 4*128*KP1){
    int k = i % KP1, n = (i / KP1) & 127, h = i / (KP1*128);
    float v = (k < FIN) ? W1[k*512 + h*128 + n] : 0.f;
    W1t[i] = f2b(v);
  } else {
    int j = i - 4*128*KP1;
    if (j < 128*512){
      int k = j & 511, n = j >> 9;
      W2t[j] = f2b(W2[k*128 + n]);
    }
  }
}

// ---- fused: nf -> bf16 (pitch 72) + layer1 attention scalars ----------------
__global__ __launch_bounds__(256) void k_cnfs1(const float* __restrict__ nf,
    const float* __restrict__ C, unsigned short* __restrict__ nfb,
    float* __restrict__ ss1, float* __restrict__ sd1){
  int lane = threadIdx.x & 63, w = threadIdx.x >> 6;
  int n = blockIdx.x * 4 + w;
  if (n >= NN) return;
  int c0 = lane * 2;
  bool act = lane < 35;                 // cols 0..69
  float v0 = 0.f, v1 = 0.f;
  if (act){
    v0 = nf[(size_t)n * FIN + c0];
    v1 = nf[(size_t)n * FIN + c0 + 1];
  }
  if (lane < 36) *(unsigned*)&nfb[(size_t)n * NFP + c0] = act ? pk2(v0, v1) : 0u;
  float sh[4] = {0,0,0,0}, dh[4] = {0,0,0,0};
  if (act){
    float4 cs0 = *(const float4*)&C[VS1 + c0*4];
    float4 cs1 = *(const float4*)&C[VS1 + (c0+1)*4];
    float4 cd0 = *(const float4*)&C[VD1 + c0*4];
    float4 cd1 = *(const float4*)&C[VD1 + (c0+1)*4];
    sh[0] = v0*cs0.x + v1*cs1.x; sh[1] = v0*cs0.y + v1*cs1.y;
    sh[2] = v0*cs0.z + v1*cs1.z; sh[3] = v0*cs0.w + v1*cs1.w;
    dh[0] = v0*cd0.x + v1*cd1.x; dh[1] = v0*cd0.y + v1*cd1.y;
    dh[2] = v0*cd0.z + v1*cd1.z; dh[3] = v0*cd0.w + v1*cd1.w;
  }
  #pragma unroll
  for (int o = 32; o; o >>= 1){
    #pragma unroll
    for (int h = 0; h < 4; ++h){
      sh[h] += __shfl_xor(sh[h], o);
      dh[h] += __shfl_xor(dh[h], o);
    }
  }
  if (lane == 0){
    *(float4*)&ss1[(size_t)n*4] = make_float4(sh[0], sh[1], sh[2], sh[3]);
    *(float4*)&sd1[(size_t)n*4] = make_float4(dh[0], dh[1], dh[2], dh[3]);
  }
}

// ---- MFMA GEMM: C[M,128] = A[M,KP] @ Bt^T, 128x128 tile, 4 waves ------------
template<int MODE>
__global__ __launch_bounds__(256) void k_mfma(
    const unsigned short* __restrict__ A, int lda, long aSz,
    const unsigned short* __restrict__ Bt, long bSz,
    void* __restrict__ Cout, const float* __restrict__ bias,
    int M, int KP){
  int z = blockIdx.y;
  A  += (size_t)z * aSz;
  Bt += (size_t)z * bSz;
  __shared__ unsigned short As[128 * 40];   // pitch 40 bf16 (80 B)
  __shared__ unsigned short Bs[128 * 40];
  int tid = threadIdx.x, lane = tid & 63, w = tid >> 6;
  int wm = w & 1, wn = w >> 1;
  int row0 = blockIdx.x * 128;
  f4v acc[4][4] = {};
  int r4 = tid >> 2, c4 = tid & 3;
  for (int k0 = 0; k0 < KP; k0 += 32){
    #pragma unroll
    for (int half = 0; half < 2; ++half){
      int r = r4 + half * 64;
      int gr = row0 + r;
      uint4 va = make_uint4(0,0,0,0);
      if (gr < M) va = *(const uint4*)&A[(size_t)gr * lda + k0 + c4*8];
      *(uint4*)&As[r*40 + c4*8] = va;
      uint4 vb = *(const uint4*)&Bt[(size_t)r * lda + k0 + c4*8];
      *(uint4*)&Bs[r*40 + c4*8] = vb;
    }
    __syncthreads();
    s8v af[4], bf[4];
    #pragma unroll
    for (int i = 0; i < 4; ++i){
      af[i] = *(const s8v*)&As[(wm*64 + i*16 + (lane & 15))*40 + (lane >> 4)*8];
      bf[i] = *(const s8v*)&Bs[(wn*64 + i*16 + (lane & 15))*40 + (lane >> 4)*8];
    }
    #pragma unroll
    for (int mi = 0; mi < 4; ++mi)
      #pragma unroll
      for (int ni = 0; ni < 4; ++ni)
        acc[mi][ni] = __builtin_amdgcn_mfma_f32_16x16x32_bf16(af[mi], bf[ni], acc[mi][ni], 0, 0, 0);
    __syncthreads();
  }
  int cq = lane & 15, rq = lane >> 4;
  #pragma unroll
  for (int mi = 0; mi < 4; ++mi){
    #pragma unroll
    for (int r = 0; r < 4; ++r){
      int row = row0 + wm*64 + mi*16 + rq*4 + r;
      if (row >= M) continue;
      #pragma unroll
      for (int ni = 0; ni < 4; ++ni){
        int col = wn*64 + ni*16 + cq;
        float v = acc[mi][ni][r];
        if (MODE == 1){
          int colg = z*128 + col;
          v = gelu_exact(v + bias[colg]);
          ((unsigned short*)Cout)[(size_t)row*512 + colg] = f2b(v);
        } else {
          ((unsigned short*)Cout)[(size_t)row*128 + col] = f2b(v);
        }
      }
    }
  }
}

// ---- layer1: fused alpha + softmax + aggregation over nf (wave per node) ----
__global__ __launch_bounds__(256) void k_aggnf(const int* __restrict__ csr,
    const int* __restrict__ esrc, const float4* __restrict__ eab,
    const float* __restrict__ ss1, const float* __restrict__ sd1,
    const float* __restrict__ C, const unsigned short* __restrict__ nfb,
    unsigned short* __restrict__ agg){
  int lane = threadIdx.x & 63, w = threadIdx.x >> 6;
  int n = blockIdx.x * 4 + w;
  if (n >= NN) return;
  float4 sdv = *(const float4*)&sd1[(size_t)n * 4];   // uniform
  int off = csr[n], end = csr[n + 1];
  int col = lane * 2;
  bool act = lane < 36;
  float d0=0,d1=0,d2=0,d3=0;
  float a00=0,a01=0,a10=0,a11=0,a20=0,a21=0,a30=0,a31=0;
  for (int p = off; p < end; ++p){
    int s = esrc[p];
    float4 a = eab[p];
    float4 ssv = *(const float4*)&ss1[(size_t)s * 4];
    float e0 = __expf(lrelu(ssv.x + sdv.x + a.x*C[VE1+0] + a.y*C[VE1+4] + a.z*C[VE1+8]  + a.w*C[VE1+12]));
    float e1 = __expf(lrelu(ssv.y + sdv.y + a.x*C[VE1+1] + a.y*C[VE1+5] + a.z*C[VE1+9]  + a.w*C[VE1+13]));
    float e2 = __expf(lrelu(ssv.z + sdv.z + a.x*C[VE1+2] + a.y*C[VE1+6] + a.z*C[VE1+10] + a.w*C[VE1+14]));
    float e3 = __expf(lrelu(ssv.w + sdv.w + a.x*C[VE1+3] + a.y*C[VE1+7] + a.z*C[VE1+11] + a.w*C[VE1+15]));
    d0 += e0; d1 += e1; d2 += e2; d3 += e3;
    if (act){
      unsigned u = *(const unsigned*)&nfb[(size_t)s * NFP + col];
      float v0 = b2f(u & 0xffffu), v1 = b2f(u >> 16);
      a00 += e0*v0; a01 += e0*v1;
      a10 += e1*v0; a11 += e1*v1;
      a20 += e2*v0; a21 += e2*v1;
      a30 += e3*v0; a31 += e3*v1;
    }
  }
  float i0 = 1.f/(d0+1e-16f), i1 = 1.f/(d1+1e-16f);
  float i2 = 1.f/(d2+1e-16f), i3 = 1.f/(d3+1e-16f);
  constexpr size_t HS = (size_t)NN * KP1;
  size_t base = (size_t)n * KP1 + col;
  if (act){
    *(unsigned*)&agg[base]        = pk2(a00*i0, a01*i0);
    *(unsigned*)&agg[base +   HS] = pk2(a10*i1, a11*i1);
    *(unsigned*)&agg[base + 2*HS] = pk2(a20*i2, a21*i2);
    *(unsigned*)&agg[base + 3*HS] = pk2(a30*i3, a31*i3);
  } else if (lane < 48){                // zero cols 72..95
    *(unsigned*)&agg[base]        = 0u;
    *(unsigned*)&agg[base +   HS] = 0u;
    *(unsigned*)&agg[base + 2*HS] = 0u;
    *(unsigned*)&agg[base + 3*HS] = 0u;
  }
}

// ---- layer2 attention scalars (x1 is bf16) ----------------------------------
__global__ void k_s2(const unsigned short* __restrict__ x1, const float* __restrict__ C,
                     float* __restrict__ ss2, float* __restrict__ sd2){
  int tid = threadIdx.x, lane = tid & 63;
  int n = blockIdx.x * 4 + (tid >> 6);
  if (n >= NN) return;
  uint4 xv = *(const uint4*)&x1[(size_t)n * 512 + lane * 8];
  float xf[8];
  xf[0] = b2f(xv.x & 0xffffu); xf[1] = b2f(xv.x >> 16);
  xf[2] = b2f(xv.y & 0xffffu); xf[3] = b2f(xv.y >> 16);
  xf[4] = b2f(xv.z & 0xffffu); xf[5] = b2f(xv.z >> 16);
  xf[6] = b2f(xv.w & 0xffffu); xf[7] = b2f(xv.w >> 16);
  float s = 0.f, d = 0.f;
  #pragma unroll
  for (int j = 0; j < 8; ++j){
    s += xf[j] * C[VS2 + lane*8 + j];
    d += xf[j] * C[VD2 + lane*8 + j];
  }
  for (int o = 32; o; o >>= 1){ s += __shfl_down(s, o); d += __shfl_down(d, o); }
  if (lane == 0){ ss2[n] = s; sd2[n] = d; }
}

// ---- layer2: fused alpha + softmax + aggregation + GELU + LN + projections --
__global__ __launch_bounds__(256) void k_agg2(
    const int* __restrict__ csr, const int* __restrict__ esrc,
    const float4* __restrict__ eab, const float* __restrict__ ss2,
    const float* __restrict__ sd2, const float* __restrict__ C,
    const unsigned short* __restrict__ xs2b,
    const float* __restrict__ b2, const float* __restrict__ lng,
    const float* __restrict__ lnb, const float* __restrict__ pw,
    const float* __restrict__ pb, const float* __restrict__ dwm,
    const float* __restrict__ dbv, float* __restrict__ out){
  int lane = threadIdx.x & 63, w = threadIdx.x >> 6;
  int n = blockIdx.x * 4 + w;
  if (n >= NN) return;
  float sdn = sd2[n];                    // uniform
  int off = csr[n], end = csr[n + 1];
  int c0 = lane * 2;
  float acc0 = 0.f, acc1 = 0.f, den = 0.f;
  for (int p = off; p < end; ++p){
    int s = esrc[p];
    float4 a = eab[p];
    float ex = __expf(lrelu(ss2[s] + sdn +
                 a.x*C[VE2] + a.y*C[VE2+1] + a.z*C[VE2+2] + a.w*C[VE2+3]));
    den += ex;
    unsigned u = *(const unsigned*)&xs2b[(size_t)s * 128 + c0];
    acc0 += ex * b2f(u & 0xffffu);
    acc1 += ex * b2f(u >> 16);
  }
  float invd = 1.f / (den + 1e-16f);
  float g0 = gelu_exact(acc0 * invd + b2[c0]);
  float g1 = gelu_exact(acc1 * invd + b2[c0 + 1]);
  float s = g0 + g1;
  #pragma unroll
  for (int o = 32; o; o >>= 1) s += __shfl_xor(s, o);
  float mu = s * (1.f / 128.f);
  float e0 = g0 - mu, e1 = g1 - mu;
  float q = e0*e0 + e1*e1;
  #pragma unroll
  for (int o = 32; o; o >>= 1) q += __shfl_xor(q, o);
  float rstd = rsqrtf(q * (1.f / 128.f) + 1e-5f);
  float y0 = e0 * rstd * lng[c0] + lnb[c0];
  float y1 = e1 * rstd * lng[c0 + 1] + lnb[c0 + 1];
  float pr[12];
  #pragma unroll
  for (int j = 0; j < 8; ++j) pr[j] = y0 * pw[c0*8 + j] + y1 * pw[(c0+1)*8 + j];
  #pragma unroll
  for (int j = 0; j < 4; ++j) pr[8+j] = y0 * dwm[c0*4 + j] + y1 * dwm[(c0+1)*4 + j];
  #pragma unroll
  for (int o = 32; o; o >>= 1)
    #pragma unroll
    for (int j = 0; j < 12; ++j) pr[j] += __shfl_xor(pr[j], o);
  if (lane == 0){
    #pragma unroll
    for (int j = 0; j < 8; ++j) out[(size_t)n*8 + j] = pr[j] + pb[j];
    #pragma unroll
    for (int j = 0; j < 4; ++j) out[(size_t)NN*8 + (size_t)n*4 + j] = pr[8+j] + dbv[j];
  }
}

extern "C" void kernel_launch(void* const* d_in, const int* in_sizes, int n_in,
                              void* d_out, int out_size, void* d_ws, size_t ws_size,
                              hipStream_t stream){
  const float* nf  = (const float*)d_in[0];
  const int*   ei  = (const int*)  d_in[1];
  const float* ea  = (const float*)d_in[2];
  const float* W1  = (const float*)d_in[3];
  const float* as1 = (const float*)d_in[4];
  const float* ad1 = (const float*)d_in[5];
  const float* We1 = (const float*)d_in[6];
  const float* ae1 = (const float*)d_in[7];
  const float* b1  = (const float*)d_in[8];
  const float* W2  = (const float*)d_in[9];
  const float* as2 = (const float*)d_in[10];
  const float* ad2 = (const float*)d_in[11];
  const float* We2 = (const float*)d_in[12];
  const float* ae2 = (const float*)d_in[13];
  const float* b2  = (const float*)d_in[14];
  const float* lng = (const float*)d_in[15];
  const float* lnb = (const float*)d_in[16];
  const float* pw  = (const float*)d_in[17];
  const float* pb  = (const float*)d_in[18];
  const float* dw  = (const float*)d_in[19];
  const float* db  = (const float*)d_in[20];
  float* out = (float*)d_out;

  float* wf = (float*)d_ws;
  int*      cnt  = (int*)     (wf + CNT_O);
  int*      csr  = (int*)     (wf + CSR_O);
  int*      bsum = (int*)     (wf + BSUM_O);
  int*      boff = (int*)     (wf + BOFF_O);
  int*      esrc = (int*)     (wf + ESRC_O);
  float4*   eab  = (float4*)  (wf + EAB_O);
  float*    ss1  =            (wf + SS1_O);
  float*    sd1  =            (wf + SD1_O);
  float*    ss2  =            (wf + SS2_O);
  float*    sd2  =            (wf + SD2_O);
  float*    Cc   =            (wf + CST_O);
  unsigned short* W1t = (unsigned short*)(wf + W1T_O);
  unsigned short* W2t = (unsigned short*)(wf + W2T_O);
  unsigned short* nfb = (unsigned short*)(wf + NFB_O);
  unsigned short* agg = (unsigned short*)(wf + AGG_O);
  unsigned short* x1  = (unsigned short*)(wf + X1_O);
  unsigned short* xs2b= (unsigned short*)(wf + XS2_O);

  hipMemsetAsync(cnt, 0, NN * sizeof(int), stream);
  k_prep<<<1, 512, 0, stream>>>(W1, as1, ad1, We1, ae1, W2, as2, ad2, We2, ae2, Cc);
  k_tw<<<(4*128*KP1 + 128*512 + 255) / 256, 256, 0, stream>>>(W1, W2, W1t, W2t);
  k_cnfs1<<<(NN + 3) / 4, 256, 0, stream>>>(nf, Cc, nfb, ss1, sd1);
  k_deg<<<(NE + 255) / 256, 256, 0, stream>>>(ei, cnt);
  k_scan1<<<SCB, 256, 0, stream>>>(cnt, bsum);
  k_scan2<<<1, 256, 0, stream>>>(bsum, boff);
  k_scan3<<<SCB, 256, 0, stream>>>(cnt, boff, csr);
  k_fill<<<(NE + 255) / 256, 256, 0, stream>>>(ei, ea, csr, cnt, esrc, eab);
  k_loopself<<<(NN + 255) / 256, 256, 0, stream>>>(csr, esrc, eab);
  k_aggnf<<<(NN + 3) / 4, 256, 0, stream>>>(csr, esrc, eab, ss1, sd1, Cc, nfb, agg);
  k_mfma<1><<<dim3((NN + 127) / 128, 4), 256, 0, stream>>>(
      agg, KP1, (long)NN * KP1, W1t, (long)128 * KP1, x1, b1, NN, KP1);
  k_s2<<<(NN + 3) / 4, 256, 0, stream>>>(x1, Cc, ss2, sd2);
  k_mfma<2><<<dim3((NN + 127) / 128, 1), 256, 0, stream>>>(
      x1, 512, 0, W2t, 0, xs2b, nullptr, NN, 512);
  k_agg2<<<(NN + 3) / 4, 256, 0, stream>>>(csr, esrc, eab, ss2, sd2, Cc, xs2b,
                                           b2, lng, lnb, pw, pb, dw, db, out);
}

// Round 6
// 430.159 us; speedup vs baseline: 2.7963x; 1.0377x over previous
//
#include <hip/hip_runtime.h>
#include <hip/hip_bf16.h>
#include <math.h>

#define NN 50000
#define NE 400000
#define FIN 70
#define EDIM 4
#define HIDD 128
#define NHEAD 4
constexpr int ET = NE + NN;
constexpr int KP1 = 96;           // layer-1 K padded (70 -> 96)
constexpr int NFP = 72;           // nf bf16 row pitch
constexpr int SCB = (NN + 255) / 256;   // scan blocks = 196

constexpr size_t al4(size_t x){ return (x + 3) & ~size_t(3); }
// ws offsets in 4-byte words
constexpr size_t CNT_O   = 0;                          // int[NN] (zeroed each call)
constexpr size_t ZEND    = al4(CNT_O + NN);
constexpr size_t CSR_O   = ZEND;                       // int[NN+1]
constexpr size_t BSUM_O  = al4(CSR_O + NN + 1);        // int[256]
constexpr size_t BOFF_O  = al4(BSUM_O + 256);          // int[256]
constexpr size_t ESRC_O  = al4(BOFF_O + 256);          // int[ET]  (CSR order)
constexpr size_t EPK_O   = al4(ESRC_O + ET);           // int4[ET] {s,d,ea01,ea23}
constexpr size_t EXF1_O  = al4(EPK_O + (size_t)ET*4);  // float4[ET] exp scores L1
constexpr size_t EXF2_O  = al4(EXF1_O + (size_t)ET*4); // f32[ET]    exp scores L2
constexpr size_t SS1_O   = al4(EXF2_O + ET);           // f32[NN*4]
constexpr size_t SD1_O   = al4(SS1_O + (size_t)NN*4);
constexpr size_t SS2_O   = al4(SD1_O + (size_t)NN*4);  // f32[NN]
constexpr size_t SD2_O   = al4(SS2_O + NN);
constexpr size_t CST_O   = al4(SD2_O + NN);            // f32[2048]
constexpr size_t W1T_O   = al4(CST_O + 2048);          // bf16[4][128][96]
constexpr size_t W2T_O   = al4(W1T_O + 4*128*KP1/2);   // bf16[128][512]
constexpr size_t NFB_O   = al4(W2T_O + 128*512/2);     // bf16[NN][72]
constexpr size_t AGG_O   = al4(NFB_O + (size_t)NN*NFP/2);   // bf16[4][NN][96]
constexpr size_t X1_O    = al4(AGG_O + (size_t)4*NN*KP1/2); // bf16[NN][512]
constexpr size_t XS2_O   = al4(X1_O + (size_t)NN*512/2);    // bf16[NN][128]

// const-block sub-offsets (words, within CST)
constexpr int VS1 = 0;    // [70][4]
constexpr int VD1 = 320;  // [70][4]
constexpr int VE1 = 640;  // [4][4]
constexpr int VE2 = 656;  // [4]
constexpr int VS2 = 704;  // [512]
constexpr int VD2 = 1216; // [512]

typedef short s8v __attribute__((ext_vector_type(8)));
typedef float f4v __attribute__((ext_vector_type(4)));

__device__ __forceinline__ float gelu_exact(float x){
  return 0.5f * x * (1.f + erff(x * 0.70710678118654752440f));
}
__device__ __forceinline__ unsigned short f2b(float v){
  __hip_bfloat16 b = __float2bfloat16(v);
  return *(unsigned short*)&b;
}
__device__ __forceinline__ float b2f(unsigned u_lo16){
  return __uint_as_float(u_lo16 << 16);
}
__device__ __forceinline__ unsigned pk2(float lo, float hi){
  return (unsigned)f2b(lo) | ((unsigned)f2b(hi) << 16);
}
__device__ __forceinline__ float lrelu(float x){ return x > 0.f ? x : 0.2f * x; }

// ---- degree histogram: ONE atomic per edge ----------------------------------
__global__ void k_deg(const int* __restrict__ ei, int* __restrict__ cnt){
  int e = blockIdx.x * 256 + threadIdx.x;
  if (e >= NE) return;
  atomicAdd(&cnt[ei[NE + e]], 1);
}

// ---- CSR build: 3-phase scan of (cnt+1) -------------------------------------
__global__ void k_scan1(const int* __restrict__ cnt, int* __restrict__ bsum){
  __shared__ int ws[4];
  int t = threadIdx.x, lane = t & 63, w = t >> 6;
  int i = blockIdx.x * 256 + t;
  int v = (i < NN) ? cnt[i] + 1 : 0;
  for (int o = 32; o; o >>= 1) v += __shfl_down(v, o);
  if (lane == 0) ws[w] = v;
  __syncthreads();
  if (t == 0) bsum[blockIdx.x] = ws[0] + ws[1] + ws[2] + ws[3];
}

__global__ void k_scan2(const int* __restrict__ bsum, int* __restrict__ boff){
  __shared__ int ws[4];
  int t = threadIdx.x, lane = t & 63, w = t >> 6;
  int v = (t < SCB) ? bsum[t] : 0;
  int x = v;
  #pragma unroll
  for (int o = 1; o < 64; o <<= 1){ int u = __shfl_up(x, o); if (lane >= o) x += u; }
  if (lane == 63) ws[w] = x;
  __syncthreads();
  if (w == 0 && lane < 4){
    int y = ws[lane];
    #pragma unroll
    for (int o = 1; o < 4; o <<= 1){ int u = __shfl_up(y, o); if (lane >= o) y += u; }
    ws[lane] = y;
  }
  __syncthreads();
  int incl = x + (w > 0 ? ws[w - 1] : 0);
  if (t < SCB) boff[t] = incl - v;
}

__global__ void k_scan3(const int* __restrict__ cnt, const int* __restrict__ boff,
                        int* __restrict__ csr){
  __shared__ int ws[4];
  int t = threadIdx.x, lane = t & 63, w = t >> 6;
  int i = blockIdx.x * 256 + t;
  int v = (i < NN) ? cnt[i] + 1 : 0;
  int x = v;
  #pragma unroll
  for (int o = 1; o < 64; o <<= 1){ int u = __shfl_up(x, o); if (lane >= o) x += u; }
  if (lane == 63) ws[w] = x;
  __syncthreads();
  if (w == 0 && lane < 4){
    int y = ws[lane];
    #pragma unroll
    for (int o = 1; o < 4; o <<= 1){ int u = __shfl_up(y, o); if (lane >= o) y += u; }
    ws[lane] = y;
  }
  __syncthreads();
  if (i < NN) csr[i + 1] = boff[blockIdx.x] + (w > 0 ? ws[w - 1] : 0) + x;
  if (i == 0) csr[0] = 0;
}

// ---- fill CSR slots: esrc + packed {s,d,ea bf16}; consumes cnt -> 0 ---------
__global__ void k_fill(const int* __restrict__ ei, const float* __restrict__ ea,
                       const int* __restrict__ csr, int* __restrict__ cnt,
                       int* __restrict__ esrc, int4* __restrict__ epk){
  int e = blockIdx.x * 256 + threadIdx.x;
  if (e >= NE) return;
  int s = ei[e], d = ei[NE + e];
  int r = atomicSub(&cnt[d], 1);        // r in [deg..1]
  int p = csr[d] + r - 1;
  float4 a = *(const float4*)&ea[(size_t)e * 4];
  esrc[p] = s;
  epk[p] = make_int4(s, d, (int)pk2(a.x, a.y), (int)pk2(a.z, a.w));
}

// ---- per-node: self-loop attr = mean of real-edge attrs ---------------------
__global__ void k_loopself(const int* __restrict__ csr, int* __restrict__ esrc,
                           int4* __restrict__ epk){
  int n = blockIdx.x * 256 + threadIdx.x;
  if (n >= NN) return;
  int a = csr[n], b = csr[n + 1];
  int deg = b - a - 1;
  float s0 = 0.f, s1 = 0.f, s2 = 0.f, s3 = 0.f;
  for (int p = a; p < b - 1; ++p){
    int4 v = epk[p];
    s0 += b2f((unsigned)v.z & 0xffffu); s1 += b2f((unsigned)v.z >> 16);
    s2 += b2f((unsigned)v.w & 0xffffu); s3 += b2f((unsigned)v.w >> 16);
  }
  float inv = 1.f / (float)(deg > 1 ? deg : 1);
  epk[b - 1] = make_int4(n, n, (int)pk2(s0*inv, s1*inv), (int)pk2(s2*inv, s3*inv));
  esrc[b - 1] = n;
}

// ---- tiny weight pre-reductions --------------------------------------------
__global__ void k_prep(const float* __restrict__ W1, const float* __restrict__ as1,
                       const float* __restrict__ ad1, const float* __restrict__ We1,
                       const float* __restrict__ ae1, const float* __restrict__ W2,
                       const float* __restrict__ as2, const float* __restrict__ ad2,
                       const float* __restrict__ We2, const float* __restrict__ ae2,
                       float* __restrict__ C){
  int t = threadIdx.x;                       // block of 512
  if (t < 280){
    int k = t >> 2, h = t & 3;
    float s = 0.f, d = 0.f;
    for (int dd = 0; dd < 128; ++dd){
      float w = W1[k*512 + h*128 + dd];
      s += w * as1[h*128 + dd];
      d += w * ad1[h*128 + dd];
    }
    C[VS1 + t] = s; C[VD1 + t] = d;
  }
  if (t < 16){
    int k = t >> 2, h = t & 3;
    float s = 0.f;
    for (int dd = 0; dd < 128; ++dd) s += We1[k*512 + h*128 + dd] * ae1[h*128 + dd];
    C[VE1 + t] = s;
  }
  if (t < 4){
    float s = 0.f;
    for (int dd = 0; dd < 128; ++dd) s += We2[t*128 + dd] * ae2[dd];
    C[VE2 + t] = s;
  }
  {
    float s = 0.f, d = 0.f;
    for (int dd = 0; dd < 128; ++dd){
      float w = W2[t*128 + dd];
      s += w * as2[dd];
      d += w * ad2[dd];
    }
    C[VS2 + t] = s; C[VD2 + t] = d;
  }
}

// ---- transpose + bf16-cast weights -----------------------------------------
__global__ void k_tw(const float* __restrict__ W1, const float* __restrict__ W2,
                     unsigned short* __restrict__ W1t, unsigned short* __restrict__ W2t){
  int i = blockIdx.x * 256 + threadIdx.x;
  if (i < 4*128*KP1){
    int k = i % KP1, n = (i / KP1) & 127, h = i / (KP1*128);
    float v = (k < FIN) ? W1[k*512 + h*128 + n] : 0.f;
    W1t[i] = f2b(v);
  } else {
    int j = i - 4*128*KP1;
    if (j < 128*512){
      int k = j & 511, n = j >> 9;
      W2t[j] = f2b(W2[k*128 + n]);
    }
  }
}

// ---- fused: nf -> bf16 (pitch 72) + layer1 attention scalars ----------------
__global__ __launch_bounds__(256) void k_cnfs1(const float* __restrict__ nf,
    const float* __restrict__ C, unsigned short* __restrict__ nfb,
    float* __restrict__ ss1, float* __restrict__ sd1){
  int lane = threadIdx.x & 63, w = threadIdx.x >> 6;
  int n = blockIdx.x * 4 + w;
  if (n >= NN) return;
  int c0 = lane * 2;
  bool act = lane < 35;                 // cols 0..69
  float v0 = 0.f, v1 = 0.f;
  if (act){
    v0 = nf[(size_t)n * FIN + c0];
    v1 = nf[(size_t)n * FIN + c0 + 1];
  }
  if (lane < 36) *(unsigned*)&nfb[(size_t)n * NFP + c0] = act ? pk2(v0, v1) : 0u;
  float sh[4] = {0,0,0,0}, dh[4] = {0,0,0,0};
  if (act){
    float4 cs0 = *(const float4*)&C[VS1 + c0*4];
    float4 cs1 = *(const float4*)&C[VS1 + (c0+1)*4];
    float4 cd0 = *(const float4*)&C[VD1 + c0*4];
    float4 cd1 = *(const float4*)&C[VD1 + (c0+1)*4];
    sh[0] = v0*cs0.x + v1*cs1.x; sh[1] = v0*cs0.y + v1*cs1.y;
    sh[2] = v0*cs0.z + v1*cs1.z; sh[3] = v0*cs0.w + v1*cs1.w;
    dh[0] = v0*cd0.x + v1*cd1.x; dh[1] = v0*cd0.y + v1*cd1.y;
    dh[2] = v0*cd0.z + v1*cd1.z; dh[3] = v0*cd0.w + v1*cd1.w;
  }
  #pragma unroll
  for (int o = 32; o; o >>= 1){
    #pragma unroll
    for (int h = 0; h < 4; ++h){
      sh[h] += __shfl_xor(sh[h], o);
      dh[h] += __shfl_xor(dh[h], o);
    }
  }
  if (lane == 0){
    *(float4*)&ss1[(size_t)n*4] = make_float4(sh[0], sh[1], sh[2], sh[3]);
    *(float4*)&sd1[(size_t)n*4] = make_float4(dh[0], dh[1], dh[2], dh[3]);
  }
}

// ---- edge-parallel alpha (layer 1): exf1[p] = exp(lrelu(score)) per head ----
__global__ void k_al1(const int4* __restrict__ epk, const float* __restrict__ ss1,
                      const float* __restrict__ sd1, const float* __restrict__ C,
                      float4* __restrict__ exf){
  int p = blockIdx.x * 256 + threadIdx.x;
  if (p >= ET) return;
  int4 pk = epk[p];
  int s = pk.x, d = pk.y;
  float ax = b2f((unsigned)pk.z & 0xffffu), ay = b2f((unsigned)pk.z >> 16);
  float az = b2f((unsigned)pk.w & 0xffffu), aw = b2f((unsigned)pk.w >> 16);
  float4 ssv = *(const float4*)&ss1[(size_t)s * 4];
  float4 sdv = *(const float4*)&sd1[(size_t)d * 4];
  float e0 = __expf(lrelu(ssv.x + sdv.x + ax*C[VE1+0] + ay*C[VE1+4] + az*C[VE1+8]  + aw*C[VE1+12]));
  float e1 = __expf(lrelu(ssv.y + sdv.y + ax*C[VE1+1] + ay*C[VE1+5] + az*C[VE1+9]  + aw*C[VE1+13]));
  float e2 = __expf(lrelu(ssv.z + sdv.z + ax*C[VE1+2] + ay*C[VE1+6] + az*C[VE1+10] + aw*C[VE1+14]));
  float e3 = __expf(lrelu(ssv.w + sdv.w + ax*C[VE1+3] + ay*C[VE1+7] + az*C[VE1+11] + aw*C[VE1+15]));
  exf[p] = make_float4(e0, e1, e2, e3);
}

// ---- edge-parallel alpha (layer 2) ------------------------------------------
__global__ void k_al2(const int4* __restrict__ epk, const float* __restrict__ ss2,
                      const float* __restrict__ sd2, const float* __restrict__ C,
                      float* __restrict__ ex2){
  int p = blockIdx.x * 256 + threadIdx.x;
  if (p >= ET) return;
  int4 pk = epk[p];
  int s = pk.x, d = pk.y;
  float ax = b2f((unsigned)pk.z & 0xffffu), ay = b2f((unsigned)pk.z >> 16);
  float az = b2f((unsigned)pk.w & 0xffffu), aw = b2f((unsigned)pk.w >> 16);
  ex2[p] = __expf(lrelu(ss2[s] + sd2[d] +
             ax*C[VE2] + ay*C[VE2+1] + az*C[VE2+2] + aw*C[VE2+3]));
}

// ---- MFMA GEMM: C[M,128] = A[M,KP] @ Bt^T, 128x128 tile, 4 waves ------------
template<int MODE>
__global__ __launch_bounds__(256) void k_mfma(
    const unsigned short* __restrict__ A, int lda, long aSz,
    const unsigned short* __restrict__ Bt, long bSz,
    void* __restrict__ Cout, const float* __restrict__ bias,
    int M, int KP){
  int z = blockIdx.y;
  A  += (size_t)z * aSz;
  Bt += (size_t)z * bSz;
  __shared__ unsigned short As[128 * 40];   // pitch 40 bf16 (80 B)
  __shared__ unsigned short Bs[128 * 40];
  int tid = threadIdx.x, lane = tid & 63, w = tid >> 6;
  int wm = w & 1, wn = w >> 1;
  int row0 = blockIdx.x * 128;
  f4v acc[4][4] = {};
  int r4 = tid >> 2, c4 = tid & 3;
  for (int k0 = 0; k0 < KP; k0 += 32){
    #pragma unroll
    for (int half = 0; half < 2; ++half){
      int r = r4 + half * 64;
      int gr = row0 + r;
      uint4 va = make_uint4(0,0,0,0);
      if (gr < M) va = *(const uint4*)&A[(size_t)gr * lda + k0 + c4*8];
      *(uint4*)&As[r*40 + c4*8] = va;
      uint4 vb = *(const uint4*)&Bt[(size_t)r * lda + k0 + c4*8];
      *(uint4*)&Bs[r*40 + c4*8] = vb;
    }
    __syncthreads();
    s8v af[4], bf[4];
    #pragma unroll
    for (int i = 0; i < 4; ++i){
      af[i] = *(const s8v*)&As[(wm*64 + i*16 + (lane & 15))*40 + (lane >> 4)*8];
      bf[i] = *(const s8v*)&Bs[(wn*64 + i*16 + (lane & 15))*40 + (lane >> 4)*8];
    }
    #pragma unroll
    for (int mi = 0; mi < 4; ++mi)
      #pragma unroll
      for (int ni = 0; ni < 4; ++ni)
        acc[mi][ni] = __builtin_amdgcn_mfma_f32_16x16x32_bf16(af[mi], bf[ni], acc[mi][ni], 0, 0, 0);
    __syncthreads();
  }
  int cq = lane & 15, rq = lane >> 4;
  #pragma unroll
  for (int mi = 0; mi < 4; ++mi){
    #pragma unroll
    for (int r = 0; r < 4; ++r){
      int row = row0 + wm*64 + mi*16 + rq*4 + r;
      if (row >= M) continue;
      #pragma unroll
      for (int ni = 0; ni < 4; ++ni){
        int col = wn*64 + ni*16 + cq;
        float v = acc[mi][ni][r];
        if (MODE == 1){
          int colg = z*128 + col;
          v = gelu_exact(v + bias[colg]);
          ((unsigned short*)Cout)[(size_t)row*512 + colg] = f2b(v);
        } else {
          ((unsigned short*)Cout)[(size_t)row*128 + col] = f2b(v);
        }
      }
    }
  }
}

// ---- layer1 aggregation: wave per node, precomputed ex, bf16 nf gather ------
__global__ __launch_bounds__(256) void k_aggnf(const int* __restrict__ csr,
    const int* __restrict__ esrc, const float4* __restrict__ exf,
    const unsigned short* __restrict__ nfb, unsigned short* __restrict__ agg){
  int lane = threadIdx.x & 63, w = threadIdx.x >> 6;
  int n = blockIdx.x * 4 + w;
  if (n >= NN) return;
  int off = csr[n], end = csr[n + 1];
  int col = lane * 2;
  bool act = lane < 36;
  float d0=0,d1=0,d2=0,d3=0;
  float a00=0,a01=0,a10=0,a11=0,a20=0,a21=0,a30=0,a31=0;
  for (int p = off; p < end; ++p){
    float4 ev = exf[p];                 // wave-uniform broadcast
    int s = esrc[p];                    // wave-uniform broadcast
    d0 += ev.x; d1 += ev.y; d2 += ev.z; d3 += ev.w;
    if (act){
      unsigned u = *(const unsigned*)&nfb[(size_t)s * NFP + col];
      float v0 = b2f(u & 0xffffu), v1 = b2f(u >> 16);
      a00 += ev.x*v0; a01 += ev.x*v1;
      a10 += ev.y*v0; a11 += ev.y*v1;
      a20 += ev.z*v0; a21 += ev.z*v1;
      a30 += ev.w*v0; a31 += ev.w*v1;
    }
  }
  float i0 = 1.f/(d0+1e-16f), i1 = 1.f/(d1+1e-16f);
  float i2 = 1.f/(d2+1e-16f), i3 = 1.f/(d3+1e-16f);
  constexpr size_t HS = (size_t)NN * KP1;
  size_t base = (size_t)n * KP1 + col;
  if (act){
    *(unsigned*)&agg[base]        = pk2(a00*i0, a01*i0);
    *(unsigned*)&agg[base +   HS] = pk2(a10*i1, a11*i1);
    *(unsigned*)&agg[base + 2*HS] = pk2(a20*i2, a21*i2);
    *(unsigned*)&agg[base + 3*HS] = pk2(a30*i3, a31*i3);
  } else if (lane < 48){                // zero cols 72..95
    *(unsigned*)&agg[base]        = 0u;
    *(unsigned*)&agg[base +   HS] = 0u;
    *(unsigned*)&agg[base + 2*HS] = 0u;
    *(unsigned*)&agg[base + 3*HS] = 0u;
  }
}

// ---- layer2 attention scalars (x1 is bf16) ----------------------------------
__global__ void k_s2(const unsigned short* __restrict__ x1, const float* __restrict__ C,
                     float* __restrict__ ss2, float* __restrict__ sd2){
  int tid = threadIdx.x, lane = tid & 63;
  int n = blockIdx.x * 4 + (tid >> 6);
  if (n >= NN) return;
  uint4 xv = *(const uint4*)&x1[(size_t)n * 512 + lane * 8];
  float xf[8];
  xf[0] = b2f(xv.x & 0xffffu); xf[1] = b2f(xv.x >> 16);
  xf[2] = b2f(xv.y & 0xffffu); xf[3] = b2f(xv.y >> 16);
  xf[4] = b2f(xv.z & 0xffffu); xf[5] = b2f(xv.z >> 16);
  xf[6] = b2f(xv.w & 0xffffu); xf[7] = b2f(xv.w >> 16);
  float s = 0.f, d = 0.f;
  #pragma unroll
  for (int j = 0; j < 8; ++j){
    s += xf[j] * C[VS2 + lane*8 + j];
    d += xf[j] * C[VD2 + lane*8 + j];
  }
  for (int o = 32; o; o >>= 1){ s += __shfl_down(s, o); d += __shfl_down(d, o); }
  if (lane == 0){ ss2[n] = s; sd2[n] = d; }
}

// ---- layer2 aggregation (precomputed ex) + GELU + LN + projections ----------
__global__ __launch_bounds__(256) void k_agg2(
    const int* __restrict__ csr, const int* __restrict__ esrc,
    const float* __restrict__ ex2, const unsigned short* __restrict__ xs2b,
    const float* __restrict__ b2, const float* __restrict__ lng,
    const float* __restrict__ lnb, const float* __restrict__ pw,
    const float* __restrict__ pb, const float* __restrict__ dwm,
    const float* __restrict__ dbv, float* __restrict__ out){
  int lane = threadIdx.x & 63, w = threadIdx.x >> 6;
  int n = blockIdx.x * 4 + w;
  if (n >= NN) return;
  int off = csr[n], end = csr[n + 1];
  int c0 = lane * 2;
  float acc0 = 0.f, acc1 = 0.f, den = 0.f;
  for (int p = off; p < end; ++p){
    float ex = ex2[p];                  // wave-uniform
    int s = esrc[p];                    // wave-uniform
    den += ex;
    unsigned u = *(const unsigned*)&xs2b[(size_t)s * 128 + c0];
    acc0 += ex * b2f(u & 0xffffu);
    acc1 += ex * b2f(u >> 16);
  }
  float invd = 1.f / (den + 1e-16f);
  float g0 = gelu_exact(acc0 * invd + b2[c0]);
  float g1 = gelu_exact(acc1 * invd + b2[c0 + 1]);
  float s = g0 + g1;
  #pragma unroll
  for (int o = 32; o; o >>= 1) s += __shfl_xor(s, o);
  float mu = s * (1.f / 128.f);
  float e0 = g0 - mu, e1 = g1 - mu;
  float q = e0*e0 + e1*e1;
  #pragma unroll
  for (int o = 32; o; o >>= 1) q += __shfl_xor(q, o);
  float rstd = rsqrtf(q * (1.f / 128.f) + 1e-5f);
  float y0 = e0 * rstd * lng[c0] + lnb[c0];
  float y1 = e1 * rstd * lng[c0 + 1] + lnb[c0 + 1];
  float pr[12];
  #pragma unroll
  for (int j = 0; j < 8; ++j) pr[j] = y0 * pw[c0*8 + j] + y1 * pw[(c0+1)*8 + j];
  #pragma unroll
  for (int j = 0; j < 4; ++j) pr[8+j] = y0 * dwm[c0*4 + j] + y1 * dwm[(c0+1)*4 + j];
  #pragma unroll
  for (int o = 32; o; o >>= 1)
    #pragma unroll
    for (int j = 0; j < 12; ++j) pr[j] += __shfl_xor(pr[j], o);
  if (lane == 0){
    #pragma unroll
    for (int j = 0; j < 8; ++j) out[(size_t)n*8 + j] = pr[j] + pb[j];
    #pragma unroll
    for (int j = 0; j < 4; ++j) out[(size_t)NN*8 + (size_t)n*4 + j] = pr[8+j] + dbv[j];
  }
}

extern "C" void kernel_launch(void* const* d_in, const int* in_sizes, int n_in,
                              void* d_out, int out_size, void* d_ws, size_t ws_size,
                              hipStream_t stream){
  const float* nf  = (const float*)d_in[0];
  const int*   ei  = (const int*)  d_in[1];
  const float* ea  = (const float*)d_in[2];
  const float* W1  = (const float*)d_in[3];
  const float* as1 = (const float*)d_in[4];
  const float* ad1 = (const float*)d_in[5];
  const float* We1 = (const float*)d_in[6];
  const float* ae1 = (const float*)d_in[7];
  const float* b1  = (const float*)d_in[8];
  const float* W2  = (const float*)d_in[9];
  const float* as2 = (const float*)d_in[10];
  const float* ad2 = (const float*)d_in[11];
  const float* We2 = (const float*)d_in[12];
  const float* ae2 = (const float*)d_in[13];
  const float* b2  = (const float*)d_in[14];
  const float* lng = (const float*)d_in[15];
  const float* lnb = (const float*)d_in[16];
  const float* pw  = (const float*)d_in[17];
  const float* pb  = (const float*)d_in[18];
  const float* dw  = (const float*)d_in[19];
  const float* db  = (const float*)d_in[20];
  float* out = (float*)d_out;

  float* wf = (float*)d_ws;
  int*      cnt  = (int*)     (wf + CNT_O);
  int*      csr  = (int*)     (wf + CSR_O);
  int*      bsum = (int*)     (wf + BSUM_O);
  int*      boff = (int*)     (wf + BOFF_O);
  int*      esrc = (int*)     (wf + ESRC_O);
  int4*     epk  = (int4*)    (wf + EPK_O);
  float4*   exf1 = (float4*)  (wf + EXF1_O);
  float*    ex2  =            (wf + EXF2_O);
  float*    ss1  =            (wf + SS1_O);
  float*    sd1  =            (wf + SD1_O);
  float*    ss2  =            (wf + SS2_O);
  float*    sd2  =            (wf + SD2_O);
  float*    Cc   =            (wf + CST_O);
  unsigned short* W1t = (unsigned short*)(wf + W1T_O);
  unsigned short* W2t = (unsigned short*)(wf + W2T_O);
  unsigned short* nfb = (unsigned short*)(wf + NFB_O);
  unsigned short* agg = (unsigned short*)(wf + AGG_O);
  unsigned short* x1  = (unsigned short*)(wf + X1_O);
  unsigned short* xs2b= (unsigned short*)(wf + XS2_O);

  hipMemsetAsync(cnt, 0, NN * sizeof(int), stream);
  k_prep<<<1, 512, 0, stream>>>(W1, as1, ad1, We1, ae1, W2, as2, ad2, We2, ae2, Cc);
  k_tw<<<(4*128*KP1 + 128*512 + 255) / 256, 256, 0, stream>>>(W1, W2, W1t, W2t);
  k_cnfs1<<<(NN + 3) / 4, 256, 0, stream>>>(nf, Cc, nfb, ss1, sd1);
  k_deg<<<(NE + 255) / 256, 256, 0, stream>>>(ei, cnt);
  k_scan1<<<SCB, 256, 0, stream>>>(cnt, bsum);
  k_scan2<<<1, 256, 0, stream>>>(bsum, boff);
  k_scan3<<<SCB, 256, 0, stream>>>(cnt, boff, csr);
  k_fill<<<(NE + 255) / 256, 256, 0, stream>>>(ei, ea, csr, cnt, esrc, epk);
  k_loopself<<<(NN + 255) / 256, 256, 0, stream>>>(csr, esrc, epk);
  k_al1<<<(ET + 255) / 256, 256, 0, stream>>>(epk, ss1, sd1, Cc, exf1);
  k_aggnf<<<(NN + 3) / 4, 256, 0, stream>>>(csr, esrc, exf1, nfb, agg);
  k_mfma<1><<<dim3((NN + 127) / 128, 4), 256, 0, stream>>>(
      agg, KP1, (long)NN * KP1, W1t, (long)128 * KP1, x1, b1, NN, KP1);
  k_s2<<<(NN + 3) / 4, 256, 0, stream>>>(x1, Cc, ss2, sd2);
  k_mfma<2><<<dim3((NN + 127) / 128, 1), 256, 0, stream>>>(
      x1, 512, 0, W2t, 0, xs2b, nullptr, NN, 512);
  k_al2<<<(ET + 255) / 256, 256, 0, stream>>>(epk, ss2, sd2, Cc, ex2);
  k_agg2<<<(NN + 3) / 4, 256, 0, stream>>>(csr, esrc, ex2, xs2b,
                                           b2, lng, lnb, pw, pb, dw, db, out);
}

// Round 7
// 388.747 us; speedup vs baseline: 3.0941x; 1.1065x over previous
//
#include <hip/hip_runtime.h>
#include <hip/hip_bf16.h>
#include <math.h>

#define NN 50000
#define NE 400000
#define FIN 70
#define EDIM 4
#define HIDD 128
#define NHEAD 4
constexpr int ET = NE + NN;
constexpr int KP1 = 96;           // layer-1 K padded (70 -> 96)
constexpr int NFP = 72;           // nf bf16 row pitch
constexpr int SCB = (NN + 255) / 256;   // scan blocks = 196

constexpr size_t al4(size_t x){ return (x + 3) & ~size_t(3); }
// ws offsets in 4-byte words
constexpr size_t CNT_O   = 0;                          // int[NN] (zeroed each call)
constexpr size_t ZEND    = al4(CNT_O + NN);
constexpr size_t CSR_O   = ZEND;                       // int[NN+1]
constexpr size_t BSUM_O  = al4(CSR_O + NN + 1);        // int[256]
constexpr size_t BOFF_O  = al4(BSUM_O + 256);          // int[256]
constexpr size_t EPK_O   = al4(BOFF_O + 256);          // int4[ET] {s,d,ea01,ea23}
constexpr size_t EXF1_O  = al4(EPK_O + (size_t)ET*4);  // float4[ET] exp scores L1
constexpr size_t EXF2_O  = al4(EXF1_O + (size_t)ET*4); // f32[ET]    exp scores L2
constexpr size_t SS1_O   = al4(EXF2_O + ET);           // f32[NN*4]
constexpr size_t SD1_O   = al4(SS1_O + (size_t)NN*4);
constexpr size_t SS2_O   = al4(SD1_O + (size_t)NN*4);  // f32[NN]
constexpr size_t SD2_O   = al4(SS2_O + NN);
constexpr size_t CST_O   = al4(SD2_O + NN);            // f32[2048]
constexpr size_t W1T_O   = al4(CST_O + 2048);          // bf16[4][128][96]
constexpr size_t W2T_O   = al4(W1T_O + 4*128*KP1/2);   // bf16[128][512]
constexpr size_t NFB_O   = al4(W2T_O + 128*512/2);     // bf16[NN][72]
constexpr size_t AGG_O   = al4(NFB_O + (size_t)NN*NFP/2);   // bf16[4][NN][96]
constexpr size_t X1_O    = al4(AGG_O + (size_t)4*NN*KP1/2); // bf16[NN][512]
constexpr size_t XS2_O   = al4(X1_O + (size_t)NN*512/2);    // bf16[NN][128]

// const-block sub-offsets (words, within CST)
constexpr int VS1 = 0;    // [70][4]
constexpr int VD1 = 320;  // [70][4]
constexpr int VE1 = 640;  // [4][4]
constexpr int VE2 = 656;  // [4]
constexpr int VS2 = 704;  // [512]
constexpr int VD2 = 1216; // [512]

typedef short s8v __attribute__((ext_vector_type(8)));
typedef float f4v __attribute__((ext_vector_type(4)));

__device__ __forceinline__ float gelu_exact(float x){
  return 0.5f * x * (1.f + erff(x * 0.70710678118654752440f));
}
__device__ __forceinline__ unsigned short f2b(float v){
  __hip_bfloat16 b = __float2bfloat16(v);
  return *(unsigned short*)&b;
}
__device__ __forceinline__ float b2f(unsigned u_lo16){
  return __uint_as_float(u_lo16 << 16);
}
__device__ __forceinline__ unsigned pk2(float lo, float hi){
  return (unsigned)f2b(lo) | ((unsigned)f2b(hi) << 16);
}
__device__ __forceinline__ float lrelu(float x){ return x > 0.f ? x : 0.2f * x; }

// ---- degree histogram: ONE atomic per edge ----------------------------------
__global__ void k_deg(const int* __restrict__ ei, int* __restrict__ cnt){
  int e = blockIdx.x * 256 + threadIdx.x;
  if (e >= NE) return;
  atomicAdd(&cnt[ei[NE + e]], 1);
}

// ---- CSR build: 3-phase scan of (cnt+1) -------------------------------------
__global__ void k_scan1(const int* __restrict__ cnt, int* __restrict__ bsum){
  __shared__ int ws[4];
  int t = threadIdx.x, lane = t & 63, w = t >> 6;
  int i = blockIdx.x * 256 + t;
  int v = (i < NN) ? cnt[i] + 1 : 0;
  for (int o = 32; o; o >>= 1) v += __shfl_down(v, o);
  if (lane == 0) ws[w] = v;
  __syncthreads();
  if (t == 0) bsum[blockIdx.x] = ws[0] + ws[1] + ws[2] + ws[3];
}

__global__ void k_scan2(const int* __restrict__ bsum, int* __restrict__ boff){
  __shared__ int ws[4];
  int t = threadIdx.x, lane = t & 63, w = t >> 6;
  int v = (t < SCB) ? bsum[t] : 0;
  int x = v;
  #pragma unroll
  for (int o = 1; o < 64; o <<= 1){ int u = __shfl_up(x, o); if (lane >= o) x += u; }
  if (lane == 63) ws[w] = x;
  __syncthreads();
  if (w == 0 && lane < 4){
    int y = ws[lane];
    #pragma unroll
    for (int o = 1; o < 4; o <<= 1){ int u = __shfl_up(y, o); if (lane >= o) y += u; }
    ws[lane] = y;
  }
  __syncthreads();
  int incl = x + (w > 0 ? ws[w - 1] : 0);
  if (t < SCB) boff[t] = incl - v;
}

__global__ void k_scan3(const int* __restrict__ cnt, const int* __restrict__ boff,
                        int* __restrict__ csr){
  __shared__ int ws[4];
  int t = threadIdx.x, lane = t & 63, w = t >> 6;
  int i = blockIdx.x * 256 + t;
  int v = (i < NN) ? cnt[i] + 1 : 0;
  int x = v;
  #pragma unroll
  for (int o = 1; o < 64; o <<= 1){ int u = __shfl_up(x, o); if (lane >= o) x += u; }
  if (lane == 63) ws[w] = x;
  __syncthreads();
  if (w == 0 && lane < 4){
    int y = ws[lane];
    #pragma unroll
    for (int o = 1; o < 4; o <<= 1){ int u = __shfl_up(y, o); if (lane >= o) y += u; }
    ws[lane] = y;
  }
  __syncthreads();
  if (i < NN) csr[i + 1] = boff[blockIdx.x] + (w > 0 ? ws[w - 1] : 0) + x;
  if (i == 0) csr[0] = 0;
}

// ---- fill CSR slots: packed {s,d,ea bf16}; consumes cnt -> 0 ----------------
__global__ void k_fill(const int* __restrict__ ei, const float* __restrict__ ea,
                       const int* __restrict__ csr, int* __restrict__ cnt,
                       int4* __restrict__ epk){
  int e = blockIdx.x * 256 + threadIdx.x;
  if (e >= NE) return;
  int s = ei[e], d = ei[NE + e];
  int r = atomicSub(&cnt[d], 1);        // r in [deg..1]
  int p = csr[d] + r - 1;
  float4 a = *(const float4*)&ea[(size_t)e * 4];
  epk[p] = make_int4(s, d, (int)pk2(a.x, a.y), (int)pk2(a.z, a.w));
}

// ---- per-node: self-loop attr = mean of real-edge attrs ---------------------
__global__ void k_loopself(const int* __restrict__ csr, int4* __restrict__ epk){
  int n = blockIdx.x * 256 + threadIdx.x;
  if (n >= NN) return;
  int a = csr[n], b = csr[n + 1];
  int deg = b - a - 1;
  float s0 = 0.f, s1 = 0.f, s2 = 0.f, s3 = 0.f;
  for (int p = a; p < b - 1; ++p){
    int4 v = epk[p];
    s0 += b2f((unsigned)v.z & 0xffffu); s1 += b2f((unsigned)v.z >> 16);
    s2 += b2f((unsigned)v.w & 0xffffu); s3 += b2f((unsigned)v.w >> 16);
  }
  float inv = 1.f / (float)(deg > 1 ? deg : 1);
  epk[b - 1] = make_int4(n, n, (int)pk2(s0*inv, s1*inv), (int)pk2(s2*inv, s3*inv));
}

// ---- tiny weight pre-reductions --------------------------------------------
__global__ void k_prep(const float* __restrict__ W1, const float* __restrict__ as1,
                       const float* __restrict__ ad1, const float* __restrict__ We1,
                       const float* __restrict__ ae1, const float* __restrict__ W2,
                       const float* __restrict__ as2, const float* __restrict__ ad2,
                       const float* __restrict__ We2, const float* __restrict__ ae2,
                       float* __restrict__ C){
  int t = threadIdx.x;                       // block of 512
  if (t < 280){
    int k = t >> 2, h = t & 3;
    float s = 0.f, d = 0.f;
    for (int dd = 0; dd < 128; ++dd){
      float w = W1[k*512 + h*128 + dd];
      s += w * as1[h*128 + dd];
      d += w * ad1[h*128 + dd];
    }
    C[VS1 + t] = s; C[VD1 + t] = d;
  }
  if (t < 16){
    int k = t >> 2, h = t & 3;
    float s = 0.f;
    for (int dd = 0; dd < 128; ++dd) s += We1[k*512 + h*128 + dd] * ae1[h*128 + dd];
    C[VE1 + t] = s;
  }
  if (t < 4){
    float s = 0.f;
    for (int dd = 0; dd < 128; ++dd) s += We2[t*128 + dd] * ae2[dd];
    C[VE2 + t] = s;
  }
  {
    float s = 0.f, d = 0.f;
    for (int dd = 0; dd < 128; ++dd){
      float w = W2[t*128 + dd];
      s += w * as2[dd];
      d += w * ad2[dd];
    }
    C[VS2 + t] = s; C[VD2 + t] = d;
  }
}

// ---- transpose + bf16-cast weights -----------------------------------------
__global__ void k_tw(const float* __restrict__ W1, const float* __restrict__ W2,
                     unsigned short* __restrict__ W1t, unsigned short* __restrict__ W2t){
  int i = blockIdx.x * 256 + threadIdx.x;
  if (i < 4*128*KP1){
    int k = i % KP1, n = (i / KP1) & 127, h = i / (KP1*128);
    float v = (k < FIN) ? W1[k*512 + h*128 + n] : 0.f;
    W1t[i] = f2b(v);
  } else {
    int j = i - 4*128*KP1;
    if (j < 128*512){
      int k = j & 511, n = j >> 9;
      W2t[j] = f2b(W2[k*128 + n]);
    }
  }
}

// ---- fused: nf -> bf16 (pitch 72) + layer1 attention scalars ----------------
__global__ __launch_bounds__(256) void k_cnfs1(const float* __restrict__ nf,
    const float* __restrict__ C, unsigned short* __restrict__ nfb,
    float* __restrict__ ss1, float* __restrict__ sd1){
  int lane = threadIdx.x & 63, w = threadIdx.x >> 6;
  int n = blockIdx.x * 4 + w;
  if (n >= NN) return;
  int c0 = lane * 2;
  bool act = lane < 35;                 // cols 0..69
  float v0 = 0.f, v1 = 0.f;
  if (act){
    v0 = nf[(size_t)n * FIN + c0];
    v1 = nf[(size_t)n * FIN + c0 + 1];
  }
  if (lane < 36) *(unsigned*)&nfb[(size_t)n * NFP + c0] = act ? pk2(v0, v1) : 0u;
  float sh[4] = {0,0,0,0}, dh[4] = {0,0,0,0};
  if (act){
    float4 cs0 = *(const float4*)&C[VS1 + c0*4];
    float4 cs1 = *(const float4*)&C[VS1 + (c0+1)*4];
    float4 cd0 = *(const float4*)&C[VD1 + c0*4];
    float4 cd1 = *(const float4*)&C[VD1 + (c0+1)*4];
    sh[0] = v0*cs0.x + v1*cs1.x; sh[1] = v0*cs0.y + v1*cs1.y;
    sh[2] = v0*cs0.z + v1*cs1.z; sh[3] = v0*cs0.w + v1*cs1.w;
    dh[0] = v0*cd0.x + v1*cd1.x; dh[1] = v0*cd0.y + v1*cd1.y;
    dh[2] = v0*cd0.z + v1*cd1.z; dh[3] = v0*cd0.w + v1*cd1.w;
  }
  #pragma unroll
  for (int o = 32; o; o >>= 1){
    #pragma unroll
    for (int h = 0; h < 4; ++h){
      sh[h] += __shfl_xor(sh[h], o);
      dh[h] += __shfl_xor(dh[h], o);
    }
  }
  if (lane == 0){
    *(float4*)&ss1[(size_t)n*4] = make_float4(sh[0], sh[1], sh[2], sh[3]);
    *(float4*)&sd1[(size_t)n*4] = make_float4(dh[0], dh[1], dh[2], dh[3]);
  }
}

// ---- edge-parallel alpha (layer 1): exf1[p] = exp(lrelu(score)) per head ----
__global__ void k_al1(const int4* __restrict__ epk, const float* __restrict__ ss1,
                      const float* __restrict__ sd1, const float* __restrict__ C,
                      float4* __restrict__ exf){
  int p = blockIdx.x * 256 + threadIdx.x;
  if (p >= ET) return;
  int4 pk = epk[p];
  int s = pk.x, d = pk.y;
  float ax = b2f((unsigned)pk.z & 0xffffu), ay = b2f((unsigned)pk.z >> 16);
  float az = b2f((unsigned)pk.w & 0xffffu), aw = b2f((unsigned)pk.w >> 16);
  float4 ssv = *(const float4*)&ss1[(size_t)s * 4];
  float4 sdv = *(const float4*)&sd1[(size_t)d * 4];
  float e0 = __expf(lrelu(ssv.x + sdv.x + ax*C[VE1+0] + ay*C[VE1+4] + az*C[VE1+8]  + aw*C[VE1+12]));
  float e1 = __expf(lrelu(ssv.y + sdv.y + ax*C[VE1+1] + ay*C[VE1+5] + az*C[VE1+9]  + aw*C[VE1+13]));
  float e2 = __expf(lrelu(ssv.z + sdv.z + ax*C[VE1+2] + ay*C[VE1+6] + az*C[VE1+10] + aw*C[VE1+14]));
  float e3 = __expf(lrelu(ssv.w + sdv.w + ax*C[VE1+3] + ay*C[VE1+7] + az*C[VE1+11] + aw*C[VE1+15]));
  exf[p] = make_float4(e0, e1, e2, e3);
}

// ---- edge-parallel alpha (layer 2) ------------------------------------------
__global__ void k_al2(const int4* __restrict__ epk, const float* __restrict__ ss2,
                      const float* __restrict__ sd2, const float* __restrict__ C,
                      float* __restrict__ ex2){
  int p = blockIdx.x * 256 + threadIdx.x;
  if (p >= ET) return;
  int4 pk = epk[p];
  int s = pk.x, d = pk.y;
  float ax = b2f((unsigned)pk.z & 0xffffu), ay = b2f((unsigned)pk.z >> 16);
  float az = b2f((unsigned)pk.w & 0xffffu), aw = b2f((unsigned)pk.w >> 16);
  ex2[p] = __expf(lrelu(ss2[s] + sd2[d] +
             ax*C[VE2] + ay*C[VE2+1] + az*C[VE2+2] + aw*C[VE2+3]));
}

// ---- MFMA GEMM: C[M,128] = A[M,KP] @ Bt^T, 128x128 tile, 4 waves ------------
template<int MODE>
__global__ __launch_bounds__(256) void k_mfma(
    const unsigned short* __restrict__ A, int lda, long aSz,
    const unsigned short* __restrict__ Bt, long bSz,
    void* __restrict__ Cout, const float* __restrict__ bias,
    int M, int KP){
  int z = blockIdx.y;
  A  += (size_t)z * aSz;
  Bt += (size_t)z * bSz;
  __shared__ unsigned short As[128 * 40];   // pitch 40 bf16 (80 B)
  __shared__ unsigned short Bs[128 * 40];
  int tid = threadIdx.x, lane = tid & 63, w = tid >> 6;
  int wm = w & 1, wn = w >> 1;
  int row0 = blockIdx.x * 128;
  f4v acc[4][4] = {};
  int r4 = tid >> 2, c4 = tid & 3;
  for (int k0 = 0; k0 < KP; k0 += 32){
    #pragma unroll
    for (int half = 0; half < 2; ++half){
      int r = r4 + half * 64;
      int gr = row0 + r;
      uint4 va = make_uint4(0,0,0,0);
      if (gr < M) va = *(const uint4*)&A[(size_t)gr * lda + k0 + c4*8];
      *(uint4*)&As[r*40 + c4*8] = va;
      uint4 vb = *(const uint4*)&Bt[(size_t)r * lda + k0 + c4*8];
      *(uint4*)&Bs[r*40 + c4*8] = vb;
    }
    __syncthreads();
    s8v af[4], bf[4];
    #pragma unroll
    for (int i = 0; i < 4; ++i){
      af[i] = *(const s8v*)&As[(wm*64 + i*16 + (lane & 15))*40 + (lane >> 4)*8];
      bf[i] = *(const s8v*)&Bs[(wn*64 + i*16 + (lane & 15))*40 + (lane >> 4)*8];
    }
    #pragma unroll
    for (int mi = 0; mi < 4; ++mi)
      #pragma unroll
      for (int ni = 0; ni < 4; ++ni)
        acc[mi][ni] = __builtin_amdgcn_mfma_f32_16x16x32_bf16(af[mi], bf[ni], acc[mi][ni], 0, 0, 0);
    __syncthreads();
  }
  int cq = lane & 15, rq = lane >> 4;
  #pragma unroll
  for (int mi = 0; mi < 4; ++mi){
    #pragma unroll
    for (int r = 0; r < 4; ++r){
      int row = row0 + wm*64 + mi*16 + rq*4 + r;
      if (row >= M) continue;
      #pragma unroll
      for (int ni = 0; ni < 4; ++ni){
        int col = wn*64 + ni*16 + cq;
        float v = acc[mi][ni][r];
        if (MODE == 1){
          int colg = z*128 + col;
          v = gelu_exact(v + bias[colg]);
          ((unsigned short*)Cout)[(size_t)row*512 + colg] = f2b(v);
        } else {
          ((unsigned short*)Cout)[(size_t)row*128 + col] = f2b(v);
        }
      }
    }
  }
}

// ---- layer1 aggregation: wave/node, 2-edge pipelined gather -----------------
__global__ __launch_bounds__(256) void k_aggnf(const int* __restrict__ csr,
    const int4* __restrict__ epk, const float4* __restrict__ exf,
    const unsigned short* __restrict__ nfb, unsigned short* __restrict__ agg){
  int lane = threadIdx.x & 63, w = threadIdx.x >> 6;
  int n = blockIdx.x * 4 + w;
  if (n >= NN) return;
  int off = __builtin_amdgcn_readfirstlane(csr[n]);
  int end = __builtin_amdgcn_readfirstlane(csr[n + 1]);
  int col = lane * 2;
  bool act = lane < 36;
  float d0=0,d1=0,d2=0,d3=0;
  float a00=0,a01=0,a10=0,a11=0,a20=0,a21=0,a30=0,a31=0;
  int p = off;
  for (; p + 2 <= end; p += 2){
    int s0 = epk[p].x, s1 = epk[p+1].x;
    float4 e0 = exf[p], e1 = exf[p+1];
    unsigned u0 = 0, u1 = 0;
    if (act){
      u0 = *(const unsigned*)&nfb[(size_t)s0 * NFP + col];
      u1 = *(const unsigned*)&nfb[(size_t)s1 * NFP + col];
    }
    d0 += e0.x + e1.x; d1 += e0.y + e1.y; d2 += e0.z + e1.z; d3 += e0.w + e1.w;
    float v00 = b2f(u0 & 0xffffu), v01 = b2f(u0 >> 16);
    float v10 = b2f(u1 & 0xffffu), v11 = b2f(u1 >> 16);
    a00 += e0.x*v00 + e1.x*v10; a01 += e0.x*v01 + e1.x*v11;
    a10 += e0.y*v00 + e1.y*v10; a11 += e0.y*v01 + e1.y*v11;
    a20 += e0.z*v00 + e1.z*v10; a21 += e0.z*v01 + e1.z*v11;
    a30 += e0.w*v00 + e1.w*v10; a31 += e0.w*v01 + e1.w*v11;
  }
  if (p < end){
    int s0 = epk[p].x;
    float4 e0 = exf[p];
    unsigned u0 = 0;
    if (act) u0 = *(const unsigned*)&nfb[(size_t)s0 * NFP + col];
    d0 += e0.x; d1 += e0.y; d2 += e0.z; d3 += e0.w;
    float v00 = b2f(u0 & 0xffffu), v01 = b2f(u0 >> 16);
    a00 += e0.x*v00; a01 += e0.x*v01;
    a10 += e0.y*v00; a11 += e0.y*v01;
    a20 += e0.z*v00; a21 += e0.z*v01;
    a30 += e0.w*v00; a31 += e0.w*v01;
  }
  float i0 = 1.f/(d0+1e-16f), i1 = 1.f/(d1+1e-16f);
  float i2 = 1.f/(d2+1e-16f), i3 = 1.f/(d3+1e-16f);
  constexpr size_t HS = (size_t)NN * KP1;
  size_t base = (size_t)n * KP1 + col;
  if (act){
    *(unsigned*)&agg[base]        = pk2(a00*i0, a01*i0);
    *(unsigned*)&agg[base +   HS] = pk2(a10*i1, a11*i1);
    *(unsigned*)&agg[base + 2*HS] = pk2(a20*i2, a21*i2);
    *(unsigned*)&agg[base + 3*HS] = pk2(a30*i3, a31*i3);
  } else if (lane < 48){                // zero cols 72..95
    *(unsigned*)&agg[base]        = 0u;
    *(unsigned*)&agg[base +   HS] = 0u;
    *(unsigned*)&agg[base + 2*HS] = 0u;
    *(unsigned*)&agg[base + 3*HS] = 0u;
  }
}

// ---- layer2 attention scalars (x1 is bf16) ----------------------------------
__global__ void k_s2(const unsigned short* __restrict__ x1, const float* __restrict__ C,
                     float* __restrict__ ss2, float* __restrict__ sd2){
  int tid = threadIdx.x, lane = tid & 63;
  int n = blockIdx.x * 4 + (tid >> 6);
  if (n >= NN) return;
  uint4 xv = *(const uint4*)&x1[(size_t)n * 512 + lane * 8];
  float xf[8];
  xf[0] = b2f(xv.x & 0xffffu); xf[1] = b2f(xv.x >> 16);
  xf[2] = b2f(xv.y & 0xffffu); xf[3] = b2f(xv.y >> 16);
  xf[4] = b2f(xv.z & 0xffffu); xf[5] = b2f(xv.z >> 16);
  xf[6] = b2f(xv.w & 0xffffu); xf[7] = b2f(xv.w >> 16);
  float s = 0.f, d = 0.f;
  #pragma unroll
  for (int j = 0; j < 8; ++j){
    s += xf[j] * C[VS2 + lane*8 + j];
    d += xf[j] * C[VD2 + lane*8 + j];
  }
  for (int o = 32; o; o >>= 1){ s += __shfl_down(s, o); d += __shfl_down(d, o); }
  if (lane == 0){ ss2[n] = s; sd2[n] = d; }
}

// ---- layer2 aggregation: 4-edge pipelined gather + GELU + LN + projections --
__global__ __launch_bounds__(256) void k_agg2(
    const int* __restrict__ csr, const int4* __restrict__ epk,
    const float* __restrict__ ex2, const unsigned short* __restrict__ xs2b,
    const float* __restrict__ b2, const float* __restrict__ lng,
    const float* __restrict__ lnb, const float* __restrict__ pw,
    const float* __restrict__ pb, const float* __restrict__ dwm,
    const float* __restrict__ dbv, float* __restrict__ out){
  int lane = threadIdx.x & 63, w = threadIdx.x >> 6;
  int n = blockIdx.x * 4 + w;
  if (n >= NN) return;
  int off = __builtin_amdgcn_readfirstlane(csr[n]);
  int end = __builtin_amdgcn_readfirstlane(csr[n + 1]);
  int c0 = lane * 2;
  float acc0 = 0.f, acc1 = 0.f, den = 0.f;
  int p = off;
  for (; p + 4 <= end; p += 4){
    int s0 = epk[p].x, s1 = epk[p+1].x, s2 = epk[p+2].x, s3 = epk[p+3].x;
    float e0 = ex2[p], e1 = ex2[p+1], e2 = ex2[p+2], e3 = ex2[p+3];
    unsigned u0 = *(const unsigned*)&xs2b[(size_t)s0 * 128 + c0];
    unsigned u1 = *(const unsigned*)&xs2b[(size_t)s1 * 128 + c0];
    unsigned u2 = *(const unsigned*)&xs2b[(size_t)s2 * 128 + c0];
    unsigned u3 = *(const unsigned*)&xs2b[(size_t)s3 * 128 + c0];
    den += (e0 + e1) + (e2 + e3);
    acc0 += e0*b2f(u0 & 0xffffu) + e1*b2f(u1 & 0xffffu)
          + e2*b2f(u2 & 0xffffu) + e3*b2f(u3 & 0xffffu);
    acc1 += e0*b2f(u0 >> 16) + e1*b2f(u1 >> 16)
          + e2*b2f(u2 >> 16) + e3*b2f(u3 >> 16);
  }
  for (; p + 2 <= end; p += 2){
    int s0 = epk[p].x, s1 = epk[p+1].x;
    float e0 = ex2[p], e1 = ex2[p+1];
    unsigned u0 = *(const unsigned*)&xs2b[(size_t)s0 * 128 + c0];
    unsigned u1 = *(const unsigned*)&xs2b[(size_t)s1 * 128 + c0];
    den += e0 + e1;
    acc0 += e0*b2f(u0 & 0xffffu) + e1*b2f(u1 & 0xffffu);
    acc1 += e0*b2f(u0 >> 16) + e1*b2f(u1 >> 16);
  }
  if (p < end){
    int s0 = epk[p].x;
    float e0 = ex2[p];
    unsigned u0 = *(const unsigned*)&xs2b[(size_t)s0 * 128 + c0];
    den += e0;
    acc0 += e0*b2f(u0 & 0xffffu);
    acc1 += e0*b2f(u0 >> 16);
  }
  float invd = 1.f / (den + 1e-16f);
  float g0 = gelu_exact(acc0 * invd + b2[c0]);
  float g1 = gelu_exact(acc1 * invd + b2[c0 + 1]);
  float s = g0 + g1;
  #pragma unroll
  for (int o = 32; o; o >>= 1) s += __shfl_xor(s, o);
  float mu = s * (1.f / 128.f);
  float e0 = g0 - mu, e1 = g1 - mu;
  float q = e0*e0 + e1*e1;
  #pragma unroll
  for (int o = 32; o; o >>= 1) q += __shfl_xor(q, o);
  float rstd = rsqrtf(q * (1.f / 128.f) + 1e-5f);
  float y0 = e0 * rstd * lng[c0] + lnb[c0];
  float y1 = e1 * rstd * lng[c0 + 1] + lnb[c0 + 1];
  float pr[12];
  #pragma unroll
  for (int j = 0; j < 8; ++j) pr[j] = y0 * pw[c0*8 + j] + y1 * pw[(c0+1)*8 + j];
  #pragma unroll
  for (int j = 0; j < 4; ++j) pr[8+j] = y0 * dwm[c0*4 + j] + y1 * dwm[(c0+1)*4 + j];
  #pragma unroll
  for (int o = 32; o; o >>= 1)
    #pragma unroll
    for (int j = 0; j < 12; ++j) pr[j] += __shfl_xor(pr[j], o);
  if (lane == 0){
    #pragma unroll
    for (int j = 0; j < 8; ++j) out[(size_t)n*8 + j] = pr[j] + pb[j];
    #pragma unroll
    for (int j = 0; j < 4; ++j) out[(size_t)NN*8 + (size_t)n*4 + j] = pr[8+j] + dbv[j];
  }
}

extern "C" void kernel_launch(void* const* d_in, const int* in_sizes, int n_in,
                              void* d_out, int out_size, void* d_ws, size_t ws_size,
                              hipStream_t stream){
  const float* nf  = (const float*)d_in[0];
  const int*   ei  = (const int*)  d_in[1];
  const float* ea  = (const float*)d_in[2];
  const float* W1  = (const float*)d_in[3];
  const float* as1 = (const float*)d_in[4];
  const float* ad1 = (const float*)d_in[5];
  const float* We1 = (const float*)d_in[6];
  const float* ae1 = (const float*)d_in[7];
  const float* b1  = (const float*)d_in[8];
  const float* W2  = (const float*)d_in[9];
  const float* as2 = (const float*)d_in[10];
  const float* ad2 = (const float*)d_in[11];
  const float* We2 = (const float*)d_in[12];
  const float* ae2 = (const float*)d_in[13];
  const float* b2  = (const float*)d_in[14];
  const float* lng = (const float*)d_in[15];
  const float* lnb = (const float*)d_in[16];
  const float* pw  = (const float*)d_in[17];
  const float* pb  = (const float*)d_in[18];
  const float* dw  = (const float*)d_in[19];
  const float* db  = (const float*)d_in[20];
  float* out = (float*)d_out;

  float* wf = (float*)d_ws;
  int*      cnt  = (int*)     (wf + CNT_O);
  int*      csr  = (int*)     (wf + CSR_O);
  int*      bsum = (int*)     (wf + BSUM_O);
  int*      boff = (int*)     (wf + BOFF_O);
  int4*     epk  = (int4*)    (wf + EPK_O);
  float4*   exf1 = (float4*)  (wf + EXF1_O);
  float*    ex2  =            (wf + EXF2_O);
  float*    ss1  =            (wf + SS1_O);
  float*    sd1  =            (wf + SD1_O);
  float*    ss2  =            (wf + SS2_O);
  float*    sd2  =            (wf + SD2_O);
  float*    Cc   =            (wf + CST_O);
  unsigned short* W1t = (unsigned short*)(wf + W1T_O);
  unsigned short* W2t = (unsigned short*)(wf + W2T_O);
  unsigned short* nfb = (unsigned short*)(wf + NFB_O);
  unsigned short* agg = (unsigned short*)(wf + AGG_O);
  unsigned short* x1  = (unsigned short*)(wf + X1_O);
  unsigned short* xs2b= (unsigned short*)(wf + XS2_O);

  hipMemsetAsync(cnt, 0, NN * sizeof(int), stream);
  k_prep<<<1, 512, 0, stream>>>(W1, as1, ad1, We1, ae1, W2, as2, ad2, We2, ae2, Cc);
  k_tw<<<(4*128*KP1 + 128*512 + 255) / 256, 256, 0, stream>>>(W1, W2, W1t, W2t);
  k_cnfs1<<<(NN + 3) / 4, 256, 0, stream>>>(nf, Cc, nfb, ss1, sd1);
  k_deg<<<(NE + 255) / 256, 256, 0, stream>>>(ei, cnt);
  k_scan1<<<SCB, 256, 0, stream>>>(cnt, bsum);
  k_scan2<<<1, 256, 0, stream>>>(bsum, boff);
  k_scan3<<<SCB, 256, 0, stream>>>(cnt, boff, csr);
  k_fill<<<(NE + 255) / 256, 256, 0, stream>>>(ei, ea, csr, cnt, epk);
  k_loopself<<<(NN + 255) / 256, 256, 0, stream>>>(csr, epk);
  k_al1<<<(ET + 255) / 256, 256, 0, stream>>>(epk, ss1, sd1, Cc, exf1);
  k_aggnf<<<(NN + 3) / 4, 256, 0, stream>>>(csr, epk, exf1, nfb, agg);
  k_mfma<1><<<dim3((NN + 127) / 128, 4), 256, 0, stream>>>(
      agg, KP1, (long)NN * KP1, W1t, (long)128 * KP1, x1, b1, NN, KP1);
  k_s2<<<(NN + 3) / 4, 256, 0, stream>>>(x1, Cc, ss2, sd2);
  k_mfma<2><<<dim3((NN + 127) / 128, 1), 256, 0, stream>>>(
      x1, 512, 0, W2t, 0, xs2b, nullptr, NN, 512);
  k_al2<<<(ET + 255) / 256, 256, 0, stream>>>(epk, ss2, sd2, Cc, ex2);
  k_agg2<<<(NN + 3) / 4, 256, 0, stream>>>(csr, epk, ex2, xs2b,
                                           b2, lng, lnb, pw, pb, dw, db, out);
}

// Round 8
// 387.397 us; speedup vs baseline: 3.1049x; 1.0035x over previous
//
#include <hip/hip_runtime.h>
#include <hip/hip_bf16.h>
#include <math.h>

#define NN 50000
#define NE 400000
#define FIN 70
#define EDIM 4
#define HIDD 128
#define NHEAD 4
constexpr int ET = NE + NN;
constexpr int KP1 = 96;           // layer-1 K padded (70 -> 96)
constexpr int NFP = 72;           // nf bf16 row pitch
constexpr int SCB = (NN + 255) / 256;   // scan blocks = 196

constexpr size_t al4(size_t x){ return (x + 3) & ~size_t(3); }
// ws offsets in 4-byte words
constexpr size_t CNT_O   = 0;                          // int[NN] (zeroed each call)
constexpr size_t ZEND    = al4(CNT_O + NN);
constexpr size_t CSR_O   = ZEND;                       // int[NN+1]
constexpr size_t BSUM_O  = al4(CSR_O + NN + 1);        // int[256]
constexpr size_t BOFF_O  = al4(BSUM_O + 256);          // int[256]
constexpr size_t EPK_O   = al4(BOFF_O + 256);          // int4[ET] {s,d,ea01,ea23}
constexpr size_t EXF1_O  = al4(EPK_O + (size_t)ET*4);  // float4[ET] exp scores L1
constexpr size_t EXF2_O  = al4(EXF1_O + (size_t)ET*4); // f32[ET]    exp scores L2
constexpr size_t SS1_O   = al4(EXF2_O + ET);           // f32[NN*4]
constexpr size_t SD1_O   = al4(SS1_O + (size_t)NN*4);
constexpr size_t SS2_O   = al4(SD1_O + (size_t)NN*4);  // f32[NN]
constexpr size_t SD2_O   = al4(SS2_O + NN);
constexpr size_t CST_O   = al4(SD2_O + NN);            // f32[2048]
constexpr size_t W1T_O   = al4(CST_O + 2048);          // bf16[4][128][96]
constexpr size_t W2T_O   = al4(W1T_O + 4*128*KP1/2);   // bf16[128][512]
constexpr size_t NFB_O   = al4(W2T_O + 128*512/2);     // bf16[NN][72]
constexpr size_t AGG_O   = al4(NFB_O + (size_t)NN*NFP/2);   // bf16[4][NN][96]
constexpr size_t X1_O    = al4(AGG_O + (size_t)4*NN*KP1/2); // bf16[NN][512]
constexpr size_t XS2_O   = al4(X1_O + (size_t)NN*512/2);    // bf16[NN][128]

// const-block sub-offsets (words, within CST)
constexpr int VS1 = 0;    // [70][4]
constexpr int VD1 = 320;  // [70][4]
constexpr int VE1 = 640;  // [4][4]
constexpr int VE2 = 656;  // [4]
constexpr int VS2 = 704;  // [512]
constexpr int VD2 = 1216; // [512]

typedef short s8v __attribute__((ext_vector_type(8)));
typedef float f4v __attribute__((ext_vector_type(4)));

__device__ __forceinline__ float gelu_exact(float x){
  return 0.5f * x * (1.f + erff(x * 0.70710678118654752440f));
}
__device__ __forceinline__ unsigned short f2b(float v){
  __hip_bfloat16 b = __float2bfloat16(v);
  return *(unsigned short*)&b;
}
__device__ __forceinline__ float b2f(unsigned u_lo16){
  return __uint_as_float(u_lo16 << 16);
}
__device__ __forceinline__ unsigned pk2(float lo, float hi){
  return (unsigned)f2b(lo) | ((unsigned)f2b(hi) << 16);
}
__device__ __forceinline__ float lrelu(float x){ return x > 0.f ? x : 0.2f * x; }

// ---- degree histogram: ONE atomic per edge ----------------------------------
__global__ void k_deg(const int* __restrict__ ei, int* __restrict__ cnt){
  int e = blockIdx.x * 256 + threadIdx.x;
  if (e >= NE) return;
  atomicAdd(&cnt[ei[NE + e]], 1);
}

// ---- CSR build: 3-phase scan of (cnt+1) -------------------------------------
__global__ void k_scan1(const int* __restrict__ cnt, int* __restrict__ bsum){
  __shared__ int ws[4];
  int t = threadIdx.x, lane = t & 63, w = t >> 6;
  int i = blockIdx.x * 256 + t;
  int v = (i < NN) ? cnt[i] + 1 : 0;
  for (int o = 32; o; o >>= 1) v += __shfl_down(v, o);
  if (lane == 0) ws[w] = v;
  __syncthreads();
  if (t == 0) bsum[blockIdx.x] = ws[0] + ws[1] + ws[2] + ws[3];
}

__global__ void k_scan2(const int* __restrict__ bsum, int* __restrict__ boff){
  __shared__ int ws[4];
  int t = threadIdx.x, lane = t & 63, w = t >> 6;
  int v = (t < SCB) ? bsum[t] : 0;
  int x = v;
  #pragma unroll
  for (int o = 1; o < 64; o <<= 1){ int u = __shfl_up(x, o); if (lane >= o) x += u; }
  if (lane == 63) ws[w] = x;
  __syncthreads();
  if (w == 0 && lane < 4){
    int y = ws[lane];
    #pragma unroll
    for (int o = 1; o < 4; o <<= 1){ int u = __shfl_up(y, o); if (lane >= o) y += u; }
    ws[lane] = y;
  }
  __syncthreads();
  int incl = x + (w > 0 ? ws[w - 1] : 0);
  if (t < SCB) boff[t] = incl - v;
}

__global__ void k_scan3(const int* __restrict__ cnt, const int* __restrict__ boff,
                        int* __restrict__ csr){
  __shared__ int ws[4];
  int t = threadIdx.x, lane = t & 63, w = t >> 6;
  int i = blockIdx.x * 256 + t;
  int v = (i < NN) ? cnt[i] + 1 : 0;
  int x = v;
  #pragma unroll
  for (int o = 1; o < 64; o <<= 1){ int u = __shfl_up(x, o); if (lane >= o) x += u; }
  if (lane == 63) ws[w] = x;
  __syncthreads();
  if (w == 0 && lane < 4){
    int y = ws[lane];
    #pragma unroll
    for (int o = 1; o < 4; o <<= 1){ int u = __shfl_up(y, o); if (lane >= o) y += u; }
    ws[lane] = y;
  }
  __syncthreads();
  if (i < NN) csr[i + 1] = boff[blockIdx.x] + (w > 0 ? ws[w - 1] : 0) + x;
  if (i == 0) csr[0] = 0;
}

// ---- fill CSR slots + FUSED layer-1 alpha; consumes cnt -> 0 ----------------
__global__ void k_fill(const int* __restrict__ ei, const float* __restrict__ ea,
                       const int* __restrict__ csr, int* __restrict__ cnt,
                       int4* __restrict__ epk, const float* __restrict__ ss1,
                       const float* __restrict__ sd1, const float* __restrict__ C,
                       float4* __restrict__ exf){
  int e = blockIdx.x * 256 + threadIdx.x;
  if (e >= NE) return;
  int s = ei[e], d = ei[NE + e];
  int r = atomicSub(&cnt[d], 1);        // r in [deg..1]
  int p = csr[d] + r - 1;
  float4 a = *(const float4*)&ea[(size_t)e * 4];
  epk[p] = make_int4(s, d, (int)pk2(a.x, a.y), (int)pk2(a.z, a.w));
  float4 ssv = *(const float4*)&ss1[(size_t)s * 4];
  float4 sdv = *(const float4*)&sd1[(size_t)d * 4];
  float e0 = __expf(lrelu(ssv.x + sdv.x + a.x*C[VE1+0] + a.y*C[VE1+4] + a.z*C[VE1+8]  + a.w*C[VE1+12]));
  float e1 = __expf(lrelu(ssv.y + sdv.y + a.x*C[VE1+1] + a.y*C[VE1+5] + a.z*C[VE1+9]  + a.w*C[VE1+13]));
  float e2 = __expf(lrelu(ssv.z + sdv.z + a.x*C[VE1+2] + a.y*C[VE1+6] + a.z*C[VE1+10] + a.w*C[VE1+14]));
  float e3 = __expf(lrelu(ssv.w + sdv.w + a.x*C[VE1+3] + a.y*C[VE1+7] + a.z*C[VE1+11] + a.w*C[VE1+15]));
  exf[p] = make_float4(e0, e1, e2, e3);
}

// ---- per-node: self-loop attr = mean of real-edge attrs + self alpha --------
__global__ void k_loopself(const int* __restrict__ csr, int4* __restrict__ epk,
                           const float* __restrict__ ss1, const float* __restrict__ sd1,
                           const float* __restrict__ C, float4* __restrict__ exf){
  int n = blockIdx.x * 256 + threadIdx.x;
  if (n >= NN) return;
  int a = csr[n], b = csr[n + 1];
  int deg = b - a - 1;
  float s0 = 0.f, s1 = 0.f, s2 = 0.f, s3 = 0.f;
  for (int p = a; p < b - 1; ++p){
    int4 v = epk[p];
    s0 += b2f((unsigned)v.z & 0xffffu); s1 += b2f((unsigned)v.z >> 16);
    s2 += b2f((unsigned)v.w & 0xffffu); s3 += b2f((unsigned)v.w >> 16);
  }
  float inv = 1.f / (float)(deg > 1 ? deg : 1);
  float m0 = s0*inv, m1 = s1*inv, m2 = s2*inv, m3 = s3*inv;
  epk[b - 1] = make_int4(n, n, (int)pk2(m0, m1), (int)pk2(m2, m3));
  float4 ssv = *(const float4*)&ss1[(size_t)n * 4];
  float4 sdv = *(const float4*)&sd1[(size_t)n * 4];
  float e0 = __expf(lrelu(ssv.x + sdv.x + m0*C[VE1+0] + m1*C[VE1+4] + m2*C[VE1+8]  + m3*C[VE1+12]));
  float e1 = __expf(lrelu(ssv.y + sdv.y + m0*C[VE1+1] + m1*C[VE1+5] + m2*C[VE1+9]  + m3*C[VE1+13]));
  float e2 = __expf(lrelu(ssv.z + sdv.z + m0*C[VE1+2] + m1*C[VE1+6] + m2*C[VE1+10] + m3*C[VE1+14]));
  float e3 = __expf(lrelu(ssv.w + sdv.w + m0*C[VE1+3] + m1*C[VE1+7] + m2*C[VE1+11] + m3*C[VE1+15]));
  exf[b - 1] = make_float4(e0, e1, e2, e3);
}

// ---- tiny weight pre-reductions --------------------------------------------
__global__ void k_prep(const float* __restrict__ W1, const float* __restrict__ as1,
                       const float* __restrict__ ad1, const float* __restrict__ We1,
                       const float* __restrict__ ae1, const float* __restrict__ W2,
                       const float* __restrict__ as2, const float* __restrict__ ad2,
                       const float* __restrict__ We2, const float* __restrict__ ae2,
                       float* __restrict__ C){
  int t = threadIdx.x;                       // block of 512
  if (t < 280){
    int k = t >> 2, h = t & 3;
    float s = 0.f, d = 0.f;
    for (int dd = 0; dd < 128; ++dd){
      float w = W1[k*512 + h*128 + dd];
      s += w * as1[h*128 + dd];
      d += w * ad1[h*128 + dd];
    }
    C[VS1 + t] = s; C[VD1 + t] = d;
  }
  if (t < 16){
    int k = t >> 2, h = t & 3;
    float s = 0.f;
    for (int dd = 0; dd < 128; ++dd) s += We1[k*512 + h*128 + dd] * ae1[h*128 + dd];
    C[VE1 + t] = s;
  }
  if (t < 4){
    float s = 0.f;
    for (int dd = 0; dd < 128; ++dd) s += We2[t*128 + dd] * ae2[dd];
    C[VE2 + t] = s;
  }
  {
    float s = 0.f, d = 0.f;
    for (int dd = 0; dd < 128; ++dd){
      float w = W2[t*128 + dd];
      s += w * as2[dd];
      d += w * ad2[dd];
    }
    C[VS2 + t] = s; C[VD2 + t] = d;
  }
}

// ---- transpose + bf16-cast weights -----------------------------------------
__global__ void k_tw(const float* __restrict__ W1, const float* __restrict__ W2,
                     unsigned short* __restrict__ W1t, unsigned short* __restrict__ W2t){
  int i = blockIdx.x * 256 + threadIdx.x;
  if (i < 4*128*KP1){
    int k = i % KP1, n = (i / KP1) & 127, h = i / (KP1*128);
    float v = (k < FIN) ? W1[k*512 + h*128 + n] : 0.f;
    W1t[i] = f2b(v);
  } else {
    int j = i - 4*128*KP1;
    if (j < 128*512){
      int k = j & 511, n = j >> 9;
      W2t[j] = f2b(W2[k*128 + n]);
    }
  }
}

// ---- fused: nf -> bf16 (pitch 72) + layer1 attention scalars ----------------
__global__ __launch_bounds__(256) void k_cnfs1(const float* __restrict__ nf,
    const float* __restrict__ C, unsigned short* __restrict__ nfb,
    float* __restrict__ ss1, float* __restrict__ sd1){
  int lane = threadIdx.x & 63, w = threadIdx.x >> 6;
  int n = blockIdx.x * 4 + w;
  if (n >= NN) return;
  int c0 = lane * 2;
  bool act = lane < 35;                 // cols 0..69
  float v0 = 0.f, v1 = 0.f;
  if (act){
    v0 = nf[(size_t)n * FIN + c0];
    v1 = nf[(size_t)n * FIN + c0 + 1];
  }
  if (lane < 36) *(unsigned*)&nfb[(size_t)n * NFP + c0] = act ? pk2(v0, v1) : 0u;
  float sh[4] = {0,0,0,0}, dh[4] = {0,0,0,0};
  if (act){
    float4 cs0 = *(const float4*)&C[VS1 + c0*4];
    float4 cs1 = *(const float4*)&C[VS1 + (c0+1)*4];
    float4 cd0 = *(const float4*)&C[VD1 + c0*4];
    float4 cd1 = *(const float4*)&C[VD1 + (c0+1)*4];
    sh[0] = v0*cs0.x + v1*cs1.x; sh[1] = v0*cs0.y + v1*cs1.y;
    sh[2] = v0*cs0.z + v1*cs1.z; sh[3] = v0*cs0.w + v1*cs1.w;
    dh[0] = v0*cd0.x + v1*cd1.x; dh[1] = v0*cd0.y + v1*cd1.y;
    dh[2] = v0*cd0.z + v1*cd1.z; dh[3] = v0*cd0.w + v1*cd1.w;
  }
  #pragma unroll
  for (int o = 32; o; o >>= 1){
    #pragma unroll
    for (int h = 0; h < 4; ++h){
      sh[h] += __shfl_xor(sh[h], o);
      dh[h] += __shfl_xor(dh[h], o);
    }
  }
  if (lane == 0){
    *(float4*)&ss1[(size_t)n*4] = make_float4(sh[0], sh[1], sh[2], sh[3]);
    *(float4*)&sd1[(size_t)n*4] = make_float4(dh[0], dh[1], dh[2], dh[3]);
  }
}

// ---- edge-parallel alpha (layer 2) ------------------------------------------
__global__ void k_al2(const int4* __restrict__ epk, const float* __restrict__ ss2,
                      const float* __restrict__ sd2, const float* __restrict__ C,
                      float* __restrict__ ex2){
  int p = blockIdx.x * 256 + threadIdx.x;
  if (p >= ET) return;
  int4 pk = epk[p];
  int s = pk.x, d = pk.y;
  float ax = b2f((unsigned)pk.z & 0xffffu), ay = b2f((unsigned)pk.z >> 16);
  float az = b2f((unsigned)pk.w & 0xffffu), aw = b2f((unsigned)pk.w >> 16);
  ex2[p] = __expf(lrelu(ss2[s] + sd2[d] +
             ax*C[VE2] + ay*C[VE2+1] + az*C[VE2+2] + aw*C[VE2+3]));
}

// ---- MFMA GEMM: C[M,128] = A[M,KP] @ Bt^T, 128x128 tile, 4 waves ------------
// LDS-staged coalesced bf16 epilogue (2 passes of 64 rows, dwordx4 stores)
template<int MODE>
__global__ __launch_bounds__(256) void k_mfma(
    const unsigned short* __restrict__ A, int lda, long aSz,
    const unsigned short* __restrict__ Bt, long bSz,
    void* __restrict__ Cout, const float* __restrict__ bias,
    int M, int KP){
  int z = blockIdx.y;
  A  += (size_t)z * aSz;
  Bt += (size_t)z * bSz;
  __shared__ unsigned short sm[10240];   // As[5120] | Bs[5120]; reused as Cs[64*136]
  unsigned short* As = sm;
  unsigned short* Bs = sm + 5120;
  int tid = threadIdx.x, lane = tid & 63, w = tid >> 6;
  int wm = w & 1, wn = w >> 1;
  int row0 = blockIdx.x * 128;
  f4v acc[4][4] = {};
  int r4 = tid >> 2, c4 = tid & 3;
  for (int k0 = 0; k0 < KP; k0 += 32){
    #pragma unroll
    for (int half = 0; half < 2; ++half){
      int r = r4 + half * 64;
      int gr = row0 + r;
      uint4 va = make_uint4(0,0,0,0);
      if (gr < M) va = *(const uint4*)&A[(size_t)gr * lda + k0 + c4*8];
      *(uint4*)&As[r*40 + c4*8] = va;
      uint4 vb = *(const uint4*)&Bt[(size_t)r * lda + k0 + c4*8];
      *(uint4*)&Bs[r*40 + c4*8] = vb;
    }
    __syncthreads();
    s8v af[4], bf[4];
    #pragma unroll
    for (int i = 0; i < 4; ++i){
      af[i] = *(const s8v*)&As[(wm*64 + i*16 + (lane & 15))*40 + (lane >> 4)*8];
      bf[i] = *(const s8v*)&Bs[(wn*64 + i*16 + (lane & 15))*40 + (lane >> 4)*8];
    }
    #pragma unroll
    for (int mi = 0; mi < 4; ++mi)
      #pragma unroll
      for (int ni = 0; ni < 4; ++ni)
        acc[mi][ni] = __builtin_amdgcn_mfma_f32_16x16x32_bf16(af[mi], bf[ni], acc[mi][ni], 0, 0, 0);
    __syncthreads();
  }
  int cq = lane & 15, rq = lane >> 4;
  float bv[4];
  if (MODE == 1){
    #pragma unroll
    for (int ni = 0; ni < 4; ++ni) bv[ni] = bias[z*128 + wn*64 + ni*16 + cq];
  }
  #pragma unroll
  for (int pass = 0; pass < 2; ++pass){
    if (wm == pass){
      #pragma unroll
      for (int mi = 0; mi < 4; ++mi)
        #pragma unroll
        for (int r = 0; r < 4; ++r){
          int lr = mi*16 + rq*4 + r;          // 0..63
          #pragma unroll
          for (int ni = 0; ni < 4; ++ni){
            float v = acc[mi][ni][r];
            if (MODE == 1) v = gelu_exact(v + bv[ni]);
            sm[lr*136 + wn*64 + ni*16 + cq] = f2b(v);
          }
        }
    }
    __syncthreads();
    #pragma unroll
    for (int j = 0; j < 4; ++j){
      int cid = tid + j*256;                  // 0..1023
      int lr = cid >> 4, ch = cid & 15;
      int grow = row0 + pass*64 + lr;
      if (grow < M){
        uint4 v = *(const uint4*)&sm[lr*136 + ch*8];
        if (MODE == 1)
          *(uint4*)&((unsigned short*)Cout)[(size_t)grow*512 + z*128 + ch*8] = v;
        else
          *(uint4*)&((unsigned short*)Cout)[(size_t)grow*128 + ch*8] = v;
      }
    }
    __syncthreads();
  }
}

// ---- layer1 aggregation: wave/node, 2-edge pipelined gather -----------------
__global__ __launch_bounds__(256) void k_aggnf(const int* __restrict__ csr,
    const int4* __restrict__ epk, const float4* __restrict__ exf,
    const unsigned short* __restrict__ nfb, unsigned short* __restrict__ agg){
  int lane = threadIdx.x & 63, w = threadIdx.x >> 6;
  int n = blockIdx.x * 4 + w;
  if (n >= NN) return;
  int off = __builtin_amdgcn_readfirstlane(csr[n]);
  int end = __builtin_amdgcn_readfirstlane(csr[n + 1]);
  int col = lane * 2;
  bool act = lane < 36;
  float d0=0,d1=0,d2=0,d3=0;
  float a00=0,a01=0,a10=0,a11=0,a20=0,a21=0,a30=0,a31=0;
  int p = off;
  for (; p + 2 <= end; p += 2){
    int s0 = epk[p].x, s1 = epk[p+1].x;
    float4 e0 = exf[p], e1 = exf[p+1];
    unsigned u0 = 0, u1 = 0;
    if (act){
      u0 = *(const unsigned*)&nfb[(size_t)s0 * NFP + col];
      u1 = *(const unsigned*)&nfb[(size_t)s1 * NFP + col];
    }
    d0 += e0.x + e1.x; d1 += e0.y + e1.y; d2 += e0.z + e1.z; d3 += e0.w + e1.w;
    float v00 = b2f(u0 & 0xffffu), v01 = b2f(u0 >> 16);
    float v10 = b2f(u1 & 0xffffu), v11 = b2f(u1 >> 16);
    a00 += e0.x*v00 + e1.x*v10; a01 += e0.x*v01 + e1.x*v11;
    a10 += e0.y*v00 + e1.y*v10; a11 += e0.y*v01 + e1.y*v11;
    a20 += e0.z*v00 + e1.z*v10; a21 += e0.z*v01 + e1.z*v11;
    a30 += e0.w*v00 + e1.w*v10; a31 += e0.w*v01 + e1.w*v11;
  }
  if (p < end){
    int s0 = epk[p].x;
    float4 e0 = exf[p];
    unsigned u0 = 0;
    if (act) u0 = *(const unsigned*)&nfb[(size_t)s0 * NFP + col];
    d0 += e0.x; d1 += e0.y; d2 += e0.z; d3 += e0.w;
    float v00 = b2f(u0 & 0xffffu), v01 = b2f(u0 >> 16);
    a00 += e0.x*v00; a01 += e0.x*v01;
    a10 += e0.y*v00; a11 += e0.y*v01;
    a20 += e0.z*v00; a21 += e0.z*v01;
    a30 += e0.w*v00; a31 += e0.w*v01;
  }
  float i0 = 1.f/(d0+1e-16f), i1 = 1.f/(d1+1e-16f);
  float i2 = 1.f/(d2+1e-16f), i3 = 1.f/(d3+1e-16f);
  constexpr size_t HS = (size_t)NN * KP1;
  size_t base = (size_t)n * KP1 + col;
  if (act){
    *(unsigned*)&agg[base]        = pk2(a00*i0, a01*i0);
    *(unsigned*)&agg[base +   HS] = pk2(a10*i1, a11*i1);
    *(unsigned*)&agg[base + 2*HS] = pk2(a20*i2, a21*i2);
    *(unsigned*)&agg[base + 3*HS] = pk2(a30*i3, a31*i3);
  } else if (lane < 48){                // zero cols 72..95
    *(unsigned*)&agg[base]        = 0u;
    *(unsigned*)&agg[base +   HS] = 0u;
    *(unsigned*)&agg[base + 2*HS] = 0u;
    *(unsigned*)&agg[base + 3*HS] = 0u;
  }
}

// ---- layer2 attention scalars (x1 is bf16) ----------------------------------
__global__ void k_s2(const unsigned short* __restrict__ x1, const float* __restrict__ C,
                     float* __restrict__ ss2, float* __restrict__ sd2){
  int tid = threadIdx.x, lane = tid & 63;
  int n = blockIdx.x * 4 + (tid >> 6);
  if (n >= NN) return;
  uint4 xv = *(const uint4*)&x1[(size_t)n * 512 + lane * 8];
  float xf[8];
  xf[0] = b2f(xv.x & 0xffffu); xf[1] = b2f(xv.x >> 16);
  xf[2] = b2f(xv.y & 0xffffu); xf[3] = b2f(xv.y >> 16);
  xf[4] = b2f(xv.z & 0xffffu); xf[5] = b2f(xv.z >> 16);
  xf[6] = b2f(xv.w & 0xffffu); xf[7] = b2f(xv.w >> 16);
  float s = 0.f, d = 0.f;
  #pragma unroll
  for (int j = 0; j < 8; ++j){
    s += xf[j] * C[VS2 + lane*8 + j];
    d += xf[j] * C[VD2 + lane*8 + j];
  }
  for (int o = 32; o; o >>= 1){ s += __shfl_down(s, o); d += __shfl_down(d, o); }
  if (lane == 0){ ss2[n] = s; sd2[n] = d; }
}

// ---- layer2 aggregation: 4-edge pipelined gather + GELU + LN + projections --
__global__ __launch_bounds__(256) void k_agg2(
    const int* __restrict__ csr, const int4* __restrict__ epk,
    const float* __restrict__ ex2, const unsigned short* __restrict__ xs2b,
    const float* __restrict__ b2, const float* __restrict__ lng,
    const float* __restrict__ lnb, const float* __restrict__ pw,
    const float* __restrict__ pb, const float* __restrict__ dwm,
    const float* __restrict__ dbv, float* __restrict__ out){
  int lane = threadIdx.x & 63, w = threadIdx.x >> 6;
  int n = blockIdx.x * 4 + w;
  if (n >= NN) return;
  int off = __builtin_amdgcn_readfirstlane(csr[n]);
  int end = __builtin_amdgcn_readfirstlane(csr[n + 1]);
  int c0 = lane * 2;
  float acc0 = 0.f, acc1 = 0.f, den = 0.f;
  int p = off;
  for (; p + 4 <= end; p += 4){
    int s0 = epk[p].x, s1 = epk[p+1].x, s2 = epk[p+2].x, s3 = epk[p+3].x;
    float e0 = ex2[p], e1 = ex2[p+1], e2 = ex2[p+2], e3 = ex2[p+3];
    unsigned u0 = *(const unsigned*)&xs2b[(size_t)s0 * 128 + c0];
    unsigned u1 = *(const unsigned*)&xs2b[(size_t)s1 * 128 + c0];
    unsigned u2 = *(const unsigned*)&xs2b[(size_t)s2 * 128 + c0];
    unsigned u3 = *(const unsigned*)&xs2b[(size_t)s3 * 128 + c0];
    den += (e0 + e1) + (e2 + e3);
    acc0 += e0*b2f(u0 & 0xffffu) + e1*b2f(u1 & 0xffffu)
          + e2*b2f(u2 & 0xffffu) + e3*b2f(u3 & 0xffffu);
    acc1 += e0*b2f(u0 >> 16) + e1*b2f(u1 >> 16)
          + e2*b2f(u2 >> 16) + e3*b2f(u3 >> 16);
  }
  for (; p + 2 <= end; p += 2){
    int s0 = epk[p].x, s1 = epk[p+1].x;
    float e0 = ex2[p], e1 = ex2[p+1];
    unsigned u0 = *(const unsigned*)&xs2b[(size_t)s0 * 128 + c0];
    unsigned u1 = *(const unsigned*)&xs2b[(size_t)s1 * 128 + c0];
    den += e0 + e1;
    acc0 += e0*b2f(u0 & 0xffffu) + e1*b2f(u1 & 0xffffu);
    acc1 += e0*b2f(u0 >> 16) + e1*b2f(u1 >> 16);
  }
  if (p < end){
    int s0 = epk[p].x;
    float e0 = ex2[p];
    unsigned u0 = *(const unsigned*)&xs2b[(size_t)s0 * 128 + c0];
    den += e0;
    acc0 += e0*b2f(u0 & 0xffffu);
    acc1 += e0*b2f(u0 >> 16);
  }
  float invd = 1.f / (den + 1e-16f);
  float g0 = gelu_exact(acc0 * invd + b2[c0]);
  float g1 = gelu_exact(acc1 * invd + b2[c0 + 1]);
  float s = g0 + g1;
  #pragma unroll
  for (int o = 32; o; o >>= 1) s += __shfl_xor(s, o);
  float mu = s * (1.f / 128.f);
  float e0 = g0 - mu, e1 = g1 - mu;
  float q = e0*e0 + e1*e1;
  #pragma unroll
  for (int o = 32; o; o >>= 1) q += __shfl_xor(q, o);
  float rstd = rsqrtf(q * (1.f / 128.f) + 1e-5f);
  float y0 = e0 * rstd * lng[c0] + lnb[c0];
  float y1 = e1 * rstd * lng[c0 + 1] + lnb[c0 + 1];
  float pr[12];
  #pragma unroll
  for (int j = 0; j < 8; ++j) pr[j] = y0 * pw[c0*8 + j] + y1 * pw[(c0+1)*8 + j];
  #pragma unroll
  for (int j = 0; j < 4; ++j) pr[8+j] = y0 * dwm[c0*4 + j] + y1 * dwm[(c0+1)*4 + j];
  #pragma unroll
  for (int o = 32; o; o >>= 1)
    #pragma unroll
    for (int j = 0; j < 12; ++j) pr[j] += __shfl_xor(pr[j], o);
  if (lane == 0){
    #pragma unroll
    for (int j = 0; j < 8; ++j) out[(size_t)n*8 + j] = pr[j] + pb[j];
    #pragma unroll
    for (int j = 0; j < 4; ++j) out[(size_t)NN*8 + (size_t)n*4 + j] = pr[8+j] + dbv[j];
  }
}

extern "C" void kernel_launch(void* const* d_in, const int* in_sizes, int n_in,
                              void* d_out, int out_size, void* d_ws, size_t ws_size,
                              hipStream_t stream){
  const float* nf  = (const float*)d_in[0];
  const int*   ei  = (const int*)  d_in[1];
  const float* ea  = (const float*)d_in[2];
  const float* W1  = (const float*)d_in[3];
  const float* as1 = (const float*)d_in[4];
  const float* ad1 = (const float*)d_in[5];
  const float* We1 = (const float*)d_in[6];
  const float* ae1 = (const float*)d_in[7];
  const float* b1  = (const float*)d_in[8];
  const float* W2  = (const float*)d_in[9];
  const float* as2 = (const float*)d_in[10];
  const float* ad2 = (const float*)d_in[11];
  const float* We2 = (const float*)d_in[12];
  const float* ae2 = (const float*)d_in[13];
  const float* b2  = (const float*)d_in[14];
  const float* lng = (const float*)d_in[15];
  const float* lnb = (const float*)d_in[16];
  const float* pw  = (const float*)d_in[17];
  const float* pb  = (const float*)d_in[18];
  const float* dw  = (const float*)d_in[19];
  const float* db  = (const float*)d_in[20];
  float* out = (float*)d_out;

  float* wf = (float*)d_ws;
  int*      cnt  = (int*)     (wf + CNT_O);
  int*      csr  = (int*)     (wf + CSR_O);
  int*      bsum = (int*)     (wf + BSUM_O);
  int*      boff = (int*)     (wf + BOFF_O);
  int4*     epk  = (int4*)    (wf + EPK_O);
  float4*   exf1 = (float4*)  (wf + EXF1_O);
  float*    ex2  =            (wf + EXF2_O);
  float*    ss1  =            (wf + SS1_O);
  float*    sd1  =            (wf + SD1_O);
  float*    ss2  =            (wf + SS2_O);
  float*    sd2  =            (wf + SD2_O);
  float*    Cc   =            (wf + CST_O);
  unsigned short* W1t = (unsigned short*)(wf + W1T_O);
  unsigned short* W2t = (unsigned short*)(wf + W2T_O);
  unsigned short* nfb = (unsigned short*)(wf + NFB_O);
  unsigned short* agg = (unsigned short*)(wf + AGG_O);
  unsigned short* x1  = (unsigned short*)(wf + X1_O);
  unsigned short* xs2b= (unsigned short*)(wf + XS2_O);

  hipMemsetAsync(cnt, 0, NN * sizeof(int), stream);
  k_prep<<<1, 512, 0, stream>>>(W1, as1, ad1, We1, ae1, W2, as2, ad2, We2, ae2, Cc);
  k_tw<<<(4*128*KP1 + 128*512 + 255) / 256, 256, 0, stream>>>(W1, W2, W1t, W2t);
  k_cnfs1<<<(NN + 3) / 4, 256, 0, stream>>>(nf, Cc, nfb, ss1, sd1);
  k_deg<<<(NE + 255) / 256, 256, 0, stream>>>(ei, cnt);
  k_scan1<<<SCB, 256, 0, stream>>>(cnt, bsum);
  k_scan2<<<1, 256, 0, stream>>>(bsum, boff);
  k_scan3<<<SCB, 256, 0, stream>>>(cnt, boff, csr);
  k_fill<<<(NE + 255) / 256, 256, 0, stream>>>(ei, ea, csr, cnt, epk, ss1, sd1, Cc, exf1);
  k_loopself<<<(NN + 255) / 256, 256, 0, stream>>>(csr, epk, ss1, sd1, Cc, exf1);
  k_aggnf<<<(NN + 3) / 4, 256, 0, stream>>>(csr, epk, exf1, nfb, agg);
  k_mfma<1><<<dim3((NN + 127) / 128, 4), 256, 0, stream>>>(
      agg, KP1, (long)NN * KP1, W1t, (long)128 * KP1, x1, b1, NN, KP1);
  k_s2<<<(NN + 3) / 4, 256, 0, stream>>>(x1, Cc, ss2, sd2);
  k_mfma<2><<<dim3((NN + 127) / 128, 1), 256, 0, stream>>>(
      x1, 512, 0, W2t, 0, xs2b, nullptr, NN, 512);
  k_al2<<<(ET + 255) / 256, 256, 0, stream>>>(epk, ss2, sd2, Cc, ex2);
  k_agg2<<<(NN + 3) / 4, 256, 0, stream>>>(csr, epk, ex2, xs2b,
                                           b2, lng, lnb, pw, pb, dw, db, out);
}

// Round 9
// 372.889 us; speedup vs baseline: 3.2257x; 1.0389x over previous
//
#include <hip/hip_runtime.h>
#include <hip/hip_bf16.h>
#include <math.h>

#define NN 50000
#define NE 400000
#define FIN 70
#define EDIM 4
#define HIDD 128
#define NHEAD 4
constexpr int ET = NE + NN;
constexpr int KP1 = 96;           // layer-1 K padded (70 -> 96)
constexpr int NFP = 72;           // nf bf16 row pitch
constexpr int SCB = (NN + 255) / 256;   // scan blocks = 196

constexpr size_t al4(size_t x){ return (x + 3) & ~size_t(3); }
// ws offsets in 4-byte words
constexpr size_t CNT_O   = 0;                          // int[NN] (zeroed each call)
constexpr size_t ZEND    = al4(CNT_O + NN);
constexpr size_t CSR_O   = ZEND;                       // int[NN+1]
constexpr size_t BSUM_O  = al4(CSR_O + NN + 1);        // int[256]
constexpr size_t BOFF_O  = al4(BSUM_O + 256);          // int[256]
constexpr size_t EPK_O   = al4(BOFF_O + 256);          // int4[ET] {s,d,ea01,ea23}
constexpr size_t EXF1_O  = al4(EPK_O + (size_t)ET*4);  // float4[ET] exp scores L1
constexpr size_t EXF2_O  = al4(EXF1_O + (size_t)ET*4); // f32[ET]    exp scores L2
constexpr size_t SS1_O   = al4(EXF2_O + ET);           // f32[NN*4]
constexpr size_t SD1_O   = al4(SS1_O + (size_t)NN*4);
constexpr size_t SS2_O   = al4(SD1_O + (size_t)NN*4);  // f32[NN]
constexpr size_t SD2_O   = al4(SS2_O + NN);
constexpr size_t CST_O   = al4(SD2_O + NN);            // f32[2048]
constexpr size_t W1T_O   = al4(CST_O + 2048);          // bf16[4][128][96]
constexpr size_t W2T_O   = al4(W1T_O + 4*128*KP1/2);   // bf16[128][512]
constexpr size_t NFB_O   = al4(W2T_O + 128*512/2);     // bf16[NN][72]
constexpr size_t AGG_O   = al4(NFB_O + (size_t)NN*NFP/2);   // bf16[4][NN][96]
constexpr size_t X1_O    = al4(AGG_O + (size_t)4*NN*KP1/2); // bf16[NN][512]
constexpr size_t XS2_O   = al4(X1_O + (size_t)NN*512/2);    // bf16[NN][128]

// const-block sub-offsets (words, within CST)
constexpr int VS1 = 0;    // [70][4]
constexpr int VD1 = 320;  // [70][4]
constexpr int VE1 = 640;  // [4][4]
constexpr int VE2 = 656;  // [4]
constexpr int VS2 = 704;  // [512]
constexpr int VD2 = 1216; // [512]

typedef short s8v __attribute__((ext_vector_type(8)));
typedef float f4v __attribute__((ext_vector_type(4)));

__device__ __forceinline__ unsigned short f2b(float v){
  __hip_bfloat16 b = __float2bfloat16(v);
  return *(unsigned short*)&b;
}
__device__ __forceinline__ float b2f(unsigned u_lo16){
  return __uint_as_float(u_lo16 << 16);
}
__device__ __forceinline__ unsigned pk2(float lo, float hi){
  return (unsigned)f2b(lo) | ((unsigned)f2b(hi) << 16);
}
__device__ __forceinline__ float lrelu(float x){ return x > 0.f ? x : 0.2f * x; }

// erf via A&S 7.1.26 (|err|<1.5e-7), one fast v_exp — avoids libm erff
__device__ __forceinline__ float gelu_fast(float x){
  float z = x * 0.70710678118654752440f;
  float a = fabsf(z);
  float t = 1.f / (1.f + 0.3275911f * a);
  float p = ((((1.061405429f*t - 1.453152027f)*t + 1.421413741f)*t
              - 0.284496736f)*t + 0.254829592f)*t;
  float erfv = 1.f - p * __expf(-a * a);
  erfv = copysignf(erfv, z);
  return 0.5f * x * (1.f + erfv);
}

// async global->LDS, 16B per lane; lptr must be wave-uniform base
__device__ __forceinline__ void gl16(const unsigned short* g, unsigned short* l){
  __builtin_amdgcn_global_load_lds(
      (const __attribute__((address_space(1))) unsigned int*)g,
      (__attribute__((address_space(3))) unsigned int*)l, 16, 0, 0);
}

// ---- degree histogram: ONE atomic per edge ----------------------------------
__global__ void k_deg(const int* __restrict__ ei, int* __restrict__ cnt){
  int e = blockIdx.x * 256 + threadIdx.x;
  if (e >= NE) return;
  atomicAdd(&cnt[ei[NE + e]], 1);
}

// ---- CSR build: 3-phase scan of (cnt+1) -------------------------------------
__global__ void k_scan1(const int* __restrict__ cnt, int* __restrict__ bsum){
  __shared__ int ws[4];
  int t = threadIdx.x, lane = t & 63, w = t >> 6;
  int i = blockIdx.x * 256 + t;
  int v = (i < NN) ? cnt[i] + 1 : 0;
  for (int o = 32; o; o >>= 1) v += __shfl_down(v, o);
  if (lane == 0) ws[w] = v;
  __syncthreads();
  if (t == 0) bsum[blockIdx.x] = ws[0] + ws[1] + ws[2] + ws[3];
}

__global__ void k_scan2(const int* __restrict__ bsum, int* __restrict__ boff){
  __shared__ int ws[4];
  int t = threadIdx.x, lane = t & 63, w = t >> 6;
  int v = (t < SCB) ? bsum[t] : 0;
  int x = v;
  #pragma unroll
  for (int o = 1; o < 64; o <<= 1){ int u = __shfl_up(x, o); if (lane >= o) x += u; }
  if (lane == 63) ws[w] = x;
  __syncthreads();
  if (w == 0 && lane < 4){
    int y = ws[lane];
    #pragma unroll
    for (int o = 1; o < 4; o <<= 1){ int u = __shfl_up(y, o); if (lane >= o) y += u; }
    ws[lane] = y;
  }
  __syncthreads();
  int incl = x + (w > 0 ? ws[w - 1] : 0);
  if (t < SCB) boff[t] = incl - v;
}

__global__ void k_scan3(const int* __restrict__ cnt, const int* __restrict__ boff,
                        int* __restrict__ csr){
  __shared__ int ws[4];
  int t = threadIdx.x, lane = t & 63, w = t >> 6;
  int i = blockIdx.x * 256 + t;
  int v = (i < NN) ? cnt[i] + 1 : 0;
  int x = v;
  #pragma unroll
  for (int o = 1; o < 64; o <<= 1){ int u = __shfl_up(x, o); if (lane >= o) x += u; }
  if (lane == 63) ws[w] = x;
  __syncthreads();
  if (w == 0 && lane < 4){
    int y = ws[lane];
    #pragma unroll
    for (int o = 1; o < 4; o <<= 1){ int u = __shfl_up(y, o); if (lane >= o) y += u; }
    ws[lane] = y;
  }
  __syncthreads();
  if (i < NN) csr[i + 1] = boff[blockIdx.x] + (w > 0 ? ws[w - 1] : 0) + x;
  if (i == 0) csr[0] = 0;
}

// ---- fill CSR slots + FUSED layer-1 alpha; consumes cnt -> 0 ----------------
__global__ void k_fill(const int* __restrict__ ei, const float* __restrict__ ea,
                       const int* __restrict__ csr, int* __restrict__ cnt,
                       int4* __restrict__ epk, const float* __restrict__ ss1,
                       const float* __restrict__ sd1, const float* __restrict__ C,
                       float4* __restrict__ exf){
  int e = blockIdx.x * 256 + threadIdx.x;
  if (e >= NE) return;
  int s = ei[e], d = ei[NE + e];
  int r = atomicSub(&cnt[d], 1);        // r in [deg..1]
  int p = csr[d] + r - 1;
  float4 a = *(const float4*)&ea[(size_t)e * 4];
  epk[p] = make_int4(s, d, (int)pk2(a.x, a.y), (int)pk2(a.z, a.w));
  float4 ssv = *(const float4*)&ss1[(size_t)s * 4];
  float4 sdv = *(const float4*)&sd1[(size_t)d * 4];
  float e0 = __expf(lrelu(ssv.x + sdv.x + a.x*C[VE1+0] + a.y*C[VE1+4] + a.z*C[VE1+8]  + a.w*C[VE1+12]));
  float e1 = __expf(lrelu(ssv.y + sdv.y + a.x*C[VE1+1] + a.y*C[VE1+5] + a.z*C[VE1+9]  + a.w*C[VE1+13]));
  float e2 = __expf(lrelu(ssv.z + sdv.z + a.x*C[VE1+2] + a.y*C[VE1+6] + a.z*C[VE1+10] + a.w*C[VE1+14]));
  float e3 = __expf(lrelu(ssv.w + sdv.w + a.x*C[VE1+3] + a.y*C[VE1+7] + a.z*C[VE1+11] + a.w*C[VE1+15]));
  exf[p] = make_float4(e0, e1, e2, e3);
}

// ---- per-node: self-loop attr = mean of real-edge attrs + self alpha --------
__global__ void k_loopself(const int* __restrict__ csr, int4* __restrict__ epk,
                           const float* __restrict__ ss1, const float* __restrict__ sd1,
                           const float* __restrict__ C, float4* __restrict__ exf){
  int n = blockIdx.x * 256 + threadIdx.x;
  if (n >= NN) return;
  int a = csr[n], b = csr[n + 1];
  int deg = b - a - 1;
  float s0 = 0.f, s1 = 0.f, s2 = 0.f, s3 = 0.f;
  for (int p = a; p < b - 1; ++p){
    int4 v = epk[p];
    s0 += b2f((unsigned)v.z & 0xffffu); s1 += b2f((unsigned)v.z >> 16);
    s2 += b2f((unsigned)v.w & 0xffffu); s3 += b2f((unsigned)v.w >> 16);
  }
  float inv = 1.f / (float)(deg > 1 ? deg : 1);
  float m0 = s0*inv, m1 = s1*inv, m2 = s2*inv, m3 = s3*inv;
  epk[b - 1] = make_int4(n, n, (int)pk2(m0, m1), (int)pk2(m2, m3));
  float4 ssv = *(const float4*)&ss1[(size_t)n * 4];
  float4 sdv = *(const float4*)&sd1[(size_t)n * 4];
  float e0 = __expf(lrelu(ssv.x + sdv.x + m0*C[VE1+0] + m1*C[VE1+4] + m2*C[VE1+8]  + m3*C[VE1+12]));
  float e1 = __expf(lrelu(ssv.y + sdv.y + m0*C[VE1+1] + m1*C[VE1+5] + m2*C[VE1+9]  + m3*C[VE1+13]));
  float e2 = __expf(lrelu(ssv.z + sdv.z + m0*C[VE1+2] + m1*C[VE1+6] + m2*C[VE1+10] + m3*C[VE1+14]));
  float e3 = __expf(lrelu(ssv.w + sdv.w + m0*C[VE1+3] + m1*C[VE1+7] + m2*C[VE1+11] + m3*C[VE1+15]));
  exf[b - 1] = make_float4(e0, e1, e2, e3);
}

// ---- tiny weight pre-reductions --------------------------------------------
__global__ void k_prep(const float* __restrict__ W1, const float* __restrict__ as1,
                       const float* __restrict__ ad1, const float* __restrict__ We1,
                       const float* __restrict__ ae1, const float* __restrict__ W2,
                       const float* __restrict__ as2, const float* __restrict__ ad2,
                       const float* __restrict__ We2, const float* __restrict__ ae2,
                       float* __restrict__ C){
  int t = threadIdx.x;                       // block of 512
  if (t < 280){
    int k = t >> 2, h = t & 3;
    float s = 0.f, d = 0.f;
    for (int dd = 0; dd < 128; ++dd){
      float w = W1[k*512 + h*128 + dd];
      s += w * as1[h*128 + dd];
      d += w * ad1[h*128 + dd];
    }
    C[VS1 + t] = s; C[VD1 + t] = d;
  }
  if (t < 16){
    int k = t >> 2, h = t & 3;
    float s = 0.f;
    for (int dd = 0; dd < 128; ++dd) s += We1[k*512 + h*128 + dd] * ae1[h*128 + dd];
    C[VE1 + t] = s;
  }
  if (t < 4){
    float s = 0.f;
    for (int dd = 0; dd < 128; ++dd) s += We2[t*128 + dd] * ae2[dd];
    C[VE2 + t] = s;
  }
  {
    float s = 0.f, d = 0.f;
    for (int dd = 0; dd < 128; ++dd){
      float w = W2[t*128 + dd];
      s += w * as2[dd];
      d += w * ad2[dd];
    }
    C[VS2 + t] = s; C[VD2 + t] = d;
  }
}

// ---- transpose + bf16-cast weights -----------------------------------------
__global__ void k_tw(const float* __restrict__ W1, const float* __restrict__ W2,
                     unsigned short* __restrict__ W1t, unsigned short* __restrict__ W2t){
  int i = blockIdx.x * 256 + threadIdx.x;
  if (i < 4*128*KP1){
    int k = i % KP1, n = (i / KP1) & 127, h = i / (KP1*128);
    float v = (k < FIN) ? W1[k*512 + h*128 + n] : 0.f;
    W1t[i] = f2b(v);
  } else {
    int j = i - 4*128*KP1;
    if (j < 128*512){
      int k = j & 511, n = j >> 9;
      W2t[j] = f2b(W2[k*128 + n]);
    }
  }
}

// ---- fused: nf -> bf16 (pitch 72) + layer1 attention scalars ----------------
__global__ __launch_bounds__(256) void k_cnfs1(const float* __restrict__ nf,
    const float* __restrict__ C, unsigned short* __restrict__ nfb,
    float* __restrict__ ss1, float* __restrict__ sd1){
  int lane = threadIdx.x & 63, w = threadIdx.x >> 6;
  int n = blockIdx.x * 4 + w;
  if (n >= NN) return;
  int c0 = lane * 2;
  bool act = lane < 35;                 // cols 0..69
  float v0 = 0.f, v1 = 0.f;
  if (act){
    v0 = nf[(size_t)n * FIN + c0];
    v1 = nf[(size_t)n * FIN + c0 + 1];
  }
  if (lane < 36) *(unsigned*)&nfb[(size_t)n * NFP + c0] = act ? pk2(v0, v1) : 0u;
  float sh[4] = {0,0,0,0}, dh[4] = {0,0,0,0};
  if (act){
    float4 cs0 = *(const float4*)&C[VS1 + c0*4];
    float4 cs1 = *(const float4*)&C[VS1 + (c0+1)*4];
    float4 cd0 = *(const float4*)&C[VD1 + c0*4];
    float4 cd1 = *(const float4*)&C[VD1 + (c0+1)*4];
    sh[0] = v0*cs0.x + v1*cs1.x; sh[1] = v0*cs0.y + v1*cs1.y;
    sh[2] = v0*cs0.z + v1*cs1.z; sh[3] = v0*cs0.w + v1*cs1.w;
    dh[0] = v0*cd0.x + v1*cd1.x; dh[1] = v0*cd0.y + v1*cd1.y;
    dh[2] = v0*cd0.z + v1*cd1.z; dh[3] = v0*cd0.w + v1*cd1.w;
  }
  #pragma unroll
  for (int o = 32; o; o >>= 1){
    #pragma unroll
    for (int h = 0; h < 4; ++h){
      sh[h] += __shfl_xor(sh[h], o);
      dh[h] += __shfl_xor(dh[h], o);
    }
  }
  if (lane == 0){
    *(float4*)&ss1[(size_t)n*4] = make_float4(sh[0], sh[1], sh[2], sh[3]);
    *(float4*)&sd1[(size_t)n*4] = make_float4(dh[0], dh[1], dh[2], dh[3]);
  }
}

// ---- edge-parallel alpha (layer 2) ------------------------------------------
__global__ void k_al2(const int4* __restrict__ epk, const float* __restrict__ ss2,
                      const float* __restrict__ sd2, const float* __restrict__ C,
                      float* __restrict__ ex2){
  int p = blockIdx.x * 256 + threadIdx.x;
  if (p >= ET) return;
  int4 pk = epk[p];
  int s = pk.x, d = pk.y;
  float ax = b2f((unsigned)pk.z & 0xffffu), ay = b2f((unsigned)pk.z >> 16);
  float az = b2f((unsigned)pk.w & 0xffffu), aw = b2f((unsigned)pk.w >> 16);
  ex2[p] = __expf(lrelu(ss2[s] + sd2[d] +
             ax*C[VE2] + ay*C[VE2+1] + az*C[VE2+2] + aw*C[VE2+3]));
}

// ---- MFMA GEMM: C[M,128] = A[M,KP] @ Bt^T, 128x128 tile, 4 waves ------------
// global_load_lds staging w/ XOR swizzle; swapped-operand MFMA -> packed 8B
// stores. MODE 1: gelu(acc+bias) -> x1 (pitch 512, col z*128). MODE 2: bf16
// out pitch 128 + fused ss2/sd2 dot products (x1 passes through LDS anyway).
template<int MODE>
__global__ __launch_bounds__(256) void k_mfma(
    const unsigned short* __restrict__ A, int lda, long aSz,
    const unsigned short* __restrict__ Bt, long bSz,
    unsigned short* __restrict__ Cout, const float* __restrict__ bias,
    const float* __restrict__ Cv, float* __restrict__ ss2, float* __restrict__ sd2,
    int M, int KP){
  int z = blockIdx.y;
  A  += (size_t)z * aSz;
  Bt += (size_t)z * bSz;
  __shared__ unsigned short As[128 * 32];   // pitch 32 shorts, XOR-swizzled chunks
  __shared__ unsigned short Bs[128 * 32];
  int tid = threadIdx.x, lane = tid & 63, w = tid >> 6;
  int wm = w & 1, wn = w >> 1;
  int row0 = blockIdx.x * 128;
  f4v acc[4][4] = {};
  int rl = lane >> 2, cslot = lane & 3;
  int m15 = lane & 15, j = lane >> 4;
  float s2a = 0.f, s2d = 0.f;
  int sr = tid >> 1, shf = tid & 1;
  int ssw = (sr ^ (sr >> 2)) & 3;
  for (int k0 = 0; k0 < KP; k0 += 32){
    #pragma unroll
    for (int half = 0; half < 2; ++half){
      int rb = w * 16 + half * 64;          // uniform chunk base (16 rows)
      int r = rb + rl;
      int cs = cslot ^ ((r ^ (r >> 2)) & 3);
      int gr = row0 + r; if (gr >= M) gr = M - 1;
      gl16(A + (size_t)gr * lda + k0 + cs * 8, &As[rb * 32]);
      gl16(Bt + (size_t)r * lda + k0 + cs * 8, &Bs[rb * 32]);
    }
    __syncthreads();
    s8v af[4], bf[4];
    #pragma unroll
    for (int t = 0; t < 4; ++t){
      int ra = wm*64 + t*16 + m15;
      af[t] = *(const s8v*)&As[ra*32 + ((j ^ ((ra ^ (ra >> 2)) & 3)) * 8)];
      int rb2 = wn*64 + t*16 + m15;
      bf[t] = *(const s8v*)&Bs[rb2*32 + ((j ^ ((rb2 ^ (rb2 >> 2)) & 3)) * 8)];
    }
    if (MODE == 2){                         // fused s2: thread owns row sr, half shf
      #pragma unroll
      for (int cc = 0; cc < 2; ++cc){
        int c = shf * 2 + cc;
        int kb = k0 + ((c ^ ssw) * 8);
        s8v xv = *(const s8v*)&As[sr*32 + c*8];
        #pragma unroll
        for (int t2 = 0; t2 < 8; ++t2){
          float xf = b2f((unsigned short)xv[t2]);
          s2a += xf * Cv[VS2 + kb + t2];
          s2d += xf * Cv[VD2 + kb + t2];
        }
      }
    }
    #pragma unroll
    for (int mi = 0; mi < 4; ++mi)
      #pragma unroll
      for (int ni = 0; ni < 4; ++ni)
        acc[mi][ni] = __builtin_amdgcn_mfma_f32_16x16x32_bf16(bf[ni], af[mi], acc[mi][ni], 0, 0, 0);
    __syncthreads();
  }
  // epilogue: swapped D layout -> lane holds row (lane&15), 4 consecutive cols
  int cq = lane & 15, rq = lane >> 4;
  #pragma unroll
  for (int mi = 0; mi < 4; ++mi){
    int grow = row0 + wm*64 + mi*16 + cq;
    if (grow < M){
      #pragma unroll
      for (int ni = 0; ni < 4; ++ni){
        int gc = wn*64 + ni*16 + rq*4;
        float v0 = acc[mi][ni][0], v1 = acc[mi][ni][1];
        float v2 = acc[mi][ni][2], v3 = acc[mi][ni][3];
        if (MODE == 1){
          float4 bv = *(const float4*)&bias[z*128 + gc];
          v0 = gelu_fast(v0 + bv.x); v1 = gelu_fast(v1 + bv.y);
          v2 = gelu_fast(v2 + bv.z); v3 = gelu_fast(v3 + bv.w);
          *(uint2*)&Cout[(size_t)grow*512 + z*128 + gc] = make_uint2(pk2(v0,v1), pk2(v2,v3));
        } else {
          *(uint2*)&Cout[(size_t)grow*128 + gc] = make_uint2(pk2(v0,v1), pk2(v2,v3));
        }
      }
    }
  }
  if (MODE == 2){
    float oa = s2a + __shfl_xor(s2a, 1);
    float od = s2d + __shfl_xor(s2d, 1);
    if (shf == 0){
      int grow = row0 + sr;
      if (grow < M){ ss2[grow] = oa; sd2[grow] = od; }
    }
  }
}

// ---- layer1 aggregation: wave/node, 2-edge pipelined gather -----------------
__global__ __launch_bounds__(256) void k_aggnf(const int* __restrict__ csr,
    const int4* __restrict__ epk, const float4* __restrict__ exf,
    const unsigned short* __restrict__ nfb, unsigned short* __restrict__ agg){
  int lane = threadIdx.x & 63, w = threadIdx.x >> 6;
  int n = blockIdx.x * 4 + w;
  if (n >= NN) return;
  int off = __builtin_amdgcn_readfirstlane(csr[n]);
  int end = __builtin_amdgcn_readfirstlane(csr[n + 1]);
  int col = lane * 2;
  bool act = lane < 36;
  float d0=0,d1=0,d2=0,d3=0;
  float a00=0,a01=0,a10=0,a11=0,a20=0,a21=0,a30=0,a31=0;
  int p = off;
  for (; p + 2 <= end; p += 2){
    int s0 = epk[p].x, s1 = epk[p+1].x;
    float4 e0 = exf[p], e1 = exf[p+1];
    unsigned u0 = 0, u1 = 0;
    if (act){
      u0 = *(const unsigned*)&nfb[(size_t)s0 * NFP + col];
      u1 = *(const unsigned*)&nfb[(size_t)s1 * NFP + col];
    }
    d0 += e0.x + e1.x; d1 += e0.y + e1.y; d2 += e0.z + e1.z; d3 += e0.w + e1.w;
    float v00 = b2f(u0 & 0xffffu), v01 = b2f(u0 >> 16);
    float v10 = b2f(u1 & 0xffffu), v11 = b2f(u1 >> 16);
    a00 += e0.x*v00 + e1.x*v10; a01 += e0.x*v01 + e1.x*v11;
    a10 += e0.y*v00 + e1.y*v10; a11 += e0.y*v01 + e1.y*v11;
    a20 += e0.z*v00 + e1.z*v10; a21 += e0.z*v01 + e1.z*v11;
    a30 += e0.w*v00 + e1.w*v10; a31 += e0.w*v01 + e1.w*v11;
  }
  if (p < end){
    int s0 = epk[p].x;
    float4 e0 = exf[p];
    unsigned u0 = 0;
    if (act) u0 = *(const unsigned*)&nfb[(size_t)s0 * NFP + col];
    d0 += e0.x; d1 += e0.y; d2 += e0.z; d3 += e0.w;
    float v00 = b2f(u0 & 0xffffu), v01 = b2f(u0 >> 16);
    a00 += e0.x*v00; a01 += e0.x*v01;
    a10 += e0.y*v00; a11 += e0.y*v01;
    a20 += e0.z*v00; a21 += e0.z*v01;
    a30 += e0.w*v00; a31 += e0.w*v01;
  }
  float i0 = 1.f/(d0+1e-16f), i1 = 1.f/(d1+1e-16f);
  float i2 = 1.f/(d2+1e-16f), i3 = 1.f/(d3+1e-16f);
  constexpr size_t HS = (size_t)NN * KP1;
  size_t base = (size_t)n * KP1 + col;
  if (act){
    *(unsigned*)&agg[base]        = pk2(a00*i0, a01*i0);
    *(unsigned*)&agg[base +   HS] = pk2(a10*i1, a11*i1);
    *(unsigned*)&agg[base + 2*HS] = pk2(a20*i2, a21*i2);
    *(unsigned*)&agg[base + 3*HS] = pk2(a30*i3, a31*i3);
  } else if (lane < 48){                // zero cols 72..95
    *(unsigned*)&agg[base]        = 0u;
    *(unsigned*)&agg[base +   HS] = 0u;
    *(unsigned*)&agg[base + 2*HS] = 0u;
    *(unsigned*)&agg[base + 3*HS] = 0u;
  }
}

// ---- layer2 aggregation: 4-edge pipelined gather + GELU + LN + projections --
__global__ __launch_bounds__(256) void k_agg2(
    const int* __restrict__ csr, const int4* __restrict__ epk,
    const float* __restrict__ ex2, const unsigned short* __restrict__ xs2b,
    const float* __restrict__ b2, const float* __restrict__ lng,
    const float* __restrict__ lnb, const float* __restrict__ pw,
    const float* __restrict__ pb, const float* __restrict__ dwm,
    const float* __restrict__ dbv, float* __restrict__ out){
  int lane = threadIdx.x & 63, w = threadIdx.x >> 6;
  int n = blockIdx.x * 4 + w;
  if (n >= NN) return;
  int off = __builtin_amdgcn_readfirstlane(csr[n]);
  int end = __builtin_amdgcn_readfirstlane(csr[n + 1]);
  int c0 = lane * 2;
  float acc0 = 0.f, acc1 = 0.f, den = 0.f;
  int p = off;
  for (; p + 4 <= end; p += 4){
    int s0 = epk[p].x, s1 = epk[p+1].x, s2 = epk[p+2].x, s3 = epk[p+3].x;
    float e0 = ex2[p], e1 = ex2[p+1], e2 = ex2[p+2], e3 = ex2[p+3];
    unsigned u0 = *(const unsigned*)&xs2b[(size_t)s0 * 128 + c0];
    unsigned u1 = *(const unsigned*)&xs2b[(size_t)s1 * 128 + c0];
    unsigned u2 = *(const unsigned*)&xs2b[(size_t)s2 * 128 + c0];
    unsigned u3 = *(const unsigned*)&xs2b[(size_t)s3 * 128 + c0];
    den += (e0 + e1) + (e2 + e3);
    acc0 += e0*b2f(u0 & 0xffffu) + e1*b2f(u1 & 0xffffu)
          + e2*b2f(u2 & 0xffffu) + e3*b2f(u3 & 0xffffu);
    acc1 += e0*b2f(u0 >> 16) + e1*b2f(u1 >> 16)
          + e2*b2f(u2 >> 16) + e3*b2f(u3 >> 16);
  }
  for (; p + 2 <= end; p += 2){
    int s0 = epk[p].x, s1 = epk[p+1].x;
    float e0 = ex2[p], e1 = ex2[p+1];
    unsigned u0 = *(const unsigned*)&xs2b[(size_t)s0 * 128 + c0];
    unsigned u1 = *(const unsigned*)&xs2b[(size_t)s1 * 128 + c0];
    den += e0 + e1;
    acc0 += e0*b2f(u0 & 0xffffu) + e1*b2f(u1 & 0xffffu);
    acc1 += e0*b2f(u0 >> 16) + e1*b2f(u1 >> 16);
  }
  if (p < end){
    int s0 = epk[p].x;
    float e0 = ex2[p];
    unsigned u0 = *(const unsigned*)&xs2b[(size_t)s0 * 128 + c0];
    den += e0;
    acc0 += e0*b2f(u0 & 0xffffu);
    acc1 += e0*b2f(u0 >> 16);
  }
  float invd = 1.f / (den + 1e-16f);
  float g0 = gelu_fast(acc0 * invd + b2[c0]);
  float g1 = gelu_fast(acc1 * invd + b2[c0 + 1]);
  float s = g0 + g1;
  #pragma unroll
  for (int o = 32; o; o >>= 1) s += __shfl_xor(s, o);
  float mu = s * (1.f / 128.f);
  float e0 = g0 - mu, e1 = g1 - mu;
  float q = e0*e0 + e1*e1;
  #pragma unroll
  for (int o = 32; o; o >>= 1) q += __shfl_xor(q, o);
  float rstd = rsqrtf(q * (1.f / 128.f) + 1e-5f);
  float y0 = e0 * rstd * lng[c0] + lnb[c0];
  float y1 = e1 * rstd * lng[c0 + 1] + lnb[c0 + 1];
  float pr[12];
  #pragma unroll
  for (int jj = 0; jj < 8; ++jj) pr[jj] = y0 * pw[c0*8 + jj] + y1 * pw[(c0+1)*8 + jj];
  #pragma unroll
  for (int jj = 0; jj < 4; ++jj) pr[8+jj] = y0 * dwm[c0*4 + jj] + y1 * dwm[(c0+1)*4 + jj];
  #pragma unroll
  for (int o = 32; o; o >>= 1)
    #pragma unroll
    for (int jj = 0; jj < 12; ++jj) pr[jj] += __shfl_xor(pr[jj], o);
  if (lane == 0){
    #pragma unroll
    for (int jj = 0; jj < 8; ++jj) out[(size_t)n*8 + jj] = pr[jj] + pb[jj];
    #pragma unroll
    for (int jj = 0; jj < 4; ++jj) out[(size_t)NN*8 + (size_t)n*4 + jj] = pr[8+jj] + dbv[jj];
  }
}

extern "C" void kernel_launch(void* const* d_in, const int* in_sizes, int n_in,
                              void* d_out, int out_size, void* d_ws, size_t ws_size,
                              hipStream_t stream){
  const float* nf  = (const float*)d_in[0];
  const int*   ei  = (const int*)  d_in[1];
  const float* ea  = (const float*)d_in[2];
  const float* W1  = (const float*)d_in[3];
  const float* as1 = (const float*)d_in[4];
  const float* ad1 = (const float*)d_in[5];
  const float* We1 = (const float*)d_in[6];
  const float* ae1 = (const float*)d_in[7];
  const float* b1  = (const float*)d_in[8];
  const float* W2  = (const float*)d_in[9];
  const float* as2 = (const float*)d_in[10];
  const float* ad2 = (const float*)d_in[11];
  const float* We2 = (const float*)d_in[12];
  const float* ae2 = (const float*)d_in[13];
  const float* b2  = (const float*)d_in[14];
  const float* lng = (const float*)d_in[15];
  const float* lnb = (const float*)d_in[16];
  const float* pw  = (const float*)d_in[17];
  const float* pb  = (const float*)d_in[18];
  const float* dw  = (const float*)d_in[19];
  const float* db  = (const float*)d_in[20];
  float* out = (float*)d_out;

  float* wf = (float*)d_ws;
  int*      cnt  = (int*)     (wf + CNT_O);
  int*      csr  = (int*)     (wf + CSR_O);
  int*      bsum = (int*)     (wf + BSUM_O);
  int*      boff = (int*)     (wf + BOFF_O);
  int4*     epk  = (int4*)    (wf + EPK_O);
  float4*   exf1 = (float4*)  (wf + EXF1_O);
  float*    ex2  =            (wf + EXF2_O);
  float*    ss1  =            (wf + SS1_O);
  float*    sd1  =            (wf + SD1_O);
  float*    ss2  =            (wf + SS2_O);
  float*    sd2  =            (wf + SD2_O);
  float*    Cc   =            (wf + CST_O);
  unsigned short* W1t = (unsigned short*)(wf + W1T_O);
  unsigned short* W2t = (unsigned short*)(wf + W2T_O);
  unsigned short* nfb = (unsigned short*)(wf + NFB_O);
  unsigned short* agg = (unsigned short*)(wf + AGG_O);
  unsigned short* x1  = (unsigned short*)(wf + X1_O);
  unsigned short* xs2b= (unsigned short*)(wf + XS2_O);

  hipMemsetAsync(cnt, 0, NN * sizeof(int), stream);
  k_prep<<<1, 512, 0, stream>>>(W1, as1, ad1, We1, ae1, W2, as2, ad2, We2, ae2, Cc);
  k_tw<<<(4*128*KP1 + 128*512 + 255) / 256, 256, 0, stream>>>(W1, W2, W1t, W2t);
  k_cnfs1<<<(NN + 3) / 4, 256, 0, stream>>>(nf, Cc, nfb, ss1, sd1);
  k_deg<<<(NE + 255) / 256, 256, 0, stream>>>(ei, cnt);
  k_scan1<<<SCB, 256, 0, stream>>>(cnt, bsum);
  k_scan2<<<1, 256, 0, stream>>>(bsum, boff);
  k_scan3<<<SCB, 256, 0, stream>>>(cnt, boff, csr);
  k_fill<<<(NE + 255) / 256, 256, 0, stream>>>(ei, ea, csr, cnt, epk, ss1, sd1, Cc, exf1);
  k_loopself<<<(NN + 255) / 256, 256, 0, stream>>>(csr, epk, ss1, sd1, Cc, exf1);
  k_aggnf<<<(NN + 3) / 4, 256, 0, stream>>>(csr, epk, exf1, nfb, agg);
  k_mfma<1><<<dim3((NN + 127) / 128, 4), 256, 0, stream>>>(
      agg, KP1, (long)NN * KP1, W1t, (long)128 * KP1, x1, b1,
      nullptr, nullptr, nullptr, NN, KP1);
  k_mfma<2><<<dim3((NN + 127) / 128, 1), 256, 0, stream>>>(
      x1, 512, 0, W2t, 0, xs2b, nullptr, Cc, ss2, sd2, NN, 512);
  k_al2<<<(ET + 255) / 256, 256, 0, stream>>>(epk, ss2, sd2, Cc, ex2);
  k_agg2<<<(NN + 3) / 4, 256, 0, stream>>>(csr, epk, ex2, xs2b,
                                           b2, lng, lnb, pw, pb, dw, db, out);
}

// Round 10
// 372.420 us; speedup vs baseline: 3.2298x; 1.0013x over previous
//
#include <hip/hip_runtime.h>
#include <hip/hip_bf16.h>
#include <math.h>

#define NN 50000
#define NE 400000
#define FIN 70
#define EDIM 4
#define HIDD 128
#define NHEAD 4
constexpr int ET = NE + NN;
constexpr int KP1 = 96;           // layer-1 K padded (70 -> 96)
constexpr int NFP = 72;           // nf bf16 row pitch
constexpr int SCB = (NN + 255) / 256;   // scan blocks = 196

constexpr size_t al4(size_t x){ return (x + 3) & ~size_t(3); }
// ws offsets in 4-byte words
constexpr size_t CNT_O   = 0;                          // int[NN] (zeroed each call)
constexpr size_t ZEND    = al4(CNT_O + NN);
constexpr size_t CSR_O   = ZEND;                       // int[NN+1]
constexpr size_t BSUM_O  = al4(CSR_O + NN + 1);        // int[256]
constexpr size_t BOFF_O  = al4(BSUM_O + 256);          // int[256]
constexpr size_t EPK_O   = al4(BOFF_O + 256);          // int4[ET] {s,d,ea01,ea23}
constexpr size_t EXF1_O  = al4(EPK_O + (size_t)ET*4);  // float4[ET] exp scores L1
constexpr size_t EXF2_O  = al4(EXF1_O + (size_t)ET*4); // f32[ET]    exp scores L2
constexpr size_t SS1_O   = al4(EXF2_O + ET);           // f32[NN*4]
constexpr size_t SD1_O   = al4(SS1_O + (size_t)NN*4);
constexpr size_t SS2_O   = al4(SD1_O + (size_t)NN*4);  // f32[NN]
constexpr size_t SD2_O   = al4(SS2_O + NN);
constexpr size_t CST_O   = al4(SD2_O + NN);            // f32[2048]
constexpr size_t W1T_O   = al4(CST_O + 2048);          // bf16[4][128][96]
constexpr size_t W2T_O   = al4(W1T_O + 4*128*KP1/2);   // bf16[128][512]
constexpr size_t NFB_O   = al4(W2T_O + 128*512/2);     // bf16[NN][72]
constexpr size_t AGG_O   = al4(NFB_O + (size_t)NN*NFP/2);   // bf16[4][NN][96]
constexpr size_t XS2_O   = al4(AGG_O + (size_t)4*NN*KP1/2); // bf16[NN][128]

// const-block sub-offsets (words, within CST)
constexpr int VS1 = 0;    // [70][4]
constexpr int VD1 = 320;  // [70][4]
constexpr int VE1 = 640;  // [4][4]
constexpr int VE2 = 656;  // [4]
constexpr int VS2 = 704;  // [512]
constexpr int VD2 = 1216; // [512]

typedef short s8v __attribute__((ext_vector_type(8)));
typedef float f4v __attribute__((ext_vector_type(4)));

__device__ __forceinline__ unsigned short f2b(float v){
  __hip_bfloat16 b = __float2bfloat16(v);
  return *(unsigned short*)&b;
}
__device__ __forceinline__ float b2f(unsigned u_lo16){
  return __uint_as_float(u_lo16 << 16);
}
__device__ __forceinline__ unsigned pk2(float lo, float hi){
  return (unsigned)f2b(lo) | ((unsigned)f2b(hi) << 16);
}
__device__ __forceinline__ float lrelu(float x){ return x > 0.f ? x : 0.2f * x; }

// erf via A&S 7.1.26 (|err|<1.5e-7), one fast v_exp — avoids libm erff
__device__ __forceinline__ float gelu_fast(float x){
  float z = x * 0.70710678118654752440f;
  float a = fabsf(z);
  float t = 1.f / (1.f + 0.3275911f * a);
  float p = ((((1.061405429f*t - 1.453152027f)*t + 1.421413741f)*t
              - 0.284496736f)*t + 0.254829592f)*t;
  float erfv = 1.f - p * __expf(-a * a);
  erfv = copysignf(erfv, z);
  return 0.5f * x * (1.f + erfv);
}

// ---- degree histogram: ONE atomic per edge ----------------------------------
__global__ void k_deg(const int* __restrict__ ei, int* __restrict__ cnt){
  int e = blockIdx.x * 256 + threadIdx.x;
  if (e >= NE) return;
  atomicAdd(&cnt[ei[NE + e]], 1);
}

// ---- CSR build: 3-phase scan of (cnt+1) -------------------------------------
__global__ void k_scan1(const int* __restrict__ cnt, int* __restrict__ bsum){
  __shared__ int ws[4];
  int t = threadIdx.x, lane = t & 63, w = t >> 6;
  int i = blockIdx.x * 256 + t;
  int v = (i < NN) ? cnt[i] + 1 : 0;
  for (int o = 32; o; o >>= 1) v += __shfl_down(v, o);
  if (lane == 0) ws[w] = v;
  __syncthreads();
  if (t == 0) bsum[blockIdx.x] = ws[0] + ws[1] + ws[2] + ws[3];
}

__global__ void k_scan2(const int* __restrict__ bsum, int* __restrict__ boff){
  __shared__ int ws[4];
  int t = threadIdx.x, lane = t & 63, w = t >> 6;
  int v = (t < SCB) ? bsum[t] : 0;
  int x = v;
  #pragma unroll
  for (int o = 1; o < 64; o <<= 1){ int u = __shfl_up(x, o); if (lane >= o) x += u; }
  if (lane == 63) ws[w] = x;
  __syncthreads();
  if (w == 0 && lane < 4){
    int y = ws[lane];
    #pragma unroll
    for (int o = 1; o < 4; o <<= 1){ int u = __shfl_up(y, o); if (lane >= o) y += u; }
    ws[lane] = y;
  }
  __syncthreads();
  int incl = x + (w > 0 ? ws[w - 1] : 0);
  if (t < SCB) boff[t] = incl - v;
}

__global__ void k_scan3(const int* __restrict__ cnt, const int* __restrict__ boff,
                        int* __restrict__ csr){
  __shared__ int ws[4];
  int t = threadIdx.x, lane = t & 63, w = t >> 6;
  int i = blockIdx.x * 256 + t;
  int v = (i < NN) ? cnt[i] + 1 : 0;
  int x = v;
  #pragma unroll
  for (int o = 1; o < 64; o <<= 1){ int u = __shfl_up(x, o); if (lane >= o) x += u; }
  if (lane == 63) ws[w] = x;
  __syncthreads();
  if (w == 0 && lane < 4){
    int y = ws[lane];
    #pragma unroll
    for (int o = 1; o < 4; o <<= 1){ int u = __shfl_up(y, o); if (lane >= o) y += u; }
    ws[lane] = y;
  }
  __syncthreads();
  if (i < NN) csr[i + 1] = boff[blockIdx.x] + (w > 0 ? ws[w - 1] : 0) + x;
  if (i == 0) csr[0] = 0;
}

// ---- fill CSR slots + FUSED layer-1 alpha; consumes cnt -> 0 ----------------
__global__ void k_fill(const int* __restrict__ ei, const float* __restrict__ ea,
                       const int* __restrict__ csr, int* __restrict__ cnt,
                       int4* __restrict__ epk, const float* __restrict__ ss1,
                       const float* __restrict__ sd1, const float* __restrict__ C,
                       float4* __restrict__ exf){
  int e = blockIdx.x * 256 + threadIdx.x;
  if (e >= NE) return;
  int s = ei[e], d = ei[NE + e];
  int r = atomicSub(&cnt[d], 1);        // r in [deg..1]
  int p = csr[d] + r - 1;
  float4 a = *(const float4*)&ea[(size_t)e * 4];
  epk[p] = make_int4(s, d, (int)pk2(a.x, a.y), (int)pk2(a.z, a.w));
  float4 ssv = *(const float4*)&ss1[(size_t)s * 4];
  float4 sdv = *(const float4*)&sd1[(size_t)d * 4];
  float e0 = __expf(lrelu(ssv.x + sdv.x + a.x*C[VE1+0] + a.y*C[VE1+4] + a.z*C[VE1+8]  + a.w*C[VE1+12]));
  float e1 = __expf(lrelu(ssv.y + sdv.y + a.x*C[VE1+1] + a.y*C[VE1+5] + a.z*C[VE1+9]  + a.w*C[VE1+13]));
  float e2 = __expf(lrelu(ssv.z + sdv.z + a.x*C[VE1+2] + a.y*C[VE1+6] + a.z*C[VE1+10] + a.w*C[VE1+14]));
  float e3 = __expf(lrelu(ssv.w + sdv.w + a.x*C[VE1+3] + a.y*C[VE1+7] + a.z*C[VE1+11] + a.w*C[VE1+15]));
  exf[p] = make_float4(e0, e1, e2, e3);
}

// ---- per-node: self-loop attr = mean of real-edge attrs + self alpha --------
__global__ void k_loopself(const int* __restrict__ csr, int4* __restrict__ epk,
                           const float* __restrict__ ss1, const float* __restrict__ sd1,
                           const float* __restrict__ C, float4* __restrict__ exf){
  int n = blockIdx.x * 256 + threadIdx.x;
  if (n >= NN) return;
  int a = csr[n], b = csr[n + 1];
  int deg = b - a - 1;
  float s0 = 0.f, s1 = 0.f, s2 = 0.f, s3 = 0.f;
  for (int p = a; p < b - 1; ++p){
    int4 v = epk[p];
    s0 += b2f((unsigned)v.z & 0xffffu); s1 += b2f((unsigned)v.z >> 16);
    s2 += b2f((unsigned)v.w & 0xffffu); s3 += b2f((unsigned)v.w >> 16);
  }
  float inv = 1.f / (float)(deg > 1 ? deg : 1);
  float m0 = s0*inv, m1 = s1*inv, m2 = s2*inv, m3 = s3*inv;
  epk[b - 1] = make_int4(n, n, (int)pk2(m0, m1), (int)pk2(m2, m3));
  float4 ssv = *(const float4*)&ss1[(size_t)n * 4];
  float4 sdv = *(const float4*)&sd1[(size_t)n * 4];
  float e0 = __expf(lrelu(ssv.x + sdv.x + m0*C[VE1+0] + m1*C[VE1+4] + m2*C[VE1+8]  + m3*C[VE1+12]));
  float e1 = __expf(lrelu(ssv.y + sdv.y + m0*C[VE1+1] + m1*C[VE1+5] + m2*C[VE1+9]  + m3*C[VE1+13]));
  float e2 = __expf(lrelu(ssv.z + sdv.z + m0*C[VE1+2] + m1*C[VE1+6] + m2*C[VE1+10] + m3*C[VE1+14]));
  float e3 = __expf(lrelu(ssv.w + sdv.w + m0*C[VE1+3] + m1*C[VE1+7] + m2*C[VE1+11] + m3*C[VE1+15]));
  exf[b - 1] = make_float4(e0, e1, e2, e3);
}

// ---- tiny weight pre-reductions --------------------------------------------
__global__ void k_prep(const float* __restrict__ W1, const float* __restrict__ as1,
                       const float* __restrict__ ad1, const float* __restrict__ We1,
                       const float* __restrict__ ae1, const float* __restrict__ W2,
                       const float* __restrict__ as2, const float* __restrict__ ad2,
                       const float* __restrict__ We2, const float* __restrict__ ae2,
                       float* __restrict__ C){
  int t = threadIdx.x;                       // block of 512
  if (t < 280){
    int k = t >> 2, h = t & 3;
    float s = 0.f, d = 0.f;
    for (int dd = 0; dd < 128; ++dd){
      float w = W1[k*512 + h*128 + dd];
      s += w * as1[h*128 + dd];
      d += w * ad1[h*128 + dd];
    }
    C[VS1 + t] = s; C[VD1 + t] = d;
  }
  if (t < 16){
    int k = t >> 2, h = t & 3;
    float s = 0.f;
    for (int dd = 0; dd < 128; ++dd) s += We1[k*512 + h*128 + dd] * ae1[h*128 + dd];
    C[VE1 + t] = s;
  }
  if (t < 4){
    float s = 0.f;
    for (int dd = 0; dd < 128; ++dd) s += We2[t*128 + dd] * ae2[dd];
    C[VE2 + t] = s;
  }
  {
    float s = 0.f, d = 0.f;
    for (int dd = 0; dd < 128; ++dd){
      float w = W2[t*128 + dd];
      s += w * as2[dd];
      d += w * ad2[dd];
    }
    C[VS2 + t] = s; C[VD2 + t] = d;
  }
}

// ---- transpose + bf16-cast weights -----------------------------------------
__global__ void k_tw(const float* __restrict__ W1, const float* __restrict__ W2,
                     unsigned short* __restrict__ W1t, unsigned short* __restrict__ W2t){
  int i = blockIdx.x * 256 + threadIdx.x;
  if (i < 4*128*KP1){
    int k = i % KP1, n = (i / KP1) & 127, h = i / (KP1*128);
    float v = (k < FIN) ? W1[k*512 + h*128 + n] : 0.f;
    W1t[i] = f2b(v);
  } else {
    int j = i - 4*128*KP1;
    if (j < 128*512){
      int k = j & 511, n = j >> 9;
      W2t[j] = f2b(W2[k*128 + n]);
    }
  }
}

// ---- fused: nf -> bf16 (pitch 72) + layer1 attention scalars ----------------
__global__ __launch_bounds__(256) void k_cnfs1(const float* __restrict__ nf,
    const float* __restrict__ C, unsigned short* __restrict__ nfb,
    float* __restrict__ ss1, float* __restrict__ sd1){
  int lane = threadIdx.x & 63, w = threadIdx.x >> 6;
  int n = blockIdx.x * 4 + w;
  if (n >= NN) return;
  int c0 = lane * 2;
  bool act = lane < 35;                 // cols 0..69
  float v0 = 0.f, v1 = 0.f;
  if (act){
    v0 = nf[(size_t)n * FIN + c0];
    v1 = nf[(size_t)n * FIN + c0 + 1];
  }
  if (lane < 36) *(unsigned*)&nfb[(size_t)n * NFP + c0] = act ? pk2(v0, v1) : 0u;
  float sh[4] = {0,0,0,0}, dh[4] = {0,0,0,0};
  if (act){
    float4 cs0 = *(const float4*)&C[VS1 + c0*4];
    float4 cs1 = *(const float4*)&C[VS1 + (c0+1)*4];
    float4 cd0 = *(const float4*)&C[VD1 + c0*4];
    float4 cd1 = *(const float4*)&C[VD1 + (c0+1)*4];
    sh[0] = v0*cs0.x + v1*cs1.x; sh[1] = v0*cs0.y + v1*cs1.y;
    sh[2] = v0*cs0.z + v1*cs1.z; sh[3] = v0*cs0.w + v1*cs1.w;
    dh[0] = v0*cd0.x + v1*cd1.x; dh[1] = v0*cd0.y + v1*cd1.y;
    dh[2] = v0*cd0.z + v1*cd1.z; dh[3] = v0*cd0.w + v1*cd1.w;
  }
  #pragma unroll
  for (int o = 32; o; o >>= 1){
    #pragma unroll
    for (int h = 0; h < 4; ++h){
      sh[h] += __shfl_xor(sh[h], o);
      dh[h] += __shfl_xor(dh[h], o);
    }
  }
  if (lane == 0){
    *(float4*)&ss1[(size_t)n*4] = make_float4(sh[0], sh[1], sh[2], sh[3]);
    *(float4*)&sd1[(size_t)n*4] = make_float4(dh[0], dh[1], dh[2], dh[3]);
  }
}

// ---- edge-parallel alpha (layer 2) ------------------------------------------
__global__ void k_al2(const int4* __restrict__ epk, const float* __restrict__ ss2,
                      const float* __restrict__ sd2, const float* __restrict__ C,
                      float* __restrict__ ex2){
  int p = blockIdx.x * 256 + threadIdx.x;
  if (p >= ET) return;
  int4 pk = epk[p];
  int s = pk.x, d = pk.y;
  float ax = b2f((unsigned)pk.z & 0xffffu), ay = b2f((unsigned)pk.z >> 16);
  float az = b2f((unsigned)pk.w & 0xffffu), aw = b2f((unsigned)pk.w >> 16);
  ex2[p] = __expf(lrelu(ss2[s] + sd2[d] +
             ax*C[VE2] + ay*C[VE2+1] + az*C[VE2+2] + aw*C[VE2+3]));
}

// ---- FUSED two-stage GEMM: 32 rows/block, x1 tile lives in LDS --------------
// stage1: xt[32][512] = gelu(agg @ W1 + b1)   (per head, K=96)
// stage2: xs2[32][128] = xt @ W2t^T (K=512) + fused ss2/sd2 dots
__global__ __launch_bounds__(256) void k_gemm12(
    const unsigned short* __restrict__ agg, const unsigned short* __restrict__ W1t,
    const unsigned short* __restrict__ W2t, const float* __restrict__ b1,
    const float* __restrict__ Cv, unsigned short* __restrict__ xs2b,
    float* __restrict__ ss2, float* __restrict__ sd2){
  __shared__ unsigned short xt[32 * 520];   // 33.3 KB
  __shared__ unsigned short Bs[128 * 40];   // 10.2 KB
  __shared__ unsigned short As[32 * 40];    //  2.6 KB
  int tid = threadIdx.x, lane = tid & 63, w = tid >> 6;
  int wm = w & 1, wn = w >> 1;
  int m15 = lane & 15, rq = lane >> 4;
  int r0 = blockIdx.x * 32;
  constexpr size_t HS = (size_t)NN * KP1;
  // ---------------- stage 1 ----------------
  for (int h = 0; h < 4; ++h){
    f4v acc[4] = {};
    const unsigned short* Ah = agg + (size_t)h * HS;
    const unsigned short* Wh = W1t + h * 128 * KP1;
    for (int k0 = 0; k0 < KP1; k0 += 32){
      if (tid < 128){
        int r = tid >> 2, c = tid & 3;
        int gr = r0 + r; if (gr >= NN) gr = NN - 1;
        *(uint4*)&As[r*40 + c*8] = *(const uint4*)&Ah[(size_t)gr*KP1 + k0 + c*8];
      }
      #pragma unroll
      for (int i = 0; i < 2; ++i){
        int idx = tid + i*256;
        int r = idx >> 2, c = idx & 3;
        *(uint4*)&Bs[r*40 + c*8] = *(const uint4*)&Wh[r*KP1 + k0 + c*8];
      }
      __syncthreads();
      s8v af = *(const s8v*)&As[(wm*16 + m15)*40 + rq*8];
      #pragma unroll
      for (int ni = 0; ni < 4; ++ni){
        s8v bf = *(const s8v*)&Bs[(wn*64 + ni*16 + m15)*40 + rq*8];
        acc[ni] = __builtin_amdgcn_mfma_f32_16x16x32_bf16(bf, af, acc[ni], 0, 0, 0);
      }
      __syncthreads();
    }
    int lr = wm*16 + m15;
    #pragma unroll
    for (int ni = 0; ni < 4; ++ni){
      int cb = h*128 + wn*64 + ni*16 + rq*4;
      float4 bv = *(const float4*)&b1[cb];
      float v0 = gelu_fast(acc[ni][0] + bv.x);
      float v1 = gelu_fast(acc[ni][1] + bv.y);
      float v2 = gelu_fast(acc[ni][2] + bv.z);
      float v3 = gelu_fast(acc[ni][3] + bv.w);
      *(uint2*)&xt[lr*520 + cb] = make_uint2(pk2(v0,v1), pk2(v2,v3));
    }
  }
  // ---------------- stage 2 ----------------
  f4v acc2[4] = {};
  for (int k0 = 0; k0 < 512; k0 += 32){
    #pragma unroll
    for (int i = 0; i < 2; ++i){
      int idx = tid + i*256;
      int r = idx >> 2, c = idx & 3;
      *(uint4*)&Bs[r*40 + c*8] = *(const uint4*)&W2t[r*512 + k0 + c*8];
    }
    __syncthreads();
    s8v af = *(const s8v*)&xt[(wm*16 + m15)*520 + k0 + rq*8];
    #pragma unroll
    for (int ni = 0; ni < 4; ++ni){
      s8v bf = *(const s8v*)&Bs[(wn*64 + ni*16 + m15)*40 + rq*8];
      acc2[ni] = __builtin_amdgcn_mfma_f32_16x16x32_bf16(bf, af, acc2[ni], 0, 0, 0);
    }
    __syncthreads();
  }
  int grow = r0 + wm*16 + m15;
  if (grow < NN){
    #pragma unroll
    for (int ni = 0; ni < 4; ++ni){
      int gc = wn*64 + ni*16 + rq*4;
      *(uint2*)&xs2b[(size_t)grow*128 + gc] =
          make_uint2(pk2(acc2[ni][0], acc2[ni][1]), pk2(acc2[ni][2], acc2[ni][3]));
    }
  }
  // ---------------- fused ss2/sd2 ----------------
  int row = tid >> 3, ch = tid & 7;
  float sa = 0.f, sdv = 0.f;
  #pragma unroll
  for (int jj = 0; jj < 8; ++jj){
    int j2 = (jj + ch) & 7;                 // rotate to spread LDS banks
    int cb = ch*64 + j2*8;
    s8v xv = *(const s8v*)&xt[row*520 + cb];
    #pragma unroll
    for (int t2 = 0; t2 < 8; ++t2){
      float xf = b2f((unsigned short)xv[t2]);
      sa  += xf * Cv[VS2 + cb + t2];
      sdv += xf * Cv[VD2 + cb + t2];
    }
  }
  #pragma unroll
  for (int o = 1; o < 8; o <<= 1){ sa += __shfl_xor(sa, o); sdv += __shfl_xor(sdv, o); }
  if (ch == 0 && r0 + row < NN){ ss2[r0 + row] = sa; sd2[r0 + row] = sdv; }
}

// ---- layer1 aggregation: wave/node, 2-edge pipelined gather -----------------
__global__ __launch_bounds__(256) void k_aggnf(const int* __restrict__ csr,
    const int4* __restrict__ epk, const float4* __restrict__ exf,
    const unsigned short* __restrict__ nfb, unsigned short* __restrict__ agg){
  int lane = threadIdx.x & 63, w = threadIdx.x >> 6;
  int n = blockIdx.x * 4 + w;
  if (n >= NN) return;
  int off = __builtin_amdgcn_readfirstlane(csr[n]);
  int end = __builtin_amdgcn_readfirstlane(csr[n + 1]);
  int col = lane * 2;
  bool act = lane < 36;
  float d0=0,d1=0,d2=0,d3=0;
  float a00=0,a01=0,a10=0,a11=0,a20=0,a21=0,a30=0,a31=0;
  int p = off;
  for (; p + 2 <= end; p += 2){
    int s0 = epk[p].x, s1 = epk[p+1].x;
    float4 e0 = exf[p], e1 = exf[p+1];
    unsigned u0 = 0, u1 = 0;
    if (act){
      u0 = *(const unsigned*)&nfb[(size_t)s0 * NFP + col];
      u1 = *(const unsigned*)&nfb[(size_t)s1 * NFP + col];
    }
    d0 += e0.x + e1.x; d1 += e0.y + e1.y; d2 += e0.z + e1.z; d3 += e0.w + e1.w;
    float v00 = b2f(u0 & 0xffffu), v01 = b2f(u0 >> 16);
    float v10 = b2f(u1 & 0xffffu), v11 = b2f(u1 >> 16);
    a00 += e0.x*v00 + e1.x*v10; a01 += e0.x*v01 + e1.x*v11;
    a10 += e0.y*v00 + e1.y*v10; a11 += e0.y*v01 + e1.y*v11;
    a20 += e0.z*v00 + e1.z*v10; a21 += e0.z*v01 + e1.z*v11;
    a30 += e0.w*v00 + e1.w*v10; a31 += e0.w*v01 + e1.w*v11;
  }
  if (p < end){
    int s0 = epk[p].x;
    float4 e0 = exf[p];
    unsigned u0 = 0;
    if (act) u0 = *(const unsigned*)&nfb[(size_t)s0 * NFP + col];
    d0 += e0.x; d1 += e0.y; d2 += e0.z; d3 += e0.w;
    float v00 = b2f(u0 & 0xffffu), v01 = b2f(u0 >> 16);
    a00 += e0.x*v00; a01 += e0.x*v01;
    a10 += e0.y*v00; a11 += e0.y*v01;
    a20 += e0.z*v00; a21 += e0.z*v01;
    a30 += e0.w*v00; a31 += e0.w*v01;
  }
  float i0 = 1.f/(d0+1e-16f), i1 = 1.f/(d1+1e-16f);
  float i2 = 1.f/(d2+1e-16f), i3 = 1.f/(d3+1e-16f);
  constexpr size_t HS = (size_t)NN * KP1;
  size_t base = (size_t)n * KP1 + col;
  if (act){
    *(unsigned*)&agg[base]        = pk2(a00*i0, a01*i0);
    *(unsigned*)&agg[base +   HS] = pk2(a10*i1, a11*i1);
    *(unsigned*)&agg[base + 2*HS] = pk2(a20*i2, a21*i2);
    *(unsigned*)&agg[base + 3*HS] = pk2(a30*i3, a31*i3);
  } else if (lane < 48){                // zero cols 72..95
    *(unsigned*)&agg[base]        = 0u;
    *(unsigned*)&agg[base +   HS] = 0u;
    *(unsigned*)&agg[base + 2*HS] = 0u;
    *(unsigned*)&agg[base + 3*HS] = 0u;
  }
}

// ---- layer2 aggregation: 4-edge pipelined gather + GELU + LN + projections --
__global__ __launch_bounds__(256) void k_agg2(
    const int* __restrict__ csr, const int4* __restrict__ epk,
    const float* __restrict__ ex2, const unsigned short* __restrict__ xs2b,
    const float* __restrict__ b2, const float* __restrict__ lng,
    const float* __restrict__ lnb, const float* __restrict__ pw,
    const float* __restrict__ pb, const float* __restrict__ dwm,
    const float* __restrict__ dbv, float* __restrict__ out){
  int lane = threadIdx.x & 63, w = threadIdx.x >> 6;
  int n = blockIdx.x * 4 + w;
  if (n >= NN) return;
  int off = __builtin_amdgcn_readfirstlane(csr[n]);
  int end = __builtin_amdgcn_readfirstlane(csr[n + 1]);
  int c0 = lane * 2;
  float acc0 = 0.f, acc1 = 0.f, den = 0.f;
  int p = off;
  for (; p + 4 <= end; p += 4){
    int s0 = epk[p].x, s1 = epk[p+1].x, s2 = epk[p+2].x, s3 = epk[p+3].x;
    float e0 = ex2[p], e1 = ex2[p+1], e2 = ex2[p+2], e3 = ex2[p+3];
    unsigned u0 = *(const unsigned*)&xs2b[(size_t)s0 * 128 + c0];
    unsigned u1 = *(const unsigned*)&xs2b[(size_t)s1 * 128 + c0];
    unsigned u2 = *(const unsigned*)&xs2b[(size_t)s2 * 128 + c0];
    unsigned u3 = *(const unsigned*)&xs2b[(size_t)s3 * 128 + c0];
    den += (e0 + e1) + (e2 + e3);
    acc0 += e0*b2f(u0 & 0xffffu) + e1*b2f(u1 & 0xffffu)
          + e2*b2f(u2 & 0xffffu) + e3*b2f(u3 & 0xffffu);
    acc1 += e0*b2f(u0 >> 16) + e1*b2f(u1 >> 16)
          + e2*b2f(u2 >> 16) + e3*b2f(u3 >> 16);
  }
  for (; p + 2 <= end; p += 2){
    int s0 = epk[p].x, s1 = epk[p+1].x;
    float e0 = ex2[p], e1 = ex2[p+1];
    unsigned u0 = *(const unsigned*)&xs2b[(size_t)s0 * 128 + c0];
    unsigned u1 = *(const unsigned*)&xs2b[(size_t)s1 * 128 + c0];
    den += e0 + e1;
    acc0 += e0*b2f(u0 & 0xffffu) + e1*b2f(u1 & 0xffffu);
    acc1 += e0*b2f(u0 >> 16) + e1*b2f(u1 >> 16);
  }
  if (p < end){
    int s0 = epk[p].x;
    float e0 = ex2[p];
    unsigned u0 = *(const unsigned*)&xs2b[(size_t)s0 * 128 + c0];
    den += e0;
    acc0 += e0*b2f(u0 & 0xffffu);
    acc1 += e0*b2f(u0 >> 16);
  }
  float invd = 1.f / (den + 1e-16f);
  float g0 = gelu_fast(acc0 * invd + b2[c0]);
  float g1 = gelu_fast(acc1 * invd + b2[c0 + 1]);
  float s = g0 + g1;
  #pragma unroll
  for (int o = 32; o; o >>= 1) s += __shfl_xor(s, o);
  float mu = s * (1.f / 128.f);
  float e0 = g0 - mu, e1 = g1 - mu;
  float q = e0*e0 + e1*e1;
  #pragma unroll
  for (int o = 32; o; o >>= 1) q += __shfl_xor(q, o);
  float rstd = rsqrtf(q * (1.f / 128.f) + 1e-5f);
  float y0 = e0 * rstd * lng[c0] + lnb[c0];
  float y1 = e1 * rstd * lng[c0 + 1] + lnb[c0 + 1];
  float pr[12];
  #pragma unroll
  for (int jj = 0; jj < 8; ++jj) pr[jj] = y0 * pw[c0*8 + jj] + y1 * pw[(c0+1)*8 + jj];
  #pragma unroll
  for (int jj = 0; jj < 4; ++jj) pr[8+jj] = y0 * dwm[c0*4 + jj] + y1 * dwm[(c0+1)*4 + jj];
  #pragma unroll
  for (int o = 32; o; o >>= 1)
    #pragma unroll
    for (int jj = 0; jj < 12; ++jj) pr[jj] += __shfl_xor(pr[jj], o);
  if (lane == 0){
    #pragma unroll
    for (int jj = 0; jj < 8; ++jj) out[(size_t)n*8 + jj] = pr[jj] + pb[jj];
    #pragma unroll
    for (int jj = 0; jj < 4; ++jj) out[(size_t)NN*8 + (size_t)n*4 + jj] = pr[8+jj] + dbv[jj];
  }
}

extern "C" void kernel_launch(void* const* d_in, const int* in_sizes, int n_in,
                              void* d_out, int out_size, void* d_ws, size_t ws_size,
                              hipStream_t stream){
  const float* nf  = (const float*)d_in[0];
  const int*   ei  = (const int*)  d_in[1];
  const float* ea  = (const float*)d_in[2];
  const float* W1  = (const float*)d_in[3];
  const float* as1 = (const float*)d_in[4];
  const float* ad1 = (const float*)d_in[5];
  const float* We1 = (const float*)d_in[6];
  const float* ae1 = (const float*)d_in[7];
  const float* b1  = (const float*)d_in[8];
  const float* W2  = (const float*)d_in[9];
  const float* as2 = (const float*)d_in[10];
  const float* ad2 = (const float*)d_in[11];
  const float* We2 = (const float*)d_in[12];
  const float* ae2 = (const float*)d_in[13];
  const float* b2  = (const float*)d_in[14];
  const float* lng = (const float*)d_in[15];
  const float* lnb = (const float*)d_in[16];
  const float* pw  = (const float*)d_in[17];
  const float* pb  = (const float*)d_in[18];
  const float* dw  = (const float*)d_in[19];
  const float* db  = (const float*)d_in[20];
  float* out = (float*)d_out;

  float* wf = (float*)d_ws;
  int*      cnt  = (int*)     (wf + CNT_O);
  int*      csr  = (int*)     (wf + CSR_O);
  int*      bsum = (int*)     (wf + BSUM_O);
  int*      boff = (int*)     (wf + BOFF_O);
  int4*     epk  = (int4*)    (wf + EPK_O);
  float4*   exf1 = (float4*)  (wf + EXF1_O);
  float*    ex2  =            (wf + EXF2_O);
  float*    ss1  =            (wf + SS1_O);
  float*    sd1  =            (wf + SD1_O);
  float*    ss2  =            (wf + SS2_O);
  float*    sd2  =            (wf + SD2_O);
  float*    Cc   =            (wf + CST_O);
  unsigned short* W1t = (unsigned short*)(wf + W1T_O);
  unsigned short* W2t = (unsigned short*)(wf + W2T_O);
  unsigned short* nfb = (unsigned short*)(wf + NFB_O);
  unsigned short* agg = (unsigned short*)(wf + AGG_O);
  unsigned short* xs2b= (unsigned short*)(wf + XS2_O);

  hipMemsetAsync(cnt, 0, NN * sizeof(int), stream);
  k_prep<<<1, 512, 0, stream>>>(W1, as1, ad1, We1, ae1, W2, as2, ad2, We2, ae2, Cc);
  k_tw<<<(4*128*KP1 + 128*512 + 255) / 256, 256, 0, stream>>>(W1, W2, W1t, W2t);
  k_cnfs1<<<(NN + 3) / 4, 256, 0, stream>>>(nf, Cc, nfb, ss1, sd1);
  k_deg<<<(NE + 255) / 256, 256, 0, stream>>>(ei, cnt);
  k_scan1<<<SCB, 256, 0, stream>>>(cnt, bsum);
  k_scan2<<<1, 256, 0, stream>>>(bsum, boff);
  k_scan3<<<SCB, 256, 0, stream>>>(cnt, boff, csr);
  k_fill<<<(NE + 255) / 256, 256, 0, stream>>>(ei, ea, csr, cnt, epk, ss1, sd1, Cc, exf1);
  k_loopself<<<(NN + 255) / 256, 256, 0, stream>>>(csr, epk, ss1, sd1, Cc, exf1);
  k_aggnf<<<(NN + 3) / 4, 256, 0, stream>>>(csr, epk, exf1, nfb, agg);
  k_gemm12<<<(NN + 31) / 32, 256, 0, stream>>>(agg, W1t, W2t, b1, Cc, xs2b, ss2, sd2);
  k_al2<<<(ET + 255) / 256, 256, 0, stream>>>(epk, ss2, sd2, Cc, ex2);
  k_agg2<<<(NN + 3) / 4, 256, 0, stream>>>(csr, epk, ex2, xs2b,
                                           b2, lng, lnb, pw, pb, dw, db, out);
}